// Round 1
// baseline (1304.818 us; speedup 1.0000x reference)
//
#include <hip/hip_runtime.h>
#include <cstdint>

#define WIDTH 128
#define NB 16

__device__ __forceinline__ float gelu_f(float v) {
    return 0.5f * v * (1.0f + erff(v * 0.70710678118654752f));
}

// ---------------------------------------------------------------------------
// Kernel 0: compute scalars + transformed embedding tables.
// U layout: [3 remix][34 rows][128 cols]; row offsets per attr column:
//   emb0: rows 0..5 (6), emb1: 6..12 (7), emb2: 13..15 (3), emb3: 16..33 (18)
// U_r[c][i][j] = s_r * xw[c] * sum_d emb_c[i][d] * remix_r_w[d][j]
//   (+ s_r * remix_r_b[j] folded into the c==0 rows)
// s_r = exp(init0[2]) for r=0,1 (scale_e); exp(init0[3]) for r=2 (scale_v)
// scal[0] = init0[0], scal[1] = init0[1]
// ---------------------------------------------------------------------------
__global__ void k_prep(const float* __restrict__ einit, const float* __restrict__ init0,
                       const float* __restrict__ emb0, const float* __restrict__ emb1,
                       const float* __restrict__ emb2, const float* __restrict__ emb3,
                       const float* __restrict__ r0w, const float* __restrict__ r0b,
                       const float* __restrict__ r1w, const float* __restrict__ r1b,
                       const float* __restrict__ r2w, const float* __restrict__ r2b,
                       float* __restrict__ U, float* __restrict__ scal) {
    float e0 = expf(einit[0]), e1 = expf(einit[1]), e2 = expf(einit[2]), e3 = expf(einit[3]);
    float inv = 1.0f / sqrtf(e0 + e1 + e2 + e3);
    float xw[4] = {e0 * inv, e1 * inv, e2 * inv, e3 * inv};
    float se = expf(init0[2]);
    float sv = expf(init0[3]);
    if (threadIdx.x == 0) { scal[0] = init0[0]; scal[1] = init0[1]; }

    const int total = 3 * 34 * WIDTH;
    for (int idx = threadIdx.x; idx < total; idx += blockDim.x) {
        int r   = idx / (34 * WIDTH);
        int rem = idx - r * (34 * WIDTH);
        int g   = rem / WIDTH;
        int j   = rem - g * WIDTH;
        int cc, base;
        if (g >= 16)      { cc = 3; base = 16; }
        else if (g >= 13) { cc = 2; base = 13; }
        else if (g >= 6)  { cc = 1; base = 6; }
        else              { cc = 0; base = 0; }
        int i = g - base;
        const float* em = (cc == 0) ? emb0 : (cc == 1) ? emb1 : (cc == 2) ? emb2 : emb3;
        const float* w  = (r == 0) ? r0w : (r == 1) ? r1w : r2w;
        const float* rb = (r == 0) ? r0b : (r == 1) ? r1b : r2b;
        float s = (r == 2) ? sv : se;
        float acc = 0.0f;
        const float* erow = em + i * 64;
        for (int d = 0; d < 64; ++d) acc += erow[d] * w[d * WIDTH + j];
        float val = s * xw[cc] * acc;
        if (cc == 0) val += s * rb[j];
        U[idx] = val;
    }
}

// ---------------------------------------------------------------------------
// Kernel 1: xx = LayerNorm(x @ pre_w + pre_b), no affine.
// Block: 128 threads (one output column each), NB=16 nodes per block.
// ---------------------------------------------------------------------------
__global__ void k_pre_ln(const float* __restrict__ x, const float* __restrict__ pre_w,
                         const float* __restrict__ pre_b, float* __restrict__ xx, int n) {
    __shared__ float xs[NB][WIDTH];
    __shared__ float outs[NB][WIDTH + 1];
    __shared__ float stats[NB][2];
    int c  = threadIdx.x;
    int n0 = blockIdx.x * NB;

    for (int i = 0; i < NB; ++i) {
        int node = n0 + i;
        xs[i][c] = (node < n) ? x[(size_t)node * WIDTH + c] : 0.0f;
    }
    __syncthreads();

    float acc[NB];
#pragma unroll
    for (int i = 0; i < NB; ++i) acc[i] = 0.0f;
#pragma unroll 4
    for (int k = 0; k < WIDTH; ++k) {
        float w = pre_w[k * WIDTH + c];
#pragma unroll
        for (int i = 0; i < NB; ++i) acc[i] += xs[i][k] * w;
    }
    float b = pre_b[c];
#pragma unroll
    for (int i = 0; i < NB; ++i) outs[i][c] = acc[i] + b;
    __syncthreads();

    // LN stats: 16 groups of 8 threads, group g handles node g
    int g = c >> 3, l = c & 7;
    float s = 0.0f, s2 = 0.0f;
    for (int j = l; j < WIDTH; j += 8) {
        float v = outs[g][j];
        s += v; s2 += v * v;
    }
    s  += __shfl_xor(s, 1);  s2 += __shfl_xor(s2, 1);
    s  += __shfl_xor(s, 2);  s2 += __shfl_xor(s2, 2);
    s  += __shfl_xor(s, 4);  s2 += __shfl_xor(s2, 4);
    if (l == 0) {
        float m   = s * (1.0f / WIDTH);
        float var = s2 * (1.0f / WIDTH) - m * m;
        stats[g][0] = m;
        stats[g][1] = rsqrtf(var + 1e-5f);
    }
    __syncthreads();

    for (int i = 0; i < NB; ++i) {
        int node = n0 + i;
        if (node < n)
            xx[(size_t)node * WIDTH + c] = (outs[i][c] - stats[i][0]) * stats[i][1];
    }
}

// ---------------------------------------------------------------------------
// Kernel 2: 4 fused node GEMMs on xx:
//   G = gelu(xx@msg0_w + b0), A = xx@msg1_w + b1, B = xx@msg2_w + b2, C = xx@msg3_w + b3
// ---------------------------------------------------------------------------
template <bool GELU>
__device__ __forceinline__ void node_gemm(const float xs[NB][WIDTH],
                                          const float* __restrict__ w,
                                          const float* __restrict__ b,
                                          float* __restrict__ out,
                                          int n0, int n, int c) {
    float acc[NB];
#pragma unroll
    for (int i = 0; i < NB; ++i) acc[i] = 0.0f;
#pragma unroll 4
    for (int k = 0; k < WIDTH; ++k) {
        float wv = w[k * WIDTH + c];
#pragma unroll
        for (int i = 0; i < NB; ++i) acc[i] += xs[i][k] * wv;
    }
    float bv = b[c];
#pragma unroll
    for (int i = 0; i < NB; ++i) {
        int node = n0 + i;
        if (node < n) {
            float v = acc[i] + bv;
            if (GELU) v = gelu_f(v);
            out[(size_t)node * WIDTH + c] = v;
        }
    }
}

__global__ void k_node4(const float* __restrict__ xx,
                        const float* __restrict__ w0, const float* __restrict__ b0,
                        const float* __restrict__ w1, const float* __restrict__ b1,
                        const float* __restrict__ w2, const float* __restrict__ b2,
                        const float* __restrict__ w3, const float* __restrict__ b3,
                        float* __restrict__ G, float* __restrict__ A,
                        float* __restrict__ B, float* __restrict__ C, int n) {
    __shared__ float xs[NB][WIDTH];
    int c  = threadIdx.x;
    int n0 = blockIdx.x * NB;
    for (int i = 0; i < NB; ++i) {
        int node = n0 + i;
        xs[i][c] = (node < n) ? xx[(size_t)node * WIDTH + c] : 0.0f;
    }
    __syncthreads();
    node_gemm<true >(xs, w0, b0, G, n0, n, c);
    node_gemm<false>(xs, w1, b1, A, n0, n, c);
    node_gemm<false>(xs, w2, b2, B, n0, n, c);
    node_gemm<false>(xs, w3, b3, C, n0, n, c);
}

// ---------------------------------------------------------------------------
// Kernel 3: per-edge attention + scatter-add.
// 32 threads per edge, thread t handles columns [4t, 4t+4).
// q = A[dst] + U0[attrs], k = B[src] + U1[attrs], v = gelu(C[src] + U2[attrs])
// att(head h) = exp((sum_{head} q*k / 8) * i0 + i1); msg = v*att; agg[dst] += msg
// ---------------------------------------------------------------------------
__global__ void k_edge(const int* __restrict__ edge_index, const int* __restrict__ edge_attr,
                       const float* __restrict__ A, const float* __restrict__ B,
                       const float* __restrict__ C, const float* __restrict__ U,
                       const float* __restrict__ scal, float* __restrict__ agg, int E) {
    int tid = blockIdx.x * blockDim.x + threadIdx.x;
    int e = tid >> 5;
    int t = tid & 31;
    if (e >= E) return;

    int src = edge_index[e];
    int dst = edge_index[E + e];
    int4 at = ((const int4*)edge_attr)[e];
    int r0 = at.x;          // offset 0
    int r1 = 6  + at.y;
    int r2 = 13 + at.z;
    int r3 = 16 + at.w;

    int col = t * 4;
    const float4* U0 = (const float4*)(U);
    const float4* U1 = (const float4*)(U + 34 * WIDTH);
    const float4* U2 = (const float4*)(U + 2 * 34 * WIDTH);
    int c4 = col >> 2;  // float4 column index (0..31)

    float4 u0a = U0[r0 * 32 + c4], u0b = U0[r1 * 32 + c4], u0c = U0[r2 * 32 + c4], u0d = U0[r3 * 32 + c4];
    float4 u1a = U1[r0 * 32 + c4], u1b = U1[r1 * 32 + c4], u1c = U1[r2 * 32 + c4], u1d = U1[r3 * 32 + c4];
    float4 u2a = U2[r0 * 32 + c4], u2b = U2[r1 * 32 + c4], u2c = U2[r2 * 32 + c4], u2d = U2[r3 * 32 + c4];

    float4 qa = ((const float4*)(A + (size_t)dst * WIDTH))[c4];
    float4 ka = ((const float4*)(B + (size_t)src * WIDTH))[c4];
    float4 va = ((const float4*)(C + (size_t)src * WIDTH))[c4];

    float qx = qa.x + u0a.x + u0b.x + u0c.x + u0d.x;
    float qy = qa.y + u0a.y + u0b.y + u0c.y + u0d.y;
    float qz = qa.z + u0a.z + u0b.z + u0c.z + u0d.z;
    float qw = qa.w + u0a.w + u0b.w + u0c.w + u0d.w;

    float kx = ka.x + u1a.x + u1b.x + u1c.x + u1d.x;
    float ky = ka.y + u1a.y + u1b.y + u1c.y + u1d.y;
    float kz = ka.z + u1a.z + u1b.z + u1c.z + u1d.z;
    float kw = ka.w + u1a.w + u1b.w + u1c.w + u1d.w;

    float vx = gelu_f(va.x + u2a.x + u2b.x + u2c.x + u2d.x);
    float vy = gelu_f(va.y + u2a.y + u2b.y + u2c.y + u2d.y);
    float vz = gelu_f(va.z + u2a.z + u2b.z + u2c.z + u2d.z);
    float vw = gelu_f(va.w + u2a.w + u2b.w + u2c.w + u2d.w);

    float s = qx * kx + qy * ky + qz * kz + qw * kw;
    // reduce across the 16 lanes of this head (lanes 0-15: head0, 16-31: head1)
    s += __shfl_xor(s, 1);
    s += __shfl_xor(s, 2);
    s += __shfl_xor(s, 4);
    s += __shfl_xor(s, 8);

    float i0 = scal[0], i1 = scal[1];
    float att = expf(s * 0.125f * i0 + i1);

    float* dstp = agg + (size_t)dst * WIDTH + col;
    atomicAdd(dstp + 0, vx * att);
    atomicAdd(dstp + 1, vy * att);
    atomicAdd(dstp + 2, vz * att);
    atomicAdd(dstp + 3, vw * att);
}

// ---------------------------------------------------------------------------
// Kernel 4: out = x + (G + agg) @ post_w + post_b
// ---------------------------------------------------------------------------
__global__ void k_post(const float* __restrict__ x, const float* __restrict__ G,
                       const float* __restrict__ agg, const float* __restrict__ post_w,
                       const float* __restrict__ post_b, float* __restrict__ out, int n) {
    __shared__ float hs[NB][WIDTH];
    int c  = threadIdx.x;
    int n0 = blockIdx.x * NB;
    for (int i = 0; i < NB; ++i) {
        int node = n0 + i;
        hs[i][c] = (node < n) ? (G[(size_t)node * WIDTH + c] + agg[(size_t)node * WIDTH + c]) : 0.0f;
    }
    __syncthreads();
    float acc[NB];
#pragma unroll
    for (int i = 0; i < NB; ++i) acc[i] = 0.0f;
#pragma unroll 4
    for (int k = 0; k < WIDTH; ++k) {
        float w = post_w[k * WIDTH + c];
#pragma unroll
        for (int i = 0; i < NB; ++i) acc[i] += hs[i][k] * w;
    }
    float b = post_b[c];
#pragma unroll
    for (int i = 0; i < NB; ++i) {
        int node = n0 + i;
        if (node < n)
            out[(size_t)node * WIDTH + c] = x[(size_t)node * WIDTH + c] + acc[i] + b;
    }
}

extern "C" void kernel_launch(void* const* d_in, const int* in_sizes, int n_in,
                              void* d_out, int out_size, void* d_ws, size_t ws_size,
                              hipStream_t stream) {
    const float* x      = (const float*)d_in[0];
    const int*   eidx   = (const int*)d_in[1];
    const int*   eattr  = (const int*)d_in[2];
    const float* pre_w  = (const float*)d_in[3];
    const float* pre_b  = (const float*)d_in[4];
    const float* msg0_w = (const float*)d_in[5];
    const float* msg0_b = (const float*)d_in[6];
    const float* msg1_w = (const float*)d_in[7];
    const float* msg1_b = (const float*)d_in[8];
    const float* msg2_w = (const float*)d_in[9];
    const float* msg2_b = (const float*)d_in[10];
    const float* msg3_w = (const float*)d_in[11];
    const float* msg3_b = (const float*)d_in[12];
    const float* r0w    = (const float*)d_in[13];
    const float* r0b    = (const float*)d_in[14];
    const float* r1w    = (const float*)d_in[15];
    const float* r1b    = (const float*)d_in[16];
    const float* r2w    = (const float*)d_in[17];
    const float* r2b    = (const float*)d_in[18];
    const float* post_w = (const float*)d_in[19];
    const float* post_b = (const float*)d_in[20];
    const float* emb0   = (const float*)d_in[21];
    const float* emb1   = (const float*)d_in[22];
    const float* emb2   = (const float*)d_in[23];
    const float* emb3   = (const float*)d_in[24];
    const float* einit  = (const float*)d_in[25];
    const float* init0  = (const float*)d_in[26];

    int n = in_sizes[0] / WIDTH;
    int E = in_sizes[2] / 4;
    size_t NW = (size_t)n * WIDTH;

    float* ws   = (float*)d_ws;
    float* xx   = ws;            // [N,128] LN(pre(x))
    float* A    = ws + NW;       // q node part (msg1, indexed by dst)
    float* B    = ws + 2 * NW;   // k node part (msg2, indexed by src)
    float* C    = ws + 3 * NW;   // v node part (msg3, indexed by src)
    float* G    = ws + 4 * NW;   // gelu(msg0(xx))
    float* agg  = ws + 5 * NW;   // segment-sum accumulator
    float* U    = ws + 6 * NW;   // [3][34][128] transformed embed tables
    float* scal = U + 3 * 34 * WIDTH;  // [2]

    k_prep<<<1, 256, 0, stream>>>(einit, init0, emb0, emb1, emb2, emb3,
                                  r0w, r0b, r1w, r1b, r2w, r2b, U, scal);
    int nb = (n + NB - 1) / NB;
    k_pre_ln<<<nb, WIDTH, 0, stream>>>(x, pre_w, pre_b, xx, n);
    k_node4<<<nb, WIDTH, 0, stream>>>(xx, msg0_w, msg0_b, msg1_w, msg1_b,
                                      msg2_w, msg2_b, msg3_w, msg3_b, G, A, B, C, n);
    hipMemsetAsync(agg, 0, NW * sizeof(float), stream);
    long long tot = (long long)E * 32;
    int eb = (int)((tot + 255) / 256);
    k_edge<<<eb, 256, 0, stream>>>(eidx, eattr, A, B, C, U, scal, agg, E);
    k_post<<<nb, WIDTH, 0, stream>>>(x, G, agg, post_w, post_b, (float*)d_out, n);
}

// Round 2
// 786.518 us; speedup vs baseline: 1.6590x; 1.6590x over previous
//
#include <hip/hip_runtime.h>
#include <cstdint>

#define WIDTH 128
#define NB 16

__device__ __forceinline__ float gelu_f(float v) {
    return 0.5f * v * (1.0f + erff(v * 0.70710678118654752f));
}

// ---------------------------------------------------------------------------
// Kernel 0: scalars + transformed embedding tables.
// U layout: [3 remix][34 rows][128 cols]; row offsets per attr column:
//   emb0: rows 0..5, emb1: 6..12, emb2: 13..15, emb3: 16..33
// U_r[c][i][j] = s_r * xw[c] * (emb_c[i] @ remix_r_w)[j]  (+ s_r*remix_r_b in c==0 rows)
// ---------------------------------------------------------------------------
__global__ void k_prep(const float* __restrict__ einit, const float* __restrict__ init0,
                       const float* __restrict__ emb0, const float* __restrict__ emb1,
                       const float* __restrict__ emb2, const float* __restrict__ emb3,
                       const float* __restrict__ r0w, const float* __restrict__ r0b,
                       const float* __restrict__ r1w, const float* __restrict__ r1b,
                       const float* __restrict__ r2w, const float* __restrict__ r2b,
                       float* __restrict__ U, float* __restrict__ scal) {
    float e0 = expf(einit[0]), e1 = expf(einit[1]), e2 = expf(einit[2]), e3 = expf(einit[3]);
    float inv = 1.0f / sqrtf(e0 + e1 + e2 + e3);
    float xw[4] = {e0 * inv, e1 * inv, e2 * inv, e3 * inv};
    float se = expf(init0[2]);
    float sv = expf(init0[3]);
    if (threadIdx.x == 0) { scal[0] = init0[0]; scal[1] = init0[1]; }

    const int total = 3 * 34 * WIDTH;
    for (int idx = threadIdx.x; idx < total; idx += blockDim.x) {
        int r   = idx / (34 * WIDTH);
        int rem = idx - r * (34 * WIDTH);
        int g   = rem / WIDTH;
        int j   = rem - g * WIDTH;
        int cc, base;
        if (g >= 16)      { cc = 3; base = 16; }
        else if (g >= 13) { cc = 2; base = 13; }
        else if (g >= 6)  { cc = 1; base = 6; }
        else              { cc = 0; base = 0; }
        int i = g - base;
        const float* em = (cc == 0) ? emb0 : (cc == 1) ? emb1 : (cc == 2) ? emb2 : emb3;
        const float* w  = (r == 0) ? r0w : (r == 1) ? r1w : r2w;
        const float* rb = (r == 0) ? r0b : (r == 1) ? r1b : r2b;
        float s = (r == 2) ? sv : se;
        float acc = 0.0f;
        const float* erow = em + i * 64;
        for (int d = 0; d < 64; ++d) acc += erow[d] * w[d * WIDTH + j];
        float val = s * xw[cc] * acc;
        if (cc == 0) val += s * rb[j];
        U[idx] = val;
    }
}

// ---------------------------------------------------------------------------
// Kernel 1: xx = LayerNorm(x @ pre_w + pre_b), no affine.
// ---------------------------------------------------------------------------
__global__ void k_pre_ln(const float* __restrict__ x, const float* __restrict__ pre_w,
                         const float* __restrict__ pre_b, float* __restrict__ xx, int n) {
    __shared__ float xs[NB][WIDTH];
    __shared__ float outs[NB][WIDTH + 1];
    __shared__ float stats[NB][2];
    int c  = threadIdx.x;
    int n0 = blockIdx.x * NB;

    for (int i = 0; i < NB; ++i) {
        int node = n0 + i;
        xs[i][c] = (node < n) ? x[(size_t)node * WIDTH + c] : 0.0f;
    }
    __syncthreads();

    float acc[NB];
#pragma unroll
    for (int i = 0; i < NB; ++i) acc[i] = 0.0f;
#pragma unroll 4
    for (int k = 0; k < WIDTH; ++k) {
        float w = pre_w[k * WIDTH + c];
#pragma unroll
        for (int i = 0; i < NB; ++i) acc[i] += xs[i][k] * w;
    }
    float b = pre_b[c];
#pragma unroll
    for (int i = 0; i < NB; ++i) outs[i][c] = acc[i] + b;
    __syncthreads();

    int g = c >> 3, l = c & 7;
    float s = 0.0f, s2 = 0.0f;
    for (int j = l; j < WIDTH; j += 8) {
        float v = outs[g][j];
        s += v; s2 += v * v;
    }
    s  += __shfl_xor(s, 1);  s2 += __shfl_xor(s2, 1);
    s  += __shfl_xor(s, 2);  s2 += __shfl_xor(s2, 2);
    s  += __shfl_xor(s, 4);  s2 += __shfl_xor(s2, 4);
    if (l == 0) {
        float m   = s * (1.0f / WIDTH);
        float var = s2 * (1.0f / WIDTH) - m * m;
        stats[g][0] = m;
        stats[g][1] = rsqrtf(var + 1e-5f);
    }
    __syncthreads();

    for (int i = 0; i < NB; ++i) {
        int node = n0 + i;
        if (node < n)
            xx[(size_t)node * WIDTH + c] = (outs[i][c] - stats[i][0]) * stats[i][1];
    }
}

// ---------------------------------------------------------------------------
// Kernel 2: 4 fused node GEMMs on xx.
// ---------------------------------------------------------------------------
template <bool GELU>
__device__ __forceinline__ void node_gemm(const float xs[NB][WIDTH],
                                          const float* __restrict__ w,
                                          const float* __restrict__ b,
                                          float* __restrict__ out,
                                          int n0, int n, int c) {
    float acc[NB];
#pragma unroll
    for (int i = 0; i < NB; ++i) acc[i] = 0.0f;
#pragma unroll 4
    for (int k = 0; k < WIDTH; ++k) {
        float wv = w[k * WIDTH + c];
#pragma unroll
        for (int i = 0; i < NB; ++i) acc[i] += xs[i][k] * wv;
    }
    float bv = b[c];
#pragma unroll
    for (int i = 0; i < NB; ++i) {
        int node = n0 + i;
        if (node < n) {
            float v = acc[i] + bv;
            if (GELU) v = gelu_f(v);
            out[(size_t)node * WIDTH + c] = v;
        }
    }
}

__global__ void k_node4(const float* __restrict__ xx,
                        const float* __restrict__ w0, const float* __restrict__ b0,
                        const float* __restrict__ w1, const float* __restrict__ b1,
                        const float* __restrict__ w2, const float* __restrict__ b2,
                        const float* __restrict__ w3, const float* __restrict__ b3,
                        float* __restrict__ G, float* __restrict__ A,
                        float* __restrict__ B, float* __restrict__ C, int n) {
    __shared__ float xs[NB][WIDTH];
    int c  = threadIdx.x;
    int n0 = blockIdx.x * NB;
    for (int i = 0; i < NB; ++i) {
        int node = n0 + i;
        xs[i][c] = (node < n) ? xx[(size_t)node * WIDTH + c] : 0.0f;
    }
    __syncthreads();
    node_gemm<true >(xs, w0, b0, G, n0, n, c);
    node_gemm<false>(xs, w1, b1, A, n0, n, c);
    node_gemm<false>(xs, w2, b2, B, n0, n, c);
    node_gemm<false>(xs, w3, b3, C, n0, n, c);
}

// ---------------------------------------------------------------------------
// Sort-by-dst machinery: histogram -> exclusive scan -> scatter.
// ---------------------------------------------------------------------------
__global__ void k_hist(const int* __restrict__ edge_index, int* __restrict__ counts, int E) {
    int e = blockIdx.x * blockDim.x + threadIdx.x;
    if (e >= E) return;
    int dst = edge_index[E + e];
    atomicAdd(&counts[dst], 1);
}

__global__ void k_scan(const int* __restrict__ counts, int* __restrict__ offsets,
                       int* __restrict__ cursor, int n) {
    __shared__ int sdata[1024];
    int t = threadIdx.x;
    int chunk = (n + 1023) >> 10;
    int lo = t * chunk;
    int hi = min(n, lo + chunk);
    int s = 0;
    for (int i = lo; i < hi; ++i) s += counts[i];
    sdata[t] = s;
    __syncthreads();
    // inclusive Hillis-Steele scan
    for (int d = 1; d < 1024; d <<= 1) {
        int v = (t >= d) ? sdata[t - d] : 0;
        __syncthreads();
        sdata[t] += v;
        __syncthreads();
    }
    int run = (t == 0) ? 0 : sdata[t - 1];
    for (int i = lo; i < hi; ++i) {
        offsets[i] = run;
        cursor[i]  = run;
        run += counts[i];
    }
    if (t == 1023) offsets[n] = sdata[1023];
}

__global__ void k_scatter(const int* __restrict__ edge_index, int* __restrict__ cursor,
                          int* __restrict__ sorted, int E) {
    int e = blockIdx.x * blockDim.x + threadIdx.x;
    if (e >= E) return;
    int dst = edge_index[E + e];
    int pos = atomicAdd(&cursor[dst], 1);
    sorted[pos] = e;
}

// ---------------------------------------------------------------------------
// Kernel 3: per-node aggregation over its dst-sorted edge segment.
// Block = 128 threads (2 waves), one node per block; thread c owns column c.
// Wave 0 = head 0 (cols 0..63), wave 1 = head 1 (cols 64..127).
// No atomics: accumulator lives in a register, one coalesced write per node.
// ---------------------------------------------------------------------------
__global__ void __launch_bounds__(128)
k_agg(const int* __restrict__ edge_index, const int* __restrict__ edge_attr,
      const int* __restrict__ offsets, const int* __restrict__ sorted,
      const float* __restrict__ A, const float* __restrict__ B,
      const float* __restrict__ C, const float* __restrict__ U,
      const float* __restrict__ scal, float* __restrict__ agg, int n, int E) {
    int node = blockIdx.x;
    int c = threadIdx.x;
    int start = offsets[node];
    int end   = offsets[node + 1];

    const float* U0 = U;
    const float* U1 = U + 34 * WIDTH;
    const float* U2 = U + 2 * 34 * WIDTH;

    float a   = A[(size_t)node * WIDTH + c];
    float i0  = scal[0], i1 = scal[1];
    float acc = 0.0f;

    for (int p = start; p < end; ++p) {
        int e = sorted[p];
        int src = edge_index[e];
        int4 at = ((const int4*)edge_attr)[e];
        int r0 = at.x * WIDTH;
        int r1 = (6  + at.y) * WIDTH;
        int r2 = (13 + at.z) * WIDTH;
        int r3 = (16 + at.w) * WIDTH;

        float q  = a + U0[r0 + c] + U0[r1 + c] + U0[r2 + c] + U0[r3 + c];
        float kk = B[(size_t)src * WIDTH + c] + U1[r0 + c] + U1[r1 + c] + U1[r2 + c] + U1[r3 + c];
        float vv = gelu_f(C[(size_t)src * WIDTH + c] + U2[r0 + c] + U2[r1 + c] + U2[r2 + c] + U2[r3 + c]);

        float s = q * kk;
        // reduce over the 64 lanes of this wave (one head per wave)
        s += __shfl_xor(s, 1);
        s += __shfl_xor(s, 2);
        s += __shfl_xor(s, 4);
        s += __shfl_xor(s, 8);
        s += __shfl_xor(s, 16);
        s += __shfl_xor(s, 32);

        float att = expf(s * 0.125f * i0 + i1);
        acc += vv * att;
    }
    agg[(size_t)node * WIDTH + c] = acc;
}

// ---------------------------------------------------------------------------
// Kernel 4: out = x + (G + agg) @ post_w + post_b
// ---------------------------------------------------------------------------
__global__ void k_post(const float* __restrict__ x, const float* __restrict__ G,
                       const float* __restrict__ agg, const float* __restrict__ post_w,
                       const float* __restrict__ post_b, float* __restrict__ out, int n) {
    __shared__ float hs[NB][WIDTH];
    int c  = threadIdx.x;
    int n0 = blockIdx.x * NB;
    for (int i = 0; i < NB; ++i) {
        int node = n0 + i;
        hs[i][c] = (node < n) ? (G[(size_t)node * WIDTH + c] + agg[(size_t)node * WIDTH + c]) : 0.0f;
    }
    __syncthreads();
    float acc[NB];
#pragma unroll
    for (int i = 0; i < NB; ++i) acc[i] = 0.0f;
#pragma unroll 4
    for (int k = 0; k < WIDTH; ++k) {
        float w = post_w[k * WIDTH + c];
#pragma unroll
        for (int i = 0; i < NB; ++i) acc[i] += hs[i][k] * w;
    }
    float b = post_b[c];
#pragma unroll
    for (int i = 0; i < NB; ++i) {
        int node = n0 + i;
        if (node < n)
            out[(size_t)node * WIDTH + c] = x[(size_t)node * WIDTH + c] + acc[i] + b;
    }
}

extern "C" void kernel_launch(void* const* d_in, const int* in_sizes, int n_in,
                              void* d_out, int out_size, void* d_ws, size_t ws_size,
                              hipStream_t stream) {
    const float* x      = (const float*)d_in[0];
    const int*   eidx   = (const int*)d_in[1];
    const int*   eattr  = (const int*)d_in[2];
    const float* pre_w  = (const float*)d_in[3];
    const float* pre_b  = (const float*)d_in[4];
    const float* msg0_w = (const float*)d_in[5];
    const float* msg0_b = (const float*)d_in[6];
    const float* msg1_w = (const float*)d_in[7];
    const float* msg1_b = (const float*)d_in[8];
    const float* msg2_w = (const float*)d_in[9];
    const float* msg2_b = (const float*)d_in[10];
    const float* msg3_w = (const float*)d_in[11];
    const float* msg3_b = (const float*)d_in[12];
    const float* r0w    = (const float*)d_in[13];
    const float* r0b    = (const float*)d_in[14];
    const float* r1w    = (const float*)d_in[15];
    const float* r1b    = (const float*)d_in[16];
    const float* r2w    = (const float*)d_in[17];
    const float* r2b    = (const float*)d_in[18];
    const float* post_w = (const float*)d_in[19];
    const float* post_b = (const float*)d_in[20];
    const float* emb0   = (const float*)d_in[21];
    const float* emb1   = (const float*)d_in[22];
    const float* emb2   = (const float*)d_in[23];
    const float* emb3   = (const float*)d_in[24];
    const float* einit  = (const float*)d_in[25];
    const float* init0  = (const float*)d_in[26];

    int n = in_sizes[0] / WIDTH;
    int E = in_sizes[2] / 4;
    size_t NW = (size_t)n * WIDTH;

    float* ws   = (float*)d_ws;
    float* xx   = ws;            // [N,128]
    float* A    = ws + NW;       // q node part (indexed by dst)
    float* B    = ws + 2 * NW;   // k node part (indexed by src)
    float* C    = ws + 3 * NW;   // v node part (indexed by src)
    float* G    = ws + 4 * NW;   // gelu(msg0(xx))
    float* agg  = ws + 5 * NW;   // segment-sum result
    float* U    = ws + 6 * NW;   // [3][34][128]
    float* scal = U + 3 * 34 * WIDTH;        // [2]
    int*   ib      = (int*)(scal + 2);
    int*   offsets = ib;                      // n+1
    int*   cursor  = offsets + (n + 1);       // n
    int*   counts  = cursor + n;              // n
    int*   sorted  = counts + n;              // E

    k_prep<<<1, 256, 0, stream>>>(einit, init0, emb0, emb1, emb2, emb3,
                                  r0w, r0b, r1w, r1b, r2w, r2b, U, scal);
    int nb = (n + NB - 1) / NB;
    k_pre_ln<<<nb, WIDTH, 0, stream>>>(x, pre_w, pre_b, xx, n);
    k_node4<<<nb, WIDTH, 0, stream>>>(xx, msg0_w, msg0_b, msg1_w, msg1_b,
                                      msg2_w, msg2_b, msg3_w, msg3_b, G, A, B, C, n);

    hipMemsetAsync(counts, 0, (size_t)n * sizeof(int), stream);
    int eb = (E + 255) / 256;
    k_hist<<<eb, 256, 0, stream>>>(eidx, counts, E);
    k_scan<<<1, 1024, 0, stream>>>(counts, offsets, cursor, n);
    k_scatter<<<eb, 256, 0, stream>>>(eidx, cursor, sorted, E);
    k_agg<<<n, WIDTH, 0, stream>>>(eidx, eattr, offsets, sorted, A, B, C, U, scal, agg, n, E);

    k_post<<<nb, WIDTH, 0, stream>>>(x, G, agg, post_w, post_b, (float*)d_out, n);
}

// Round 3
// 609.902 us; speedup vs baseline: 2.1394x; 1.2896x over previous
//
#include <hip/hip_runtime.h>
#include <cstdint>

#define WIDTH 128
#define NB 16

__device__ __forceinline__ float gelu_f(float v) {
    return 0.5f * v * (1.0f + erff(v * 0.70710678118654752f));
}

// ---------------------------------------------------------------------------
// Kernel 0: scalars + transformed embedding tables.
// U layout: [3 remix][34 rows][128 cols]; row offsets per attr column:
//   emb0: rows 0..5, emb1: 6..12, emb2: 13..15, emb3: 16..33
// U_r[c][i][j] = s_r * xw[c] * (emb_c[i] @ remix_r_w)[j]  (+ s_r*remix_r_b in c==0 rows)
// ---------------------------------------------------------------------------
__global__ void k_prep(const float* __restrict__ einit, const float* __restrict__ init0,
                       const float* __restrict__ emb0, const float* __restrict__ emb1,
                       const float* __restrict__ emb2, const float* __restrict__ emb3,
                       const float* __restrict__ r0w, const float* __restrict__ r0b,
                       const float* __restrict__ r1w, const float* __restrict__ r1b,
                       const float* __restrict__ r2w, const float* __restrict__ r2b,
                       float* __restrict__ U, float* __restrict__ scal) {
    float e0 = expf(einit[0]), e1 = expf(einit[1]), e2 = expf(einit[2]), e3 = expf(einit[3]);
    float inv = 1.0f / sqrtf(e0 + e1 + e2 + e3);
    float xw[4] = {e0 * inv, e1 * inv, e2 * inv, e3 * inv};
    float se = expf(init0[2]);
    float sv = expf(init0[3]);
    if (threadIdx.x == 0) { scal[0] = init0[0]; scal[1] = init0[1]; }

    const int total = 3 * 34 * WIDTH;
    for (int idx = threadIdx.x; idx < total; idx += blockDim.x) {
        int r   = idx / (34 * WIDTH);
        int rem = idx - r * (34 * WIDTH);
        int g   = rem / WIDTH;
        int j   = rem - g * WIDTH;
        int cc, base;
        if (g >= 16)      { cc = 3; base = 16; }
        else if (g >= 13) { cc = 2; base = 13; }
        else if (g >= 6)  { cc = 1; base = 6; }
        else              { cc = 0; base = 0; }
        int i = g - base;
        const float* em = (cc == 0) ? emb0 : (cc == 1) ? emb1 : (cc == 2) ? emb2 : emb3;
        const float* w  = (r == 0) ? r0w : (r == 1) ? r1w : r2w;
        const float* rb = (r == 0) ? r0b : (r == 1) ? r1b : r2b;
        float s = (r == 2) ? sv : se;
        float acc = 0.0f;
        const float* erow = em + i * 64;
        for (int d = 0; d < 64; ++d) acc += erow[d] * w[d * WIDTH + j];
        float val = s * xw[cc] * acc;
        if (cc == 0) val += s * rb[j];
        U[idx] = val;
    }
}

// ---------------------------------------------------------------------------
// GEMM helper: out[col c] for NB nodes, K=128, k-unrolled x4 with b128 LDS reads.
// ---------------------------------------------------------------------------
template <bool GELU>
__device__ __forceinline__ void gemm16(const float (*xs)[WIDTH],
                                       const float* __restrict__ w,
                                       const float* __restrict__ b,
                                       float* __restrict__ out,
                                       int n0, int n, int c) {
    float acc[NB];
#pragma unroll
    for (int i = 0; i < NB; ++i) acc[i] = 0.0f;
    for (int k0 = 0; k0 < WIDTH; k0 += 4) {
        float4 xv[NB];
#pragma unroll
        for (int i = 0; i < NB; ++i) xv[i] = *(const float4*)(&xs[i][k0]);
#pragma unroll
        for (int kk = 0; kk < 4; ++kk) {
            float wv = w[(k0 + kk) * WIDTH + c];
#pragma unroll
            for (int i = 0; i < NB; ++i) {
                float xval = (kk == 0) ? xv[i].x : (kk == 1) ? xv[i].y : (kk == 2) ? xv[i].z : xv[i].w;
                acc[i] += xval * wv;
            }
        }
    }
    float bv = b[c];
#pragma unroll
    for (int i = 0; i < NB; ++i) {
        int node = n0 + i;
        if (node < n) {
            float v = acc[i] + bv;
            if (GELU) v = gelu_f(v);
            out[(size_t)node * WIDTH + c] = v;
        }
    }
}

// ---------------------------------------------------------------------------
// Kernel 1: fused  xx = LN(x@pre_w + pre_b)  ->  {G, (A), (B), C} node GEMMs.
// A (msg1/q) and B (msg2/k) are only computed when scal[0] != 0 (att depends
// on q,k only through s*init0[0]).  xx never touches HBM.
// ---------------------------------------------------------------------------
__global__ void __launch_bounds__(128) k_node(
        const float* __restrict__ x,
        const float* __restrict__ pre_w, const float* __restrict__ pre_b,
        const float* __restrict__ w0, const float* __restrict__ b0,
        const float* __restrict__ w1, const float* __restrict__ b1,
        const float* __restrict__ w2, const float* __restrict__ b2,
        const float* __restrict__ w3, const float* __restrict__ b3,
        const float* __restrict__ scal,
        float* __restrict__ G, float* __restrict__ A,
        float* __restrict__ B, float* __restrict__ C, int n) {
    __shared__ float xs[NB][WIDTH];
    __shared__ float stats[NB][2];
    int c  = threadIdx.x;
    int n0 = blockIdx.x * NB;

    for (int i = 0; i < NB; ++i) {
        int node = n0 + i;
        xs[i][c] = (node < n) ? x[(size_t)node * WIDTH + c] : 0.0f;
    }
    __syncthreads();

    // pre GEMM
    float acc[NB];
#pragma unroll
    for (int i = 0; i < NB; ++i) acc[i] = 0.0f;
    for (int k0 = 0; k0 < WIDTH; k0 += 4) {
        float4 xv[NB];
#pragma unroll
        for (int i = 0; i < NB; ++i) xv[i] = *(const float4*)(&xs[i][k0]);
#pragma unroll
        for (int kk = 0; kk < 4; ++kk) {
            float wv = pre_w[(k0 + kk) * WIDTH + c];
#pragma unroll
            for (int i = 0; i < NB; ++i) {
                float xval = (kk == 0) ? xv[i].x : (kk == 1) ? xv[i].y : (kk == 2) ? xv[i].z : xv[i].w;
                acc[i] += xval * wv;
            }
        }
    }
    float bv = pre_b[c];
    __syncthreads();   // all xs reads done before overwrite
#pragma unroll
    for (int i = 0; i < NB; ++i) xs[i][c] = acc[i] + bv;
    __syncthreads();

    // LN stats: 16 groups of 8 threads; group g handles node-row g
    {
        int g = c >> 3, l = c & 7;
        float s = 0.0f, s2 = 0.0f;
        for (int j = l; j < WIDTH; j += 8) {
            float v = xs[g][j];
            s += v; s2 += v * v;
        }
        s  += __shfl_xor(s, 1);  s2 += __shfl_xor(s2, 1);
        s  += __shfl_xor(s, 2);  s2 += __shfl_xor(s2, 2);
        s  += __shfl_xor(s, 4);  s2 += __shfl_xor(s2, 4);
        if (l == 0) {
            float m   = s * (1.0f / WIDTH);
            float var = s2 * (1.0f / WIDTH) - m * m;
            stats[g][0] = m;
            stats[g][1] = rsqrtf(var + 1e-5f);
        }
    }
    __syncthreads();
#pragma unroll
    for (int i = 0; i < NB; ++i) xs[i][c] = (xs[i][c] - stats[i][0]) * stats[i][1];
    __syncthreads();

    bool full = (scal[0] != 0.0f);
    gemm16<true >(xs, w0, b0, G, n0, n, c);   // G = gelu(msg0)
    gemm16<false>(xs, w3, b3, C, n0, n, c);   // C = msg3 (v node part)
    if (full) {
        gemm16<false>(xs, w1, b1, A, n0, n, c);   // A = msg1 (q)
        gemm16<false>(xs, w2, b2, B, n0, n, c);   // B = msg2 (k)
    }
}

// ---------------------------------------------------------------------------
// Sort-by-dst: histogram -> exclusive scan -> scatter (writes src + packed attr).
// ---------------------------------------------------------------------------
__global__ void k_hist(const int* __restrict__ edge_index, int* __restrict__ counts, int E) {
    int e = blockIdx.x * blockDim.x + threadIdx.x;
    if (e >= E) return;
    atomicAdd(&counts[edge_index[E + e]], 1);
}

__global__ void k_scan(const int* __restrict__ counts, int* __restrict__ offsets,
                       int* __restrict__ cursor, int n) {
    __shared__ int sdata[1024];
    int t = threadIdx.x;
    int chunk = (n + 1023) >> 10;
    int lo = t * chunk;
    int hi = min(n, lo + chunk);
    int s = 0;
    for (int i = lo; i < hi; ++i) s += counts[i];
    sdata[t] = s;
    __syncthreads();
    for (int d = 1; d < 1024; d <<= 1) {
        int v = (t >= d) ? sdata[t - d] : 0;
        __syncthreads();
        sdata[t] += v;
        __syncthreads();
    }
    int run = (t == 0) ? 0 : sdata[t - 1];
    for (int i = lo; i < hi; ++i) {
        offsets[i] = run;
        cursor[i]  = run;
        run += counts[i];
    }
    if (t == 1023) offsets[n] = sdata[1023];
}

__global__ void k_scatter(const int* __restrict__ edge_index, const int* __restrict__ edge_attr,
                          int* __restrict__ cursor,
                          int* __restrict__ s_src, unsigned* __restrict__ s_att, int E) {
    int e = blockIdx.x * blockDim.x + threadIdx.x;
    if (e >= E) return;
    int src = edge_index[e];
    int dst = edge_index[E + e];
    int4 at = ((const int4*)edge_attr)[e];
    unsigned pack = (unsigned)at.x | ((unsigned)at.y << 8) | ((unsigned)at.z << 16) | ((unsigned)at.w << 24);
    int pos = atomicAdd(&cursor[dst], 1);
    s_src[pos] = src;
    s_att[pos] = pack;
}

// ---------------------------------------------------------------------------
// Kernel 3: per-node aggregation. Block = 128 threads (2 waves), one node.
// Fast path (scal[0]==0): att = exp(scal[1]) is constant -> v-only.
// ---------------------------------------------------------------------------
__global__ void __launch_bounds__(128)
k_agg(const int* __restrict__ offsets, const int* __restrict__ s_src,
      const unsigned* __restrict__ s_att,
      const float* __restrict__ A, const float* __restrict__ B,
      const float* __restrict__ C, const float* __restrict__ U,
      const float* __restrict__ scal, float* __restrict__ agg, int n) {
    int node = blockIdx.x;
    int c = threadIdx.x;
    int start = offsets[node];
    int end   = offsets[node + 1];

    const float* U0 = U;
    const float* U1 = U + 34 * WIDTH;
    const float* U2 = U + 2 * 34 * WIDTH;

    float i0 = scal[0], i1 = scal[1];
    float acc = 0.0f;

    if (i0 == 0.0f) {
        // att = exp(i1) constant: only the v-path matters.
        for (int p = start; p < end; ++p) {
            int src = s_src[p];
            unsigned pk = s_att[p];
            int r0 = (int)(pk & 255u) << 7;
            int r1 = (int)(6u  + ((pk >> 8)  & 255u)) << 7;
            int r2 = (int)(13u + ((pk >> 16) & 255u)) << 7;
            int r3 = (int)(16u + (pk >> 24)) << 7;
            float cv = C[(size_t)src * WIDTH + c];
            float u  = U2[r0 + c] + U2[r1 + c] + U2[r2 + c] + U2[r3 + c];
            acc += gelu_f(cv + u);
        }
        acc *= expf(i1);
    } else {
        float a = A[(size_t)node * WIDTH + c];
        for (int p = start; p < end; ++p) {
            int src = s_src[p];
            unsigned pk = s_att[p];
            int r0 = (int)(pk & 255u) << 7;
            int r1 = (int)(6u  + ((pk >> 8)  & 255u)) << 7;
            int r2 = (int)(13u + ((pk >> 16) & 255u)) << 7;
            int r3 = (int)(16u + (pk >> 24)) << 7;

            float q  = a + U0[r0 + c] + U0[r1 + c] + U0[r2 + c] + U0[r3 + c];
            float kk = B[(size_t)src * WIDTH + c] + U1[r0 + c] + U1[r1 + c] + U1[r2 + c] + U1[r3 + c];
            float vv = gelu_f(C[(size_t)src * WIDTH + c] + U2[r0 + c] + U2[r1 + c] + U2[r2 + c] + U2[r3 + c]);

            float s = q * kk;
            s += __shfl_xor(s, 1);
            s += __shfl_xor(s, 2);
            s += __shfl_xor(s, 4);
            s += __shfl_xor(s, 8);
            s += __shfl_xor(s, 16);
            s += __shfl_xor(s, 32);

            acc += vv * expf(s * 0.125f * i0 + i1);
        }
    }
    agg[(size_t)node * WIDTH + c] = acc;
}

// ---------------------------------------------------------------------------
// Kernel 4: out = x + (G + agg) @ post_w + post_b
// ---------------------------------------------------------------------------
__global__ void __launch_bounds__(128)
k_post(const float* __restrict__ x, const float* __restrict__ G,
       const float* __restrict__ agg, const float* __restrict__ post_w,
       const float* __restrict__ post_b, float* __restrict__ out, int n) {
    __shared__ float hs[NB][WIDTH];
    int c  = threadIdx.x;
    int n0 = blockIdx.x * NB;
    for (int i = 0; i < NB; ++i) {
        int node = n0 + i;
        hs[i][c] = (node < n) ? (G[(size_t)node * WIDTH + c] + agg[(size_t)node * WIDTH + c]) : 0.0f;
    }
    __syncthreads();
    float acc[NB];
#pragma unroll
    for (int i = 0; i < NB; ++i) acc[i] = 0.0f;
    for (int k0 = 0; k0 < WIDTH; k0 += 4) {
        float4 xv[NB];
#pragma unroll
        for (int i = 0; i < NB; ++i) xv[i] = *(const float4*)(&hs[i][k0]);
#pragma unroll
        for (int kk = 0; kk < 4; ++kk) {
            float wv = post_w[(k0 + kk) * WIDTH + c];
#pragma unroll
            for (int i = 0; i < NB; ++i) {
                float xval = (kk == 0) ? xv[i].x : (kk == 1) ? xv[i].y : (kk == 2) ? xv[i].z : xv[i].w;
                acc[i] += xval * wv;
            }
        }
    }
    float b = post_b[c];
#pragma unroll
    for (int i = 0; i < NB; ++i) {
        int node = n0 + i;
        if (node < n)
            out[(size_t)node * WIDTH + c] = x[(size_t)node * WIDTH + c] + acc[i] + b;
    }
}

extern "C" void kernel_launch(void* const* d_in, const int* in_sizes, int n_in,
                              void* d_out, int out_size, void* d_ws, size_t ws_size,
                              hipStream_t stream) {
    const float* x      = (const float*)d_in[0];
    const int*   eidx   = (const int*)d_in[1];
    const int*   eattr  = (const int*)d_in[2];
    const float* pre_w  = (const float*)d_in[3];
    const float* pre_b  = (const float*)d_in[4];
    const float* msg0_w = (const float*)d_in[5];
    const float* msg0_b = (const float*)d_in[6];
    const float* msg1_w = (const float*)d_in[7];
    const float* msg1_b = (const float*)d_in[8];
    const float* msg2_w = (const float*)d_in[9];
    const float* msg2_b = (const float*)d_in[10];
    const float* msg3_w = (const float*)d_in[11];
    const float* msg3_b = (const float*)d_in[12];
    const float* r0w    = (const float*)d_in[13];
    const float* r0b    = (const float*)d_in[14];
    const float* r1w    = (const float*)d_in[15];
    const float* r1b    = (const float*)d_in[16];
    const float* r2w    = (const float*)d_in[17];
    const float* r2b    = (const float*)d_in[18];
    const float* post_w = (const float*)d_in[19];
    const float* post_b = (const float*)d_in[20];
    const float* emb0   = (const float*)d_in[21];
    const float* emb1   = (const float*)d_in[22];
    const float* emb2   = (const float*)d_in[23];
    const float* emb3   = (const float*)d_in[24];
    const float* einit  = (const float*)d_in[25];
    const float* init0  = (const float*)d_in[26];

    int n = in_sizes[0] / WIDTH;
    int E = in_sizes[2] / 4;
    size_t NW = (size_t)n * WIDTH;

    float* ws   = (float*)d_ws;
    float* A    = ws;            // q node part
    float* B    = ws + NW;       // k node part
    float* C    = ws + 2 * NW;   // v node part
    float* G    = ws + 3 * NW;   // gelu(msg0(xx))
    float* agg  = ws + 4 * NW;   // segment-sum result
    float* U    = ws + 5 * NW;   // [3][34][128]
    float* scal = U + 3 * 34 * WIDTH;        // [2]
    int*      ib      = (int*)(scal + 2);
    int*      offsets = ib;                       // n+1
    int*      cursor  = offsets + (n + 1);        // n
    int*      counts  = cursor + n;               // n
    int*      s_src   = counts + n;               // E
    unsigned* s_att   = (unsigned*)(s_src + E);   // E

    k_prep<<<1, 256, 0, stream>>>(einit, init0, emb0, emb1, emb2, emb3,
                                  r0w, r0b, r1w, r1b, r2w, r2b, U, scal);

    hipMemsetAsync(counts, 0, (size_t)n * sizeof(int), stream);
    int eb = (E + 255) / 256;
    k_hist<<<eb, 256, 0, stream>>>(eidx, counts, E);
    k_scan<<<1, 1024, 0, stream>>>(counts, offsets, cursor, n);
    k_scatter<<<eb, 256, 0, stream>>>(eidx, eattr, cursor, s_src, s_att, E);

    int nb = (n + NB - 1) / NB;
    k_node<<<nb, WIDTH, 0, stream>>>(x, pre_w, pre_b, msg0_w, msg0_b, msg1_w, msg1_b,
                                     msg2_w, msg2_b, msg3_w, msg3_b, scal, G, A, B, C, n);
    k_agg<<<n, WIDTH, 0, stream>>>(offsets, s_src, s_att, A, B, C, U, scal, agg, n);
    k_post<<<nb, WIDTH, 0, stream>>>(x, G, agg, post_w, post_b, (float*)d_out, n);
}

// Round 4
// 475.095 us; speedup vs baseline: 2.7464x; 1.2837x over previous
//
#include <hip/hip_runtime.h>
#include <cstdint>

#define WIDTH 128

typedef short bf16x8 __attribute__((ext_vector_type(8)));
typedef float f32x4  __attribute__((ext_vector_type(4)));

__device__ __forceinline__ float gelu_f(float v) {
    return 0.5f * v * (1.0f + erff(v * 0.70710678118654752f));
}
__device__ __forceinline__ short f2b(float f) {
    unsigned u = __float_as_uint(f);
    unsigned r = (u + 0x7FFFu + ((u >> 16) & 1u)) >> 16;
    return (short)r;
}
__device__ __forceinline__ float b2f(unsigned short s) {
    return __uint_as_float(((unsigned)s) << 16);
}

// ---------------------------------------------------------------------------
// k_prep: scalars + transformed embedding tables U (grid-stride, 52 blocks).
// U layout: [3 remix][34 rows][128 cols]; rows: emb0 0..5, emb1 6..12,
// emb2 13..15, emb3 16..33.
// ---------------------------------------------------------------------------
__global__ void k_prep(const float* __restrict__ einit, const float* __restrict__ init0,
                       const float* __restrict__ emb0, const float* __restrict__ emb1,
                       const float* __restrict__ emb2, const float* __restrict__ emb3,
                       const float* __restrict__ r0w, const float* __restrict__ r0b,
                       const float* __restrict__ r1w, const float* __restrict__ r1b,
                       const float* __restrict__ r2w, const float* __restrict__ r2b,
                       float* __restrict__ U, float* __restrict__ scal) {
    float e0 = expf(einit[0]), e1 = expf(einit[1]), e2 = expf(einit[2]), e3 = expf(einit[3]);
    float inv = 1.0f / sqrtf(e0 + e1 + e2 + e3);
    float xw[4] = {e0 * inv, e1 * inv, e2 * inv, e3 * inv};
    float se = expf(init0[2]);
    float sv = expf(init0[3]);
    int tid = blockIdx.x * blockDim.x + threadIdx.x;
    if (tid == 0) { scal[0] = init0[0]; scal[1] = init0[1]; }

    const int total = 3 * 34 * WIDTH;
    for (int idx = tid; idx < total; idx += gridDim.x * blockDim.x) {
        int r   = idx / (34 * WIDTH);
        int rem = idx - r * (34 * WIDTH);
        int g   = rem / WIDTH;
        int j   = rem - g * WIDTH;
        int cc, base;
        if (g >= 16)      { cc = 3; base = 16; }
        else if (g >= 13) { cc = 2; base = 13; }
        else if (g >= 6)  { cc = 1; base = 6; }
        else              { cc = 0; base = 0; }
        int i = g - base;
        const float* em = (cc == 0) ? emb0 : (cc == 1) ? emb1 : (cc == 2) ? emb2 : emb3;
        const float* w  = (r == 0) ? r0w : (r == 1) ? r1w : r2w;
        const float* rb = (r == 0) ? r0b : (r == 1) ? r1b : r2b;
        float s = (r == 2) ? sv : se;
        float acc = 0.0f;
        const float* erow = em + i * 64;
        for (int d = 0; d < 64; ++d) acc += erow[d] * w[d * WIDTH + j];
        float val = s * xw[cc] * acc;
        if (cc == 0) val += s * rb[j];
        U[idx] = val;
    }
}

// ---------------------------------------------------------------------------
// k_prepw: bf16-transpose 6 weight matrices [k][n] -> [n][k].
// tid: which = tid>>14 (0..5), r = tid&16383, k = r>>7, n = r&127.
// ---------------------------------------------------------------------------
__global__ void k_prepw(const float* __restrict__ w0, const float* __restrict__ w1,
                        const float* __restrict__ w2, const float* __restrict__ w3,
                        const float* __restrict__ w4, const float* __restrict__ w5,
                        short* __restrict__ o0, short* __restrict__ o1,
                        short* __restrict__ o2, short* __restrict__ o3,
                        short* __restrict__ o4, short* __restrict__ o5) {
    int tid = blockIdx.x * blockDim.x + threadIdx.x;
    if (tid >= 6 * 16384) return;
    int which = tid >> 14;
    int r = tid & 16383;
    int k = r >> 7, nn = r & 127;
    const float* w = (which == 0) ? w0 : (which == 1) ? w1 : (which == 2) ? w2
                   : (which == 3) ? w3 : (which == 4) ? w4 : w5;
    short* o = (which == 0) ? o0 : (which == 1) ? o1 : (which == 2) ? o2
             : (which == 3) ? o3 : (which == 4) ? o4 : o5;
    o[nn * 128 + k] = f2b(w[k * 128 + nn]);
}

// ---------------------------------------------------------------------------
// Sort-by-dst: histogram -> scan -> scatter (src + packed attr).
// ---------------------------------------------------------------------------
__global__ void k_hist(const int* __restrict__ edge_index, int* __restrict__ counts, int E) {
    int e = blockIdx.x * blockDim.x + threadIdx.x;
    if (e >= E) return;
    atomicAdd(&counts[edge_index[E + e]], 1);
}

__global__ void k_scan(const int* __restrict__ counts, int* __restrict__ offsets,
                       int* __restrict__ cursor, int n) {
    __shared__ int sdata[1024];
    int t = threadIdx.x;
    int chunk = (n + 1023) >> 10;
    int lo = t * chunk;
    int hi = min(n, lo + chunk);
    int s = 0;
    for (int i = lo; i < hi; ++i) s += counts[i];
    sdata[t] = s;
    __syncthreads();
    for (int d = 1; d < 1024; d <<= 1) {
        int v = (t >= d) ? sdata[t - d] : 0;
        __syncthreads();
        sdata[t] += v;
        __syncthreads();
    }
    int run = (t == 0) ? 0 : sdata[t - 1];
    for (int i = lo; i < hi; ++i) {
        offsets[i] = run;
        cursor[i]  = run;
        run += counts[i];
    }
    if (t == 1023) offsets[n] = sdata[1023];
}

__global__ void k_scatter(const int* __restrict__ edge_index, const int* __restrict__ edge_attr,
                          int* __restrict__ cursor,
                          int* __restrict__ s_src, unsigned* __restrict__ s_att, int E) {
    int e = blockIdx.x * blockDim.x + threadIdx.x;
    if (e >= E) return;
    int src = edge_index[e];
    int dst = edge_index[E + e];
    int4 at = ((const int4*)edge_attr)[e];
    unsigned pack = (unsigned)at.x | ((unsigned)at.y << 8) | ((unsigned)at.z << 16) | ((unsigned)at.w << 24);
    int pos = atomicAdd(&cursor[dst], 1);
    s_src[pos] = src;
    s_att[pos] = pack;
}

// ---------------------------------------------------------------------------
// k_gemm1 (MFMA): xxb = bf16( LN( x @ pre_w + pre_b ) ).
// Block 256 = 4 waves; wave handles 16 rows x 128 cols (8 16x16 tiles).
// A-frag: lane holds A[m=lane&15][k=quad*8+j]; B-frag from preT[n][k] rows.
// C/D layout: col=lane&15, row=quad*4+reg. LN done in-register: each quad's
// 16 lanes hold a full 128-col row per reg -> shfl_xor(1,2,4,8) stats.
// ---------------------------------------------------------------------------
__global__ void __launch_bounds__(256) k_gemm1(
        const float* __restrict__ x, const short* __restrict__ preT,
        const float* __restrict__ pre_b, short* __restrict__ xxb, int n) {
    int w    = threadIdx.x >> 6;
    int lane = threadIdx.x & 63;
    int quad = lane >> 4, l16 = lane & 15;
    int m0 = blockIdx.x * 64 + w * 16;
    int mA = min(m0 + l16, n - 1);

    bf16x8 a[4];
#pragma unroll
    for (int kc = 0; kc < 4; ++kc) {
        const float* px = x + (size_t)mA * WIDTH + kc * 32 + quad * 8;
        float4 f0 = *(const float4*)(px);
        float4 f1 = *(const float4*)(px + 4);
        bf16x8 av;
        av[0] = f2b(f0.x); av[1] = f2b(f0.y); av[2] = f2b(f0.z); av[3] = f2b(f0.w);
        av[4] = f2b(f1.x); av[5] = f2b(f1.y); av[6] = f2b(f1.z); av[7] = f2b(f1.w);
        a[kc] = av;
    }

    f32x4 acc[8];
#pragma unroll
    for (int t = 0; t < 8; ++t) acc[t] = (f32x4){0.f, 0.f, 0.f, 0.f};
#pragma unroll
    for (int kc = 0; kc < 4; ++kc) {
#pragma unroll
        for (int t = 0; t < 8; ++t) {
            bf16x8 b = *(const bf16x8*)(preT + (t * 16 + l16) * 128 + kc * 32 + quad * 8);
            acc[t] = __builtin_amdgcn_mfma_f32_16x16x32_bf16(a[kc], b, acc[t], 0, 0, 0);
        }
    }
#pragma unroll
    for (int t = 0; t < 8; ++t) {
        float bv = pre_b[t * 16 + l16];
#pragma unroll
        for (int r = 0; r < 4; ++r) acc[t][r] += bv;
    }
    // in-register LayerNorm per output row (quad*4 + r)
#pragma unroll
    for (int r = 0; r < 4; ++r) {
        float s = 0.f, s2 = 0.f;
#pragma unroll
        for (int t = 0; t < 8; ++t) { float v = acc[t][r]; s += v; s2 += v * v; }
        s  += __shfl_xor(s, 1);  s2 += __shfl_xor(s2, 1);
        s  += __shfl_xor(s, 2);  s2 += __shfl_xor(s2, 2);
        s  += __shfl_xor(s, 4);  s2 += __shfl_xor(s2, 4);
        s  += __shfl_xor(s, 8);  s2 += __shfl_xor(s2, 8);
        float m   = s * (1.0f / WIDTH);
        float var = s2 * (1.0f / WIDTH) - m * m;
        float rs  = rsqrtf(var + 1e-5f);
#pragma unroll
        for (int t = 0; t < 8; ++t) acc[t][r] = (acc[t][r] - m) * rs;
    }
    int mD = m0 + quad * 4;
#pragma unroll
    for (int r = 0; r < 4; ++r) {
        if (mD + r < n) {
#pragma unroll
            for (int t = 0; t < 8; ++t)
                xxb[(size_t)(mD + r) * WIDTH + t * 16 + l16] = f2b(acc[t][r]);
        }
    }
}

// ---------------------------------------------------------------------------
// k_gemm2 (MFMA): from xxb compute
//   G  = gelu(xx@w0 + b0)   (f32)
//   Cb = bf16(xx@w3 + b3)   (bf16 - gathered by k_agg)
// and, when scal[0] != 0:  A = xx@w1 + b1 (f32), Bb = bf16(xx@w2 + b2).
// ---------------------------------------------------------------------------
__global__ void __launch_bounds__(256) k_gemm2(
        const short* __restrict__ xxb,
        const short* __restrict__ w0T, const float* __restrict__ b0,
        const short* __restrict__ w1T, const float* __restrict__ b1,
        const short* __restrict__ w2T, const float* __restrict__ b2,
        const short* __restrict__ w3T, const float* __restrict__ b3,
        const float* __restrict__ scal,
        float* __restrict__ G, float* __restrict__ A,
        short* __restrict__ Bb, short* __restrict__ Cb, int n) {
    int w    = threadIdx.x >> 6;
    int lane = threadIdx.x & 63;
    int quad = lane >> 4, l16 = lane & 15;
    int m0 = blockIdx.x * 64 + w * 16;
    int mA = min(m0 + l16, n - 1);
    int mD = m0 + quad * 4;

    bf16x8 a[4];
#pragma unroll
    for (int kc = 0; kc < 4; ++kc)
        a[kc] = *(const bf16x8*)(xxb + (size_t)mA * WIDTH + kc * 32 + quad * 8);

    {
        f32x4 accG[8], accC[8];
#pragma unroll
        for (int t = 0; t < 8; ++t) { accG[t] = (f32x4){0.f,0.f,0.f,0.f}; accC[t] = (f32x4){0.f,0.f,0.f,0.f}; }
#pragma unroll
        for (int kc = 0; kc < 4; ++kc) {
#pragma unroll
            for (int t = 0; t < 8; ++t) {
                bf16x8 bg = *(const bf16x8*)(w0T + (t * 16 + l16) * 128 + kc * 32 + quad * 8);
                accG[t] = __builtin_amdgcn_mfma_f32_16x16x32_bf16(a[kc], bg, accG[t], 0, 0, 0);
                bf16x8 bc = *(const bf16x8*)(w3T + (t * 16 + l16) * 128 + kc * 32 + quad * 8);
                accC[t] = __builtin_amdgcn_mfma_f32_16x16x32_bf16(a[kc], bc, accC[t], 0, 0, 0);
            }
        }
#pragma unroll
        for (int t = 0; t < 8; ++t) {
            float bg = b0[t * 16 + l16];
            float bc = b3[t * 16 + l16];
#pragma unroll
            for (int r = 0; r < 4; ++r) {
                if (mD + r < n) {
                    size_t idx = (size_t)(mD + r) * WIDTH + t * 16 + l16;
                    G[idx]  = gelu_f(accG[t][r] + bg);
                    Cb[idx] = f2b(accC[t][r] + bc);
                }
            }
        }
    }
    if (scal[0] != 0.0f) {
        f32x4 accA[8], accB[8];
#pragma unroll
        for (int t = 0; t < 8; ++t) { accA[t] = (f32x4){0.f,0.f,0.f,0.f}; accB[t] = (f32x4){0.f,0.f,0.f,0.f}; }
#pragma unroll
        for (int kc = 0; kc < 4; ++kc) {
#pragma unroll
            for (int t = 0; t < 8; ++t) {
                bf16x8 ba = *(const bf16x8*)(w1T + (t * 16 + l16) * 128 + kc * 32 + quad * 8);
                accA[t] = __builtin_amdgcn_mfma_f32_16x16x32_bf16(a[kc], ba, accA[t], 0, 0, 0);
                bf16x8 bb = *(const bf16x8*)(w2T + (t * 16 + l16) * 128 + kc * 32 + quad * 8);
                accB[t] = __builtin_amdgcn_mfma_f32_16x16x32_bf16(a[kc], bb, accB[t], 0, 0, 0);
            }
        }
#pragma unroll
        for (int t = 0; t < 8; ++t) {
            float ba = b1[t * 16 + l16];
            float bb = b2[t * 16 + l16];
#pragma unroll
            for (int r = 0; r < 4; ++r) {
                if (mD + r < n) {
                    size_t idx = (size_t)(mD + r) * WIDTH + t * 16 + l16;
                    A[idx]  = accA[t][r] + ba;
                    Bb[idx] = f2b(accB[t][r] + bb);
                }
            }
        }
    }
}

// ---------------------------------------------------------------------------
// k_agg: per-node aggregation over dst-sorted edges + fuse h = G + agg.
// Fast path (scal[0]==0): att = exp(scal[1]) constant -> v-only, Cb gather.
// ---------------------------------------------------------------------------
__global__ void __launch_bounds__(128)
k_agg(const int* __restrict__ offsets, const int* __restrict__ s_src,
      const unsigned* __restrict__ s_att,
      const float* __restrict__ A, const short* __restrict__ Bb,
      const short* __restrict__ Cb, const float* __restrict__ U,
      const float* __restrict__ scal, const float* __restrict__ G,
      float* __restrict__ h, int n) {
    int node = blockIdx.x;
    int c = threadIdx.x;
    int start = offsets[node];
    int end   = offsets[node + 1];

    const float* U0 = U;
    const float* U1 = U + 34 * WIDTH;
    const float* U2 = U + 2 * 34 * WIDTH;

    float i0 = scal[0], i1 = scal[1];
    float acc = 0.0f;

    if (i0 == 0.0f) {
        for (int p = start; p < end; ++p) {
            int src = s_src[p];
            unsigned pk = s_att[p];
            int r0 = (int)(pk & 255u) << 7;
            int r1 = (int)(6u  + ((pk >> 8)  & 255u)) << 7;
            int r2 = (int)(13u + ((pk >> 16) & 255u)) << 7;
            int r3 = (int)(16u + (pk >> 24)) << 7;
            float cv = b2f(((const unsigned short*)Cb)[(size_t)src * WIDTH + c]);
            float u  = U2[r0 + c] + U2[r1 + c] + U2[r2 + c] + U2[r3 + c];
            acc += gelu_f(cv + u);
        }
        acc *= expf(i1);
    } else {
        float av = A[(size_t)node * WIDTH + c];
        for (int p = start; p < end; ++p) {
            int src = s_src[p];
            unsigned pk = s_att[p];
            int r0 = (int)(pk & 255u) << 7;
            int r1 = (int)(6u  + ((pk >> 8)  & 255u)) << 7;
            int r2 = (int)(13u + ((pk >> 16) & 255u)) << 7;
            int r3 = (int)(16u + (pk >> 24)) << 7;

            float q  = av + U0[r0 + c] + U0[r1 + c] + U0[r2 + c] + U0[r3 + c];
            float kk = b2f(((const unsigned short*)Bb)[(size_t)src * WIDTH + c])
                       + U1[r0 + c] + U1[r1 + c] + U1[r2 + c] + U1[r3 + c];
            float vv = gelu_f(b2f(((const unsigned short*)Cb)[(size_t)src * WIDTH + c])
                       + U2[r0 + c] + U2[r1 + c] + U2[r2 + c] + U2[r3 + c]);

            float s = q * kk;
            s += __shfl_xor(s, 1);
            s += __shfl_xor(s, 2);
            s += __shfl_xor(s, 4);
            s += __shfl_xor(s, 8);
            s += __shfl_xor(s, 16);
            s += __shfl_xor(s, 32);

            acc += vv * expf(s * 0.125f * i0 + i1);
        }
    }
    size_t idx = (size_t)node * WIDTH + c;
    h[idx] = G[idx] + acc;
}

// ---------------------------------------------------------------------------
// k_post (MFMA): out = x + h @ post_w + post_b.
// ---------------------------------------------------------------------------
__global__ void __launch_bounds__(256) k_post(
        const float* __restrict__ x, const float* __restrict__ h,
        const short* __restrict__ postT, const float* __restrict__ post_b,
        float* __restrict__ out, int n) {
    int w    = threadIdx.x >> 6;
    int lane = threadIdx.x & 63;
    int quad = lane >> 4, l16 = lane & 15;
    int m0 = blockIdx.x * 64 + w * 16;
    int mA = min(m0 + l16, n - 1);
    int mD = m0 + quad * 4;

    bf16x8 a[4];
#pragma unroll
    for (int kc = 0; kc < 4; ++kc) {
        const float* ph = h + (size_t)mA * WIDTH + kc * 32 + quad * 8;
        float4 f0 = *(const float4*)(ph);
        float4 f1 = *(const float4*)(ph + 4);
        bf16x8 av;
        av[0] = f2b(f0.x); av[1] = f2b(f0.y); av[2] = f2b(f0.z); av[3] = f2b(f0.w);
        av[4] = f2b(f1.x); av[5] = f2b(f1.y); av[6] = f2b(f1.z); av[7] = f2b(f1.w);
        a[kc] = av;
    }

    f32x4 acc[8];
#pragma unroll
    for (int t = 0; t < 8; ++t) acc[t] = (f32x4){0.f, 0.f, 0.f, 0.f};
#pragma unroll
    for (int kc = 0; kc < 4; ++kc) {
#pragma unroll
        for (int t = 0; t < 8; ++t) {
            bf16x8 b = *(const bf16x8*)(postT + (t * 16 + l16) * 128 + kc * 32 + quad * 8);
            acc[t] = __builtin_amdgcn_mfma_f32_16x16x32_bf16(a[kc], b, acc[t], 0, 0, 0);
        }
    }
#pragma unroll
    for (int t = 0; t < 8; ++t) {
        float bv = post_b[t * 16 + l16];
#pragma unroll
        for (int r = 0; r < 4; ++r) {
            if (mD + r < n) {
                size_t idx = (size_t)(mD + r) * WIDTH + t * 16 + l16;
                out[idx] = x[idx] + acc[t][r] + bv;
            }
        }
    }
}

extern "C" void kernel_launch(void* const* d_in, const int* in_sizes, int n_in,
                              void* d_out, int out_size, void* d_ws, size_t ws_size,
                              hipStream_t stream) {
    const float* x      = (const float*)d_in[0];
    const int*   eidx   = (const int*)d_in[1];
    const int*   eattr  = (const int*)d_in[2];
    const float* pre_w  = (const float*)d_in[3];
    const float* pre_b  = (const float*)d_in[4];
    const float* msg0_w = (const float*)d_in[5];
    const float* msg0_b = (const float*)d_in[6];
    const float* msg1_w = (const float*)d_in[7];
    const float* msg1_b = (const float*)d_in[8];
    const float* msg2_w = (const float*)d_in[9];
    const float* msg2_b = (const float*)d_in[10];
    const float* msg3_w = (const float*)d_in[11];
    const float* msg3_b = (const float*)d_in[12];
    const float* r0w    = (const float*)d_in[13];
    const float* r0b    = (const float*)d_in[14];
    const float* r1w    = (const float*)d_in[15];
    const float* r1b    = (const float*)d_in[16];
    const float* r2w    = (const float*)d_in[17];
    const float* r2b    = (const float*)d_in[18];
    const float* post_w = (const float*)d_in[19];
    const float* post_b = (const float*)d_in[20];
    const float* emb0   = (const float*)d_in[21];
    const float* emb1   = (const float*)d_in[22];
    const float* emb2   = (const float*)d_in[23];
    const float* emb3   = (const float*)d_in[24];
    const float* einit  = (const float*)d_in[25];
    const float* init0  = (const float*)d_in[26];

    int n = in_sizes[0] / WIDTH;
    int E = in_sizes[2] / 4;
    size_t NW = (size_t)n * WIDTH;

    float* ws   = (float*)d_ws;
    float* A    = ws;                 // [N,128] f32 (full path only)
    float* G    = ws + NW;            // [N,128] f32
    float* h    = ws + 2 * NW;        // [N,128] f32  (G + agg)
    float* U    = ws + 3 * NW;        // [3][34][128]
    float* scal = U + 3 * 34 * WIDTH; // [2]
    short* sw   = (short*)(scal + 2);
    short* preT  = sw;                // 6 x [128][128] bf16 transposed weights
    short* w0T   = sw + 16384;
    short* w1T   = sw + 2 * 16384;
    short* w2T   = sw + 3 * 16384;
    short* w3T   = sw + 4 * 16384;
    short* postT = sw + 5 * 16384;
    short* xxb   = sw + 6 * 16384;    // [N,128] bf16
    short* Bb    = xxb + NW;          // [N,128] bf16 (full path only)
    short* Cb    = Bb + NW;           // [N,128] bf16
    int*      ib      = (int*)(Cb + NW);
    int*      offsets = ib;                       // n+1
    int*      cursor  = offsets + (n + 1);        // n
    int*      counts  = cursor + n;               // n
    int*      s_src   = counts + n;               // E
    unsigned* s_att   = (unsigned*)(s_src + E);   // E

    k_prepw<<<384, 256, 0, stream>>>(pre_w, msg0_w, msg1_w, msg2_w, msg3_w, post_w,
                                     preT, w0T, w1T, w2T, w3T, postT);
    k_prep<<<52, 256, 0, stream>>>(einit, init0, emb0, emb1, emb2, emb3,
                                   r0w, r0b, r1w, r1b, r2w, r2b, U, scal);

    hipMemsetAsync(counts, 0, (size_t)n * sizeof(int), stream);
    int eb = (E + 255) / 256;
    k_hist<<<eb, 256, 0, stream>>>(eidx, counts, E);
    k_scan<<<1, 1024, 0, stream>>>(counts, offsets, cursor, n);
    k_scatter<<<eb, 256, 0, stream>>>(eidx, eattr, cursor, s_src, s_att, E);

    int gb = (n + 63) / 64;
    k_gemm1<<<gb, 256, 0, stream>>>(x, preT, pre_b, xxb, n);
    k_gemm2<<<gb, 256, 0, stream>>>(xxb, w0T, msg0_b, w1T, msg1_b, w2T, msg2_b,
                                    w3T, msg3_b, scal, G, A, Bb, Cb, n);
    k_agg<<<n, WIDTH, 0, stream>>>(offsets, s_src, s_att, A, Bb, Cb, U, scal, G, h, n);
    k_post<<<gb, 256, 0, stream>>>(x, h, postT, post_b, (float*)d_out, n);
}

// Round 5
// 373.967 us; speedup vs baseline: 3.4891x; 1.2704x over previous
//
#include <hip/hip_runtime.h>
#include <cstdint>

#define WIDTH 128

typedef short bf16x8 __attribute__((ext_vector_type(8)));
typedef float f32x4  __attribute__((ext_vector_type(4)));

__device__ __forceinline__ float gelu_f(float v) {
    return 0.5f * v * (1.0f + erff(v * 0.70710678118654752f));
}
__device__ __forceinline__ short f2b(float f) {
    unsigned u = __float_as_uint(f);
    unsigned r = (u + 0x7FFFu + ((u >> 16) & 1u)) >> 16;
    return (short)r;
}
__device__ __forceinline__ float b2f(unsigned short s) {
    return __uint_as_float(((unsigned)s) << 16);
}

// ---------------------------------------------------------------------------
// k_prep: scalars + transformed embedding tables U (grid-stride, 52 blocks).
// U layout: [3 remix][34 rows][128 cols]; rows: emb0 0..5, emb1 6..12,
// emb2 13..15, emb3 16..33.
// ---------------------------------------------------------------------------
__global__ void k_prep(const float* __restrict__ einit, const float* __restrict__ init0,
                       const float* __restrict__ emb0, const float* __restrict__ emb1,
                       const float* __restrict__ emb2, const float* __restrict__ emb3,
                       const float* __restrict__ r0w, const float* __restrict__ r0b,
                       const float* __restrict__ r1w, const float* __restrict__ r1b,
                       const float* __restrict__ r2w, const float* __restrict__ r2b,
                       float* __restrict__ U, float* __restrict__ scal) {
    float e0 = expf(einit[0]), e1 = expf(einit[1]), e2 = expf(einit[2]), e3 = expf(einit[3]);
    float inv = 1.0f / sqrtf(e0 + e1 + e2 + e3);
    float xw[4] = {e0 * inv, e1 * inv, e2 * inv, e3 * inv};
    float se = expf(init0[2]);
    float sv = expf(init0[3]);
    int tid = blockIdx.x * blockDim.x + threadIdx.x;
    if (tid == 0) { scal[0] = init0[0]; scal[1] = init0[1]; }

    const int total = 3 * 34 * WIDTH;
    for (int idx = tid; idx < total; idx += gridDim.x * blockDim.x) {
        int r   = idx / (34 * WIDTH);
        int rem = idx - r * (34 * WIDTH);
        int g   = rem / WIDTH;
        int j   = rem - g * WIDTH;
        int cc, base;
        if (g >= 16)      { cc = 3; base = 16; }
        else if (g >= 13) { cc = 2; base = 13; }
        else if (g >= 6)  { cc = 1; base = 6; }
        else              { cc = 0; base = 0; }
        int i = g - base;
        const float* em = (cc == 0) ? emb0 : (cc == 1) ? emb1 : (cc == 2) ? emb2 : emb3;
        const float* w  = (r == 0) ? r0w : (r == 1) ? r1w : r2w;
        const float* rb = (r == 0) ? r0b : (r == 1) ? r1b : r2b;
        float s = (r == 2) ? sv : se;
        float acc = 0.0f;
        const float* erow = em + i * 64;
        for (int d = 0; d < 64; ++d) acc += erow[d] * w[d * WIDTH + j];
        float val = s * xw[cc] * acc;
        if (cc == 0) val += s * rb[j];
        U[idx] = val;
    }
}

// ---------------------------------------------------------------------------
// k_prepw: bf16-transpose 6 weight matrices [k][n] -> [n][k].
// ---------------------------------------------------------------------------
__global__ void k_prepw(const float* __restrict__ w0, const float* __restrict__ w1,
                        const float* __restrict__ w2, const float* __restrict__ w3,
                        const float* __restrict__ w4, const float* __restrict__ w5,
                        short* __restrict__ o0, short* __restrict__ o1,
                        short* __restrict__ o2, short* __restrict__ o3,
                        short* __restrict__ o4, short* __restrict__ o5) {
    int tid = blockIdx.x * blockDim.x + threadIdx.x;
    if (tid >= 6 * 16384) return;
    int which = tid >> 14;
    int r = tid & 16383;
    int k = r >> 7, nn = r & 127;
    const float* w = (which == 0) ? w0 : (which == 1) ? w1 : (which == 2) ? w2
                   : (which == 3) ? w3 : (which == 4) ? w4 : w5;
    short* o = (which == 0) ? o0 : (which == 1) ? o1 : (which == 2) ? o2
             : (which == 3) ? o3 : (which == 4) ? o4 : o5;
    o[nn * 128 + k] = f2b(w[k * 128 + nn]);
}

// ---------------------------------------------------------------------------
// Sort-by-dst: histogram -> 3-phase parallel scan -> scatter.
// ---------------------------------------------------------------------------
__global__ void k_hist(const int* __restrict__ edge_index, int* __restrict__ counts, int E) {
    int e = blockIdx.x * blockDim.x + threadIdx.x;
    if (e >= E) return;
    atomicAdd(&counts[edge_index[E + e]], 1);
}

// Phase 1: block-local inclusive scan of 256 counts + block total.
__global__ void k_scan1(const int* __restrict__ counts, int* __restrict__ lscan,
                        int* __restrict__ partials, int n) {
    __shared__ int s[256];
    int t = threadIdx.x;
    int i = blockIdx.x * 256 + t;
    int v = (i < n) ? counts[i] : 0;
    s[t] = v;
    __syncthreads();
    for (int d = 1; d < 256; d <<= 1) {
        int u = (t >= d) ? s[t - d] : 0;
        __syncthreads();
        s[t] += u;
        __syncthreads();
    }
    if (i < n) lscan[i] = s[t];
    if (t == 255) partials[blockIdx.x] = s[255];
}

// Phase 2: single block exclusive-scans block totals (nb <= 1024); total -> offsets[n].
__global__ void k_scan2(int* __restrict__ partials, int nb,
                        int* __restrict__ offsets, int n) {
    __shared__ int s[1024];
    int t = threadIdx.x;
    int v = (t < nb) ? partials[t] : 0;
    s[t] = v;
    __syncthreads();
    for (int d = 1; d < 1024; d <<= 1) {
        int u = (t >= d) ? s[t - d] : 0;
        __syncthreads();
        s[t] += u;
        __syncthreads();
    }
    if (t < nb) partials[t] = s[t] - v;   // exclusive prefix of block totals
    if (t == 1023) offsets[n] = s[1023];  // grand total
}

// Phase 3: combine -> offsets/cursor (exclusive global scan).
__global__ void k_scan3(const int* __restrict__ counts, const int* __restrict__ lscan,
                        const int* __restrict__ partials,
                        int* __restrict__ offsets, int* __restrict__ cursor, int n) {
    int i = blockIdx.x * 256 + threadIdx.x;
    if (i >= n) return;
    int off = partials[blockIdx.x] + lscan[i] - counts[i];
    offsets[i] = off;
    cursor[i]  = off;
}

__global__ void k_scatter(const int* __restrict__ edge_index, const int* __restrict__ edge_attr,
                          int* __restrict__ cursor,
                          int* __restrict__ s_src, unsigned* __restrict__ s_att, int E) {
    int e = blockIdx.x * blockDim.x + threadIdx.x;
    if (e >= E) return;
    int src = edge_index[e];
    int dst = edge_index[E + e];
    int4 at = ((const int4*)edge_attr)[e];
    unsigned pack = (unsigned)at.x | ((unsigned)at.y << 8) | ((unsigned)at.z << 16) | ((unsigned)at.w << 24);
    int pos = atomicAdd(&cursor[dst], 1);
    s_src[pos] = src;
    s_att[pos] = pack;
}

// ---------------------------------------------------------------------------
// k_gemm1 (MFMA): xxb = bf16( LN( x @ pre_w + pre_b ) ).
// ---------------------------------------------------------------------------
__global__ void __launch_bounds__(256) k_gemm1(
        const float* __restrict__ x, const short* __restrict__ preT,
        const float* __restrict__ pre_b, short* __restrict__ xxb, int n) {
    int w    = threadIdx.x >> 6;
    int lane = threadIdx.x & 63;
    int quad = lane >> 4, l16 = lane & 15;
    int m0 = blockIdx.x * 64 + w * 16;
    int mA = min(m0 + l16, n - 1);

    bf16x8 a[4];
#pragma unroll
    for (int kc = 0; kc < 4; ++kc) {
        const float* px = x + (size_t)mA * WIDTH + kc * 32 + quad * 8;
        float4 f0 = *(const float4*)(px);
        float4 f1 = *(const float4*)(px + 4);
        bf16x8 av;
        av[0] = f2b(f0.x); av[1] = f2b(f0.y); av[2] = f2b(f0.z); av[3] = f2b(f0.w);
        av[4] = f2b(f1.x); av[5] = f2b(f1.y); av[6] = f2b(f1.z); av[7] = f2b(f1.w);
        a[kc] = av;
    }

    f32x4 acc[8];
#pragma unroll
    for (int t = 0; t < 8; ++t) acc[t] = (f32x4){0.f, 0.f, 0.f, 0.f};
#pragma unroll
    for (int kc = 0; kc < 4; ++kc) {
#pragma unroll
        for (int t = 0; t < 8; ++t) {
            bf16x8 b = *(const bf16x8*)(preT + (t * 16 + l16) * 128 + kc * 32 + quad * 8);
            acc[t] = __builtin_amdgcn_mfma_f32_16x16x32_bf16(a[kc], b, acc[t], 0, 0, 0);
        }
    }
#pragma unroll
    for (int t = 0; t < 8; ++t) {
        float bv = pre_b[t * 16 + l16];
#pragma unroll
        for (int r = 0; r < 4; ++r) acc[t][r] += bv;
    }
#pragma unroll
    for (int r = 0; r < 4; ++r) {
        float s = 0.f, s2 = 0.f;
#pragma unroll
        for (int t = 0; t < 8; ++t) { float v = acc[t][r]; s += v; s2 += v * v; }
        s  += __shfl_xor(s, 1);  s2 += __shfl_xor(s2, 1);
        s  += __shfl_xor(s, 2);  s2 += __shfl_xor(s2, 2);
        s  += __shfl_xor(s, 4);  s2 += __shfl_xor(s2, 4);
        s  += __shfl_xor(s, 8);  s2 += __shfl_xor(s2, 8);
        float m   = s * (1.0f / WIDTH);
        float var = s2 * (1.0f / WIDTH) - m * m;
        float rs  = rsqrtf(var + 1e-5f);
#pragma unroll
        for (int t = 0; t < 8; ++t) acc[t][r] = (acc[t][r] - m) * rs;
    }
    int mD = m0 + quad * 4;
#pragma unroll
    for (int r = 0; r < 4; ++r) {
        if (mD + r < n) {
#pragma unroll
            for (int t = 0; t < 8; ++t)
                xxb[(size_t)(mD + r) * WIDTH + t * 16 + l16] = f2b(acc[t][r]);
        }
    }
}

// ---------------------------------------------------------------------------
// k_gemm2 (MFMA): G = gelu(xx@w0+b0) f32, Cb = bf16(xx@w3+b3);
// full path adds A = xx@w1+b1 f32, Bb = bf16(xx@w2+b2).
// ---------------------------------------------------------------------------
__global__ void __launch_bounds__(256) k_gemm2(
        const short* __restrict__ xxb,
        const short* __restrict__ w0T, const float* __restrict__ b0,
        const short* __restrict__ w1T, const float* __restrict__ b1,
        const short* __restrict__ w2T, const float* __restrict__ b2,
        const short* __restrict__ w3T, const float* __restrict__ b3,
        const float* __restrict__ scal,
        float* __restrict__ G, float* __restrict__ A,
        short* __restrict__ Bb, short* __restrict__ Cb, int n) {
    int w    = threadIdx.x >> 6;
    int lane = threadIdx.x & 63;
    int quad = lane >> 4, l16 = lane & 15;
    int m0 = blockIdx.x * 64 + w * 16;
    int mA = min(m0 + l16, n - 1);
    int mD = m0 + quad * 4;

    bf16x8 a[4];
#pragma unroll
    for (int kc = 0; kc < 4; ++kc)
        a[kc] = *(const bf16x8*)(xxb + (size_t)mA * WIDTH + kc * 32 + quad * 8);

    {
        f32x4 accG[8], accC[8];
#pragma unroll
        for (int t = 0; t < 8; ++t) { accG[t] = (f32x4){0.f,0.f,0.f,0.f}; accC[t] = (f32x4){0.f,0.f,0.f,0.f}; }
#pragma unroll
        for (int kc = 0; kc < 4; ++kc) {
#pragma unroll
            for (int t = 0; t < 8; ++t) {
                bf16x8 bg = *(const bf16x8*)(w0T + (t * 16 + l16) * 128 + kc * 32 + quad * 8);
                accG[t] = __builtin_amdgcn_mfma_f32_16x16x32_bf16(a[kc], bg, accG[t], 0, 0, 0);
                bf16x8 bc = *(const bf16x8*)(w3T + (t * 16 + l16) * 128 + kc * 32 + quad * 8);
                accC[t] = __builtin_amdgcn_mfma_f32_16x16x32_bf16(a[kc], bc, accC[t], 0, 0, 0);
            }
        }
#pragma unroll
        for (int t = 0; t < 8; ++t) {
            float bg = b0[t * 16 + l16];
            float bc = b3[t * 16 + l16];
#pragma unroll
            for (int r = 0; r < 4; ++r) {
                if (mD + r < n) {
                    size_t idx = (size_t)(mD + r) * WIDTH + t * 16 + l16;
                    G[idx]  = gelu_f(accG[t][r] + bg);
                    Cb[idx] = f2b(accC[t][r] + bc);
                }
            }
        }
    }
    if (scal[0] != 0.0f) {
        f32x4 accA[8], accB[8];
#pragma unroll
        for (int t = 0; t < 8; ++t) { accA[t] = (f32x4){0.f,0.f,0.f,0.f}; accB[t] = (f32x4){0.f,0.f,0.f,0.f}; }
#pragma unroll
        for (int kc = 0; kc < 4; ++kc) {
#pragma unroll
            for (int t = 0; t < 8; ++t) {
                bf16x8 ba = *(const bf16x8*)(w1T + (t * 16 + l16) * 128 + kc * 32 + quad * 8);
                accA[t] = __builtin_amdgcn_mfma_f32_16x16x32_bf16(a[kc], ba, accA[t], 0, 0, 0);
                bf16x8 bb = *(const bf16x8*)(w2T + (t * 16 + l16) * 128 + kc * 32 + quad * 8);
                accB[t] = __builtin_amdgcn_mfma_f32_16x16x32_bf16(a[kc], bb, accB[t], 0, 0, 0);
            }
        }
#pragma unroll
        for (int t = 0; t < 8; ++t) {
            float ba = b1[t * 16 + l16];
            float bb = b2[t * 16 + l16];
#pragma unroll
            for (int r = 0; r < 4; ++r) {
                if (mD + r < n) {
                    size_t idx = (size_t)(mD + r) * WIDTH + t * 16 + l16;
                    A[idx]  = accA[t][r] + ba;
                    Bb[idx] = f2b(accB[t][r] + bb);
                }
            }
        }
    }
}

// ---------------------------------------------------------------------------
// k_agg: per-node aggregation over dst-sorted edges + fuse h = G + agg.
// ---------------------------------------------------------------------------
__global__ void __launch_bounds__(128)
k_agg(const int* __restrict__ offsets, const int* __restrict__ s_src,
      const unsigned* __restrict__ s_att,
      const float* __restrict__ A, const short* __restrict__ Bb,
      const short* __restrict__ Cb, const float* __restrict__ U,
      const float* __restrict__ scal, const float* __restrict__ G,
      float* __restrict__ h, int n) {
    int node = blockIdx.x;
    int c = threadIdx.x;
    int start = offsets[node];
    int end   = offsets[node + 1];

    const float* U0 = U;
    const float* U1 = U + 34 * WIDTH;
    const float* U2 = U + 2 * 34 * WIDTH;

    float i0 = scal[0], i1 = scal[1];
    float acc = 0.0f;

    if (i0 == 0.0f) {
        for (int p = start; p < end; ++p) {
            int src = s_src[p];
            unsigned pk = s_att[p];
            int r0 = (int)(pk & 255u) << 7;
            int r1 = (int)(6u  + ((pk >> 8)  & 255u)) << 7;
            int r2 = (int)(13u + ((pk >> 16) & 255u)) << 7;
            int r3 = (int)(16u + (pk >> 24)) << 7;
            float cv = b2f(((const unsigned short*)Cb)[(size_t)src * WIDTH + c]);
            float u  = U2[r0 + c] + U2[r1 + c] + U2[r2 + c] + U2[r3 + c];
            acc += gelu_f(cv + u);
        }
        acc *= expf(i1);
    } else {
        float av = A[(size_t)node * WIDTH + c];
        for (int p = start; p < end; ++p) {
            int src = s_src[p];
            unsigned pk = s_att[p];
            int r0 = (int)(pk & 255u) << 7;
            int r1 = (int)(6u  + ((pk >> 8)  & 255u)) << 7;
            int r2 = (int)(13u + ((pk >> 16) & 255u)) << 7;
            int r3 = (int)(16u + (pk >> 24)) << 7;

            float q  = av + U0[r0 + c] + U0[r1 + c] + U0[r2 + c] + U0[r3 + c];
            float kk = b2f(((const unsigned short*)Bb)[(size_t)src * WIDTH + c])
                       + U1[r0 + c] + U1[r1 + c] + U1[r2 + c] + U1[r3 + c];
            float vv = gelu_f(b2f(((const unsigned short*)Cb)[(size_t)src * WIDTH + c])
                       + U2[r0 + c] + U2[r1 + c] + U2[r2 + c] + U2[r3 + c]);

            float s = q * kk;
            s += __shfl_xor(s, 1);
            s += __shfl_xor(s, 2);
            s += __shfl_xor(s, 4);
            s += __shfl_xor(s, 8);
            s += __shfl_xor(s, 16);
            s += __shfl_xor(s, 32);

            acc += vv * expf(s * 0.125f * i0 + i1);
        }
    }
    size_t idx = (size_t)node * WIDTH + c;
    h[idx] = G[idx] + acc;
}

// ---------------------------------------------------------------------------
// k_post (MFMA): out = x + h @ post_w + post_b.
// ---------------------------------------------------------------------------
__global__ void __launch_bounds__(256) k_post(
        const float* __restrict__ x, const float* __restrict__ h,
        const short* __restrict__ postT, const float* __restrict__ post_b,
        float* __restrict__ out, int n) {
    int w    = threadIdx.x >> 6;
    int lane = threadIdx.x & 63;
    int quad = lane >> 4, l16 = lane & 15;
    int m0 = blockIdx.x * 64 + w * 16;
    int mA = min(m0 + l16, n - 1);
    int mD = m0 + quad * 4;

    bf16x8 a[4];
#pragma unroll
    for (int kc = 0; kc < 4; ++kc) {
        const float* ph = h + (size_t)mA * WIDTH + kc * 32 + quad * 8;
        float4 f0 = *(const float4*)(ph);
        float4 f1 = *(const float4*)(ph + 4);
        bf16x8 av;
        av[0] = f2b(f0.x); av[1] = f2b(f0.y); av[2] = f2b(f0.z); av[3] = f2b(f0.w);
        av[4] = f2b(f1.x); av[5] = f2b(f1.y); av[6] = f2b(f1.z); av[7] = f2b(f1.w);
        a[kc] = av;
    }

    f32x4 acc[8];
#pragma unroll
    for (int t = 0; t < 8; ++t) acc[t] = (f32x4){0.f, 0.f, 0.f, 0.f};
#pragma unroll
    for (int kc = 0; kc < 4; ++kc) {
#pragma unroll
        for (int t = 0; t < 8; ++t) {
            bf16x8 b = *(const bf16x8*)(postT + (t * 16 + l16) * 128 + kc * 32 + quad * 8);
            acc[t] = __builtin_amdgcn_mfma_f32_16x16x32_bf16(a[kc], b, acc[t], 0, 0, 0);
        }
    }
#pragma unroll
    for (int t = 0; t < 8; ++t) {
        float bv = post_b[t * 16 + l16];
#pragma unroll
        for (int r = 0; r < 4; ++r) {
            if (mD + r < n) {
                size_t idx = (size_t)(mD + r) * WIDTH + t * 16 + l16;
                out[idx] = x[idx] + acc[t][r] + bv;
            }
        }
    }
}

extern "C" void kernel_launch(void* const* d_in, const int* in_sizes, int n_in,
                              void* d_out, int out_size, void* d_ws, size_t ws_size,
                              hipStream_t stream) {
    const float* x      = (const float*)d_in[0];
    const int*   eidx   = (const int*)d_in[1];
    const int*   eattr  = (const int*)d_in[2];
    const float* pre_w  = (const float*)d_in[3];
    const float* pre_b  = (const float*)d_in[4];
    const float* msg0_w = (const float*)d_in[5];
    const float* msg0_b = (const float*)d_in[6];
    const float* msg1_w = (const float*)d_in[7];
    const float* msg1_b = (const float*)d_in[8];
    const float* msg2_w = (const float*)d_in[9];
    const float* msg2_b = (const float*)d_in[10];
    const float* msg3_w = (const float*)d_in[11];
    const float* msg3_b = (const float*)d_in[12];
    const float* r0w    = (const float*)d_in[13];
    const float* r0b    = (const float*)d_in[14];
    const float* r1w    = (const float*)d_in[15];
    const float* r1b    = (const float*)d_in[16];
    const float* r2w    = (const float*)d_in[17];
    const float* r2b    = (const float*)d_in[18];
    const float* post_w = (const float*)d_in[19];
    const float* post_b = (const float*)d_in[20];
    const float* emb0   = (const float*)d_in[21];
    const float* emb1   = (const float*)d_in[22];
    const float* emb2   = (const float*)d_in[23];
    const float* emb3   = (const float*)d_in[24];
    const float* einit  = (const float*)d_in[25];
    const float* init0  = (const float*)d_in[26];

    int n = in_sizes[0] / WIDTH;
    int E = in_sizes[2] / 4;
    size_t NW = (size_t)n * WIDTH;

    float* ws   = (float*)d_ws;
    float* A    = ws;                 // [N,128] f32 (full path only)
    float* G    = ws + NW;            // [N,128] f32
    float* h    = ws + 2 * NW;        // [N,128] f32  (G + agg)
    float* U    = ws + 3 * NW;        // [3][34][128]
    float* scal = U + 3 * 34 * WIDTH; // [2]
    short* sw   = (short*)(scal + 2);
    short* preT  = sw;                // 6 x [128][128] bf16 transposed weights
    short* w0T   = sw + 16384;
    short* w1T   = sw + 2 * 16384;
    short* w2T   = sw + 3 * 16384;
    short* w3T   = sw + 4 * 16384;
    short* postT = sw + 5 * 16384;
    short* xxb   = sw + 6 * 16384;    // [N,128] bf16
    short* Bb    = xxb + NW;          // [N,128] bf16 (full path only)
    short* Cb    = Bb + NW;           // [N,128] bf16
    int*      ib       = (int*)(Cb + NW);
    int*      offsets  = ib;                       // n+1
    int*      cursor   = offsets + (n + 1);        // n
    int*      counts   = cursor + n;               // n
    int*      lscan    = counts + n;               // n
    int*      partials = lscan + n;                // <=1024
    int*      s_src    = partials + 1024;          // E
    unsigned* s_att    = (unsigned*)(s_src + E);   // E

    k_prepw<<<384, 256, 0, stream>>>(pre_w, msg0_w, msg1_w, msg2_w, msg3_w, post_w,
                                     preT, w0T, w1T, w2T, w3T, postT);
    k_prep<<<52, 256, 0, stream>>>(einit, init0, emb0, emb1, emb2, emb3,
                                   r0w, r0b, r1w, r1b, r2w, r2b, U, scal);

    hipMemsetAsync(counts, 0, (size_t)n * sizeof(int), stream);
    int eb = (E + 255) / 256;
    k_hist<<<eb, 256, 0, stream>>>(eidx, counts, E);
    int sb = (n + 255) / 256;   // 196 blocks for n=50000 (<=1024 required)
    k_scan1<<<sb, 256, 0, stream>>>(counts, lscan, partials, n);
    k_scan2<<<1, 1024, 0, stream>>>(partials, sb, offsets, n);
    k_scan3<<<sb, 256, 0, stream>>>(counts, lscan, partials, offsets, cursor, n);
    k_scatter<<<eb, 256, 0, stream>>>(eidx, eattr, cursor, s_src, s_att, E);

    int gb = (n + 63) / 64;
    k_gemm1<<<gb, 256, 0, stream>>>(x, preT, pre_b, xxb, n);
    k_gemm2<<<gb, 256, 0, stream>>>(xxb, w0T, msg0_b, w1T, msg1_b, w2T, msg2_b,
                                    w3T, msg3_b, scal, G, A, Bb, Cb, n);
    k_agg<<<n, WIDTH, 0, stream>>>(offsets, s_src, s_att, A, Bb, Cb, U, scal, G, h, n);
    k_post<<<gb, 256, 0, stream>>>(x, h, postT, post_b, (float*)d_out, n);
}

// Round 6
// 351.502 us; speedup vs baseline: 3.7121x; 1.0639x over previous
//
#include <hip/hip_runtime.h>
#include <cstdint>

#define WIDTH 128
#define NCOMBO 2268   // 6*7*3*18 attr-combo rows

typedef short bf16x8 __attribute__((ext_vector_type(8)));
typedef float f32x4  __attribute__((ext_vector_type(4)));

__device__ __forceinline__ float gelu_fast(float v) {
    // tanh-approx GELU; max |err| vs erf-GELU ~3e-4. t = 1 - 2/(e+1) is inf-safe.
    float u = 0.7978845608f * v * (1.0f + 0.044715f * v * v);
    float e = __expf(2.0f * u);
    float t = 1.0f - 2.0f / (e + 1.0f);
    return 0.5f * v * (1.0f + t);
}
__device__ __forceinline__ short f2b(float f) {
    unsigned u = __float_as_uint(f);
    unsigned r = (u + 0x7FFFu + ((u >> 16) & 1u)) >> 16;
    return (short)r;
}
__device__ __forceinline__ float b2f(unsigned short s) {
    return __uint_as_float(((unsigned)s) << 16);
}

// ---------------------------------------------------------------------------
// k_prep: scalars + transformed embedding tables U.
// U layout: [3 remix][34 rows][128]; rows: emb0 0..5, emb1 6..12, emb2 13..15,
// emb3 16..33.  Bias folded into emb0 rows.
// ---------------------------------------------------------------------------
__global__ void k_prep(const float* __restrict__ einit, const float* __restrict__ init0,
                       const float* __restrict__ emb0, const float* __restrict__ emb1,
                       const float* __restrict__ emb2, const float* __restrict__ emb3,
                       const float* __restrict__ r0w, const float* __restrict__ r0b,
                       const float* __restrict__ r1w, const float* __restrict__ r1b,
                       const float* __restrict__ r2w, const float* __restrict__ r2b,
                       float* __restrict__ U, float* __restrict__ scal) {
    float e0 = expf(einit[0]), e1 = expf(einit[1]), e2 = expf(einit[2]), e3 = expf(einit[3]);
    float inv = 1.0f / sqrtf(e0 + e1 + e2 + e3);
    float xw[4] = {e0 * inv, e1 * inv, e2 * inv, e3 * inv};
    float se = expf(init0[2]);
    float sv = expf(init0[3]);
    int tid = blockIdx.x * blockDim.x + threadIdx.x;
    if (tid == 0) { scal[0] = init0[0]; scal[1] = init0[1]; }

    const int total = 3 * 34 * WIDTH;
    for (int idx = tid; idx < total; idx += gridDim.x * blockDim.x) {
        int r   = idx / (34 * WIDTH);
        int rem = idx - r * (34 * WIDTH);
        int g   = rem / WIDTH;
        int j   = rem - g * WIDTH;
        int cc, base;
        if (g >= 16)      { cc = 3; base = 16; }
        else if (g >= 13) { cc = 2; base = 13; }
        else if (g >= 6)  { cc = 1; base = 6; }
        else              { cc = 0; base = 0; }
        int i = g - base;
        const float* em = (cc == 0) ? emb0 : (cc == 1) ? emb1 : (cc == 2) ? emb2 : emb3;
        const float* w  = (r == 0) ? r0w : (r == 1) ? r1w : r2w;
        const float* rb = (r == 0) ? r0b : (r == 1) ? r1b : r2b;
        float s = (r == 2) ? sv : se;
        float acc = 0.0f;
        const float* erow = em + i * 64;
        for (int d = 0; d < 64; ++d) acc += erow[d] * w[d * WIDTH + j];
        float val = s * xw[cc] * acc;
        if (cc == 0) val += s * rb[j];
        U[idx] = val;
    }
}

// ---------------------------------------------------------------------------
// k_prepc: expand U into per-combo rows. Uc[r][combo][j] = sum of 4 U rows.
// combo = ((a*7 + b)*3 + c)*18 + d.  Grid = 3*NCOMBO blocks x 128.
// ---------------------------------------------------------------------------
__global__ void k_prepc(const float* __restrict__ U, float* __restrict__ Uc) {
    int bi = blockIdx.x;           // 0 .. 3*NCOMBO-1
    int r  = bi / NCOMBO;
    int cb = bi - r * NCOMBO;
    int a  = cb / 378;             // 7*3*18
    int rm = cb - a * 378;
    int b  = rm / 54;              // 3*18
    rm -= b * 54;
    int c  = rm / 18;
    int d  = rm - c * 18;
    int j  = threadIdx.x;
    const float* Ur = U + r * 34 * WIDTH;
    Uc[(size_t)bi * WIDTH + j] = Ur[a * WIDTH + j] + Ur[(6 + b) * WIDTH + j]
                               + Ur[(13 + c) * WIDTH + j] + Ur[(16 + d) * WIDTH + j];
}

// ---------------------------------------------------------------------------
// k_prepw: bf16-transpose 6 weight matrices [k][n] -> [n][k].
// ---------------------------------------------------------------------------
__global__ void k_prepw(const float* __restrict__ w0, const float* __restrict__ w1,
                        const float* __restrict__ w2, const float* __restrict__ w3,
                        const float* __restrict__ w4, const float* __restrict__ w5,
                        short* __restrict__ o0, short* __restrict__ o1,
                        short* __restrict__ o2, short* __restrict__ o3,
                        short* __restrict__ o4, short* __restrict__ o5) {
    int tid = blockIdx.x * blockDim.x + threadIdx.x;
    if (tid >= 6 * 16384) return;
    int which = tid >> 14;
    int r = tid & 16383;
    int k = r >> 7, nn = r & 127;
    const float* w = (which == 0) ? w0 : (which == 1) ? w1 : (which == 2) ? w2
                   : (which == 3) ? w3 : (which == 4) ? w4 : w5;
    short* o = (which == 0) ? o0 : (which == 1) ? o1 : (which == 2) ? o2
             : (which == 3) ? o3 : (which == 4) ? o4 : o5;
    o[nn * 128 + k] = f2b(w[k * 128 + nn]);
}

// ---------------------------------------------------------------------------
// Sort-by-dst: hist(+rank) -> 3-phase scan -> atomic-free scatter.
// ---------------------------------------------------------------------------
__global__ void k_hist(const int* __restrict__ edge_index, int* __restrict__ counts,
                       int* __restrict__ rank, int E) {
    int e = blockIdx.x * blockDim.x + threadIdx.x;
    if (e >= E) return;
    rank[e] = atomicAdd(&counts[edge_index[E + e]], 1);
}

__global__ void k_scan1(const int* __restrict__ counts, int* __restrict__ lscan,
                        int* __restrict__ partials, int n) {
    __shared__ int s[256];
    int t = threadIdx.x;
    int i = blockIdx.x * 256 + t;
    int v = (i < n) ? counts[i] : 0;
    s[t] = v;
    __syncthreads();
    for (int d = 1; d < 256; d <<= 1) {
        int u = (t >= d) ? s[t - d] : 0;
        __syncthreads();
        s[t] += u;
        __syncthreads();
    }
    if (i < n) lscan[i] = s[t];
    if (t == 255) partials[blockIdx.x] = s[255];
}

__global__ void k_scan2(int* __restrict__ partials, int nb,
                        int* __restrict__ offsets, int n) {
    __shared__ int s[1024];
    int t = threadIdx.x;
    int v = (t < nb) ? partials[t] : 0;
    s[t] = v;
    __syncthreads();
    for (int d = 1; d < 1024; d <<= 1) {
        int u = (t >= d) ? s[t - d] : 0;
        __syncthreads();
        s[t] += u;
        __syncthreads();
    }
    if (t < nb) partials[t] = s[t] - v;
    if (t == 1023) offsets[n] = s[1023];
}

__global__ void k_scan3(const int* __restrict__ counts, const int* __restrict__ lscan,
                        const int* __restrict__ partials, int* __restrict__ offsets, int n) {
    int i = blockIdx.x * 256 + threadIdx.x;
    if (i >= n) return;
    offsets[i] = partials[blockIdx.x] + lscan[i] - counts[i];
}

// scatter: pos = offsets[dst] + rank[e]; pack src (17b) | combo (12b) << 17.
__global__ void k_scatter(const int* __restrict__ edge_index, const int* __restrict__ edge_attr,
                          const int* __restrict__ offsets, const int* __restrict__ rank,
                          unsigned* __restrict__ s_pk, int E) {
    int e = blockIdx.x * blockDim.x + threadIdx.x;
    if (e >= E) return;
    int src = edge_index[e];
    int dst = edge_index[E + e];
    int4 at = ((const int4*)edge_attr)[e];
    int combo = ((at.x * 7 + at.y) * 3 + at.z) * 18 + at.w;
    int pos = offsets[dst] + rank[e];
    s_pk[pos] = (unsigned)src | ((unsigned)combo << 17);
}

// ---------------------------------------------------------------------------
// k_gemm1 (MFMA): xxb = bf16( LN( x @ pre_w + pre_b ) ).
// ---------------------------------------------------------------------------
__global__ void __launch_bounds__(256) k_gemm1(
        const float* __restrict__ x, const short* __restrict__ preT,
        const float* __restrict__ pre_b, short* __restrict__ xxb, int n) {
    int w    = threadIdx.x >> 6;
    int lane = threadIdx.x & 63;
    int quad = lane >> 4, l16 = lane & 15;
    int m0 = blockIdx.x * 64 + w * 16;
    int mA = min(m0 + l16, n - 1);

    bf16x8 a[4];
#pragma unroll
    for (int kc = 0; kc < 4; ++kc) {
        const float* px = x + (size_t)mA * WIDTH + kc * 32 + quad * 8;
        float4 f0 = *(const float4*)(px);
        float4 f1 = *(const float4*)(px + 4);
        bf16x8 av;
        av[0] = f2b(f0.x); av[1] = f2b(f0.y); av[2] = f2b(f0.z); av[3] = f2b(f0.w);
        av[4] = f2b(f1.x); av[5] = f2b(f1.y); av[6] = f2b(f1.z); av[7] = f2b(f1.w);
        a[kc] = av;
    }

    f32x4 acc[8];
#pragma unroll
    for (int t = 0; t < 8; ++t) acc[t] = (f32x4){0.f, 0.f, 0.f, 0.f};
#pragma unroll
    for (int kc = 0; kc < 4; ++kc) {
#pragma unroll
        for (int t = 0; t < 8; ++t) {
            bf16x8 b = *(const bf16x8*)(preT + (t * 16 + l16) * 128 + kc * 32 + quad * 8);
            acc[t] = __builtin_amdgcn_mfma_f32_16x16x32_bf16(a[kc], b, acc[t], 0, 0, 0);
        }
    }
#pragma unroll
    for (int t = 0; t < 8; ++t) {
        float bv = pre_b[t * 16 + l16];
#pragma unroll
        for (int r = 0; r < 4; ++r) acc[t][r] += bv;
    }
#pragma unroll
    for (int r = 0; r < 4; ++r) {
        float s = 0.f, s2 = 0.f;
#pragma unroll
        for (int t = 0; t < 8; ++t) { float v = acc[t][r]; s += v; s2 += v * v; }
        s  += __shfl_xor(s, 1);  s2 += __shfl_xor(s2, 1);
        s  += __shfl_xor(s, 2);  s2 += __shfl_xor(s2, 2);
        s  += __shfl_xor(s, 4);  s2 += __shfl_xor(s2, 4);
        s  += __shfl_xor(s, 8);  s2 += __shfl_xor(s2, 8);
        float m   = s * (1.0f / WIDTH);
        float var = s2 * (1.0f / WIDTH) - m * m;
        float rs  = rsqrtf(var + 1e-5f);
#pragma unroll
        for (int t = 0; t < 8; ++t) acc[t][r] = (acc[t][r] - m) * rs;
    }
    int mD = m0 + quad * 4;
#pragma unroll
    for (int r = 0; r < 4; ++r) {
        if (mD + r < n) {
#pragma unroll
            for (int t = 0; t < 8; ++t)
                xxb[(size_t)(mD + r) * WIDTH + t * 16 + l16] = f2b(acc[t][r]);
        }
    }
}

// ---------------------------------------------------------------------------
// k_gemm2 (MFMA): Gb = bf16(gelu(xx@w0+b0)), Cb = bf16(xx@w3+b3);
// full path adds A = xx@w1+b1 (f32), Bb = bf16(xx@w2+b2).
// ---------------------------------------------------------------------------
__global__ void __launch_bounds__(256) k_gemm2(
        const short* __restrict__ xxb,
        const short* __restrict__ w0T, const float* __restrict__ b0,
        const short* __restrict__ w1T, const float* __restrict__ b1,
        const short* __restrict__ w2T, const float* __restrict__ b2,
        const short* __restrict__ w3T, const float* __restrict__ b3,
        const float* __restrict__ scal,
        short* __restrict__ Gb, float* __restrict__ A,
        short* __restrict__ Bb, short* __restrict__ Cb, int n) {
    int w    = threadIdx.x >> 6;
    int lane = threadIdx.x & 63;
    int quad = lane >> 4, l16 = lane & 15;
    int m0 = blockIdx.x * 64 + w * 16;
    int mA = min(m0 + l16, n - 1);
    int mD = m0 + quad * 4;

    bf16x8 a[4];
#pragma unroll
    for (int kc = 0; kc < 4; ++kc)
        a[kc] = *(const bf16x8*)(xxb + (size_t)mA * WIDTH + kc * 32 + quad * 8);

    {
        f32x4 accG[8], accC[8];
#pragma unroll
        for (int t = 0; t < 8; ++t) { accG[t] = (f32x4){0.f,0.f,0.f,0.f}; accC[t] = (f32x4){0.f,0.f,0.f,0.f}; }
#pragma unroll
        for (int kc = 0; kc < 4; ++kc) {
#pragma unroll
            for (int t = 0; t < 8; ++t) {
                bf16x8 bg = *(const bf16x8*)(w0T + (t * 16 + l16) * 128 + kc * 32 + quad * 8);
                accG[t] = __builtin_amdgcn_mfma_f32_16x16x32_bf16(a[kc], bg, accG[t], 0, 0, 0);
                bf16x8 bc = *(const bf16x8*)(w3T + (t * 16 + l16) * 128 + kc * 32 + quad * 8);
                accC[t] = __builtin_amdgcn_mfma_f32_16x16x32_bf16(a[kc], bc, accC[t], 0, 0, 0);
            }
        }
#pragma unroll
        for (int t = 0; t < 8; ++t) {
            float bg = b0[t * 16 + l16];
            float bc = b3[t * 16 + l16];
#pragma unroll
            for (int r = 0; r < 4; ++r) {
                if (mD + r < n) {
                    size_t idx = (size_t)(mD + r) * WIDTH + t * 16 + l16;
                    Gb[idx] = f2b(gelu_fast(accG[t][r] + bg));
                    Cb[idx] = f2b(accC[t][r] + bc);
                }
            }
        }
    }
    if (scal[0] != 0.0f) {
        f32x4 accA[8], accB[8];
#pragma unroll
        for (int t = 0; t < 8; ++t) { accA[t] = (f32x4){0.f,0.f,0.f,0.f}; accB[t] = (f32x4){0.f,0.f,0.f,0.f}; }
#pragma unroll
        for (int kc = 0; kc < 4; ++kc) {
#pragma unroll
            for (int t = 0; t < 8; ++t) {
                bf16x8 ba = *(const bf16x8*)(w1T + (t * 16 + l16) * 128 + kc * 32 + quad * 8);
                accA[t] = __builtin_amdgcn_mfma_f32_16x16x32_bf16(a[kc], ba, accA[t], 0, 0, 0);
                bf16x8 bb = *(const bf16x8*)(w2T + (t * 16 + l16) * 128 + kc * 32 + quad * 8);
                accB[t] = __builtin_amdgcn_mfma_f32_16x16x32_bf16(a[kc], bb, accB[t], 0, 0, 0);
            }
        }
#pragma unroll
        for (int t = 0; t < 8; ++t) {
            float ba = b1[t * 16 + l16];
            float bb = b2[t * 16 + l16];
#pragma unroll
            for (int r = 0; r < 4; ++r) {
                if (mD + r < n) {
                    size_t idx = (size_t)(mD + r) * WIDTH + t * 16 + l16;
                    A[idx]  = accA[t][r] + ba;
                    Bb[idx] = f2b(accB[t][r] + bb);
                }
            }
        }
    }
}

// ---------------------------------------------------------------------------
// k_agg: per-node aggregation over dst-sorted packed edges; writes
// hb = bf16(Gb + agg).  Per edge: 1 packed word + 1 Cb gather + 1 Uc row.
// ---------------------------------------------------------------------------
__global__ void __launch_bounds__(128)
k_agg(const int* __restrict__ offsets, const unsigned* __restrict__ s_pk,
      const float* __restrict__ A, const short* __restrict__ Bb,
      const short* __restrict__ Cb, const float* __restrict__ Uc,
      const float* __restrict__ scal, const short* __restrict__ Gb,
      short* __restrict__ hb, int n) {
    int node = blockIdx.x;
    int c = threadIdx.x;
    int start = offsets[node];
    int end   = offsets[node + 1];

    const float* U0c = Uc;
    const float* U1c = Uc + (size_t)NCOMBO * WIDTH;
    const float* U2c = Uc + 2 * (size_t)NCOMBO * WIDTH;

    float i0 = scal[0], i1 = scal[1];
    float acc = 0.0f;

    if (i0 == 0.0f) {
        for (int p = start; p < end; ++p) {
            unsigned pk = s_pk[p];
            int src = (int)(pk & 0x1FFFFu);
            int cmb = (int)(pk >> 17);
            float cv = b2f(((const unsigned short*)Cb)[(size_t)src * WIDTH + c]);
            float u  = U2c[(size_t)cmb * WIDTH + c];
            acc += gelu_fast(cv + u);
        }
        acc *= expf(i1);
    } else {
        float av = A[(size_t)node * WIDTH + c];
        for (int p = start; p < end; ++p) {
            unsigned pk = s_pk[p];
            int src = (int)(pk & 0x1FFFFu);
            int cmb = (int)(pk >> 17);
            float q  = av + U0c[(size_t)cmb * WIDTH + c];
            float kk = b2f(((const unsigned short*)Bb)[(size_t)src * WIDTH + c])
                       + U1c[(size_t)cmb * WIDTH + c];
            float vv = gelu_fast(b2f(((const unsigned short*)Cb)[(size_t)src * WIDTH + c])
                       + U2c[(size_t)cmb * WIDTH + c]);
            float s = q * kk;
            s += __shfl_xor(s, 1);
            s += __shfl_xor(s, 2);
            s += __shfl_xor(s, 4);
            s += __shfl_xor(s, 8);
            s += __shfl_xor(s, 16);
            s += __shfl_xor(s, 32);
            acc += vv * expf(s * 0.125f * i0 + i1);
        }
    }
    size_t idx = (size_t)node * WIDTH + c;
    hb[idx] = f2b(b2f(((const unsigned short*)Gb)[idx]) + acc);
}

// ---------------------------------------------------------------------------
// k_post (MFMA): out = x + h @ post_w + post_b; h read directly as bf16.
// ---------------------------------------------------------------------------
__global__ void __launch_bounds__(256) k_post(
        const float* __restrict__ x, const short* __restrict__ hb,
        const short* __restrict__ postT, const float* __restrict__ post_b,
        float* __restrict__ out, int n) {
    int w    = threadIdx.x >> 6;
    int lane = threadIdx.x & 63;
    int quad = lane >> 4, l16 = lane & 15;
    int m0 = blockIdx.x * 64 + w * 16;
    int mA = min(m0 + l16, n - 1);
    int mD = m0 + quad * 4;

    bf16x8 a[4];
#pragma unroll
    for (int kc = 0; kc < 4; ++kc)
        a[kc] = *(const bf16x8*)(hb + (size_t)mA * WIDTH + kc * 32 + quad * 8);

    f32x4 acc[8];
#pragma unroll
    for (int t = 0; t < 8; ++t) acc[t] = (f32x4){0.f, 0.f, 0.f, 0.f};
#pragma unroll
    for (int kc = 0; kc < 4; ++kc) {
#pragma unroll
        for (int t = 0; t < 8; ++t) {
            bf16x8 b = *(const bf16x8*)(postT + (t * 16 + l16) * 128 + kc * 32 + quad * 8);
            acc[t] = __builtin_amdgcn_mfma_f32_16x16x32_bf16(a[kc], b, acc[t], 0, 0, 0);
        }
    }
#pragma unroll
    for (int t = 0; t < 8; ++t) {
        float bv = post_b[t * 16 + l16];
#pragma unroll
        for (int r = 0; r < 4; ++r) {
            if (mD + r < n) {
                size_t idx = (size_t)(mD + r) * WIDTH + t * 16 + l16;
                out[idx] = x[idx] + acc[t][r] + bv;
            }
        }
    }
}

extern "C" void kernel_launch(void* const* d_in, const int* in_sizes, int n_in,
                              void* d_out, int out_size, void* d_ws, size_t ws_size,
                              hipStream_t stream) {
    const float* x      = (const float*)d_in[0];
    const int*   eidx   = (const int*)d_in[1];
    const int*   eattr  = (const int*)d_in[2];
    const float* pre_w  = (const float*)d_in[3];
    const float* pre_b  = (const float*)d_in[4];
    const float* msg0_w = (const float*)d_in[5];
    const float* msg0_b = (const float*)d_in[6];
    const float* msg1_w = (const float*)d_in[7];
    const float* msg1_b = (const float*)d_in[8];
    const float* msg2_w = (const float*)d_in[9];
    const float* msg2_b = (const float*)d_in[10];
    const float* msg3_w = (const float*)d_in[11];
    const float* msg3_b = (const float*)d_in[12];
    const float* r0w    = (const float*)d_in[13];
    const float* r0b    = (const float*)d_in[14];
    const float* r1w    = (const float*)d_in[15];
    const float* r1b    = (const float*)d_in[16];
    const float* r2w    = (const float*)d_in[17];
    const float* r2b    = (const float*)d_in[18];
    const float* post_w = (const float*)d_in[19];
    const float* post_b = (const float*)d_in[20];
    const float* emb0   = (const float*)d_in[21];
    const float* emb1   = (const float*)d_in[22];
    const float* emb2   = (const float*)d_in[23];
    const float* emb3   = (const float*)d_in[24];
    const float* einit  = (const float*)d_in[25];
    const float* init0  = (const float*)d_in[26];

    int n = in_sizes[0] / WIDTH;
    int E = in_sizes[2] / 4;
    size_t NW = (size_t)n * WIDTH;

    float* ws   = (float*)d_ws;
    float* A    = ws;                              // [N,128] f32 (full path only)
    float* U    = ws + NW;                         // [3][34][128]
    float* Uc   = U + 3 * 34 * WIDTH;              // [3][NCOMBO][128]
    float* scal = Uc + 3 * (size_t)NCOMBO * WIDTH; // [2]
    short* sw   = (short*)(scal + 2);
    short* preT  = sw;                             // 6 x [128][128] bf16 weights^T
    short* w0T   = sw + 16384;
    short* w1T   = sw + 2 * 16384;
    short* w2T   = sw + 3 * 16384;
    short* w3T   = sw + 4 * 16384;
    short* postT = sw + 5 * 16384;
    short* xxb   = sw + 6 * 16384;                 // [N,128] bf16
    short* Bb    = xxb + NW;                       // [N,128] bf16 (full path)
    short* Cb    = Bb + NW;                        // [N,128] bf16
    short* Gb    = Cb + NW;                        // [N,128] bf16
    short* hb    = Gb + NW;                        // [N,128] bf16
    int*      ib       = (int*)(hb + NW);
    int*      offsets  = ib;                       // n+1
    int*      counts   = offsets + (n + 1);        // n
    int*      lscan    = counts + n;               // n
    int*      partials = lscan + n;                // <=1024
    int*      rank     = partials + 1024;          // E
    unsigned* s_pk     = (unsigned*)(rank + E);    // E

    k_prepw<<<384, 256, 0, stream>>>(pre_w, msg0_w, msg1_w, msg2_w, msg3_w, post_w,
                                     preT, w0T, w1T, w2T, w3T, postT);
    k_prep<<<52, 256, 0, stream>>>(einit, init0, emb0, emb1, emb2, emb3,
                                   r0w, r0b, r1w, r1b, r2w, r2b, U, scal);
    k_prepc<<<3 * NCOMBO, 128, 0, stream>>>(U, Uc);

    hipMemsetAsync(counts, 0, (size_t)n * sizeof(int), stream);
    int eb = (E + 255) / 256;
    k_hist<<<eb, 256, 0, stream>>>(eidx, counts, rank, E);
    int sb = (n + 255) / 256;   // 196 blocks for n=50000 (<=1024 required)
    k_scan1<<<sb, 256, 0, stream>>>(counts, lscan, partials, n);
    k_scan2<<<1, 1024, 0, stream>>>(partials, sb, offsets, n);
    k_scan3<<<sb, 256, 0, stream>>>(counts, lscan, partials, offsets, n);
    k_scatter<<<eb, 256, 0, stream>>>(eidx, eattr, offsets, rank, s_pk, E);

    int gb = (n + 63) / 64;
    k_gemm1<<<gb, 256, 0, stream>>>(x, preT, pre_b, xxb, n);
    k_gemm2<<<gb, 256, 0, stream>>>(xxb, w0T, msg0_b, w1T, msg1_b, w2T, msg2_b,
                                    w3T, msg3_b, scal, Gb, A, Bb, Cb, n);
    k_agg<<<n, WIDTH, 0, stream>>>(offsets, s_pk, A, Bb, Cb, Uc, scal, Gb, hb, n);
    k_post<<<gb, 256, 0, stream>>>(x, hb, postT, post_b, (float*)d_out, n);
}

// Round 7
// 308.054 us; speedup vs baseline: 4.2357x; 1.1410x over previous
//
#include <hip/hip_runtime.h>
#include <cstdint>

#define WIDTH 128
#define NCOMBO 2268   // 6*7*3*18 attr-combo rows

typedef short bf16x8 __attribute__((ext_vector_type(8)));
typedef float f32x4  __attribute__((ext_vector_type(4)));

// gelu(v) = v * sigmoid(2u), u = 0.79788456*v*(1+0.044715 v^2): 9 VALU ops.
// inf-safe: v->+inf: rcp(inf+1)=0 -> v; v->-inf: e->0 -> v - v*1 = 0.
__device__ __forceinline__ float gelu_fast(float v) {
    float e = __expf(v * __builtin_fmaf(v * v, 0.0713548f, 1.5957691f));
    return v - v * __builtin_amdgcn_rcpf(e + 1.0f);
}
__device__ __forceinline__ short f2b(float f) {
    unsigned u = __float_as_uint(f);
    unsigned r = (u + 0x7FFFu + ((u >> 16) & 1u)) >> 16;
    return (short)r;
}
__device__ __forceinline__ float b2f(unsigned short s) {
    return __uint_as_float(((unsigned)s) << 16);
}
__device__ __forceinline__ float b2f_lo(unsigned u) { return __uint_as_float(u << 16); }
__device__ __forceinline__ float b2f_hi(unsigned u) { return __uint_as_float(u & 0xFFFF0000u); }
__device__ __forceinline__ unsigned pack2(float lo, float hi) {
    return (unsigned)(unsigned short)f2b(lo) | ((unsigned)(unsigned short)f2b(hi) << 16);
}

// ---------------------------------------------------------------------------
// k_prep: one kernel does (a) bf16-transpose of 6 weight mats, (b) U tables
// [3][34][128] (bias folded into emb0 rows), (c) zero counts, (d) scal.
// ---------------------------------------------------------------------------
__global__ void k_prep(const float* __restrict__ einit, const float* __restrict__ init0,
                       const float* __restrict__ emb0, const float* __restrict__ emb1,
                       const float* __restrict__ emb2, const float* __restrict__ emb3,
                       const float* __restrict__ r0w, const float* __restrict__ r0b,
                       const float* __restrict__ r1w, const float* __restrict__ r1b,
                       const float* __restrict__ r2w, const float* __restrict__ r2b,
                       const float* __restrict__ pw0, const float* __restrict__ pw1,
                       const float* __restrict__ pw2, const float* __restrict__ pw3,
                       const float* __restrict__ pw4, const float* __restrict__ pw5,
                       short* __restrict__ o0, short* __restrict__ o1,
                       short* __restrict__ o2, short* __restrict__ o3,
                       short* __restrict__ o4, short* __restrict__ o5,
                       float* __restrict__ U, float* __restrict__ scal,
                       int* __restrict__ counts, int n) {
    int tid = blockIdx.x * blockDim.x + threadIdx.x;
    if (tid == 0) { scal[0] = init0[0]; scal[1] = init0[1]; }
    const int TOTW = 6 * 16384;
    const int TOTU = 3 * 34 * WIDTH;
    if (tid < TOTW) {
        int which = tid >> 14;
        int r = tid & 16383;
        int k = r >> 7, nn = r & 127;
        const float* w = (which == 0) ? pw0 : (which == 1) ? pw1 : (which == 2) ? pw2
                       : (which == 3) ? pw3 : (which == 4) ? pw4 : pw5;
        short* o = (which == 0) ? o0 : (which == 1) ? o1 : (which == 2) ? o2
                 : (which == 3) ? o3 : (which == 4) ? o4 : o5;
        o[nn * 128 + k] = f2b(w[k * 128 + nn]);
    } else if (tid < TOTW + TOTU) {
        int idx = tid - TOTW;
        float e0 = expf(einit[0]), e1 = expf(einit[1]), e2 = expf(einit[2]), e3 = expf(einit[3]);
        float inv = 1.0f / sqrtf(e0 + e1 + e2 + e3);
        float xw[4] = {e0 * inv, e1 * inv, e2 * inv, e3 * inv};
        float se = expf(init0[2]);
        float sv = expf(init0[3]);
        int r   = idx / (34 * WIDTH);
        int rem = idx - r * (34 * WIDTH);
        int g   = rem / WIDTH;
        int j   = rem - g * WIDTH;
        int cc, base;
        if (g >= 16)      { cc = 3; base = 16; }
        else if (g >= 13) { cc = 2; base = 13; }
        else if (g >= 6)  { cc = 1; base = 6; }
        else              { cc = 0; base = 0; }
        int i = g - base;
        const float* em = (cc == 0) ? emb0 : (cc == 1) ? emb1 : (cc == 2) ? emb2 : emb3;
        const float* w  = (r == 0) ? r0w : (r == 1) ? r1w : r2w;
        const float* rb = (r == 0) ? r0b : (r == 1) ? r1b : r2b;
        float s = (r == 2) ? sv : se;
        float acc = 0.0f;
        const float* erow = em + i * 64;
        for (int d = 0; d < 64; ++d) acc += erow[d] * w[d * WIDTH + j];
        float val = s * xw[cc] * acc;
        if (cc == 0) val += s * rb[j];
        U[idx] = val;
    } else if (tid < TOTW + TOTU + n) {
        counts[tid - TOTW - TOTU] = 0;
    }
}

// ---------------------------------------------------------------------------
// k_prepc: Uc[r][combo][j] = sum of 4 U rows. Fast path (init0[0]==0) skips
// r=0,1 (q/k tables unread). Grid = 3*NCOMBO x 128.
// ---------------------------------------------------------------------------
__global__ void k_prepc(const float* __restrict__ U, const float* __restrict__ init0,
                        float* __restrict__ Uc) {
    int bi = blockIdx.x;
    int r  = bi / NCOMBO;
    if (r < 2 && init0[0] == 0.0f) return;
    int cb = bi - r * NCOMBO;
    int a  = cb / 378;
    int rm = cb - a * 378;
    int b  = rm / 54;
    rm -= b * 54;
    int c  = rm / 18;
    int d  = rm - c * 18;
    int j  = threadIdx.x;
    const float* Ur = U + r * 34 * WIDTH;
    Uc[(size_t)bi * WIDTH + j] = Ur[a * WIDTH + j] + Ur[(6 + b) * WIDTH + j]
                               + Ur[(13 + c) * WIDTH + j] + Ur[(16 + d) * WIDTH + j];
}

// ---------------------------------------------------------------------------
// Sort-by-dst: hist(+rank) -> 3-phase scan -> atomic-free scatter.
// ---------------------------------------------------------------------------
__global__ void k_hist(const int* __restrict__ edge_index, int* __restrict__ counts,
                       int* __restrict__ rank, int E) {
    int e = blockIdx.x * blockDim.x + threadIdx.x;
    if (e >= E) return;
    rank[e] = atomicAdd(&counts[edge_index[E + e]], 1);
}

__global__ void k_scan1(const int* __restrict__ counts, int* __restrict__ lscan,
                        int* __restrict__ partials, int n) {
    __shared__ int s[256];
    int t = threadIdx.x;
    int i = blockIdx.x * 256 + t;
    int v = (i < n) ? counts[i] : 0;
    s[t] = v;
    __syncthreads();
    for (int d = 1; d < 256; d <<= 1) {
        int u = (t >= d) ? s[t - d] : 0;
        __syncthreads();
        s[t] += u;
        __syncthreads();
    }
    if (i < n) lscan[i] = s[t];
    if (t == 255) partials[blockIdx.x] = s[255];
}

__global__ void k_scan2(int* __restrict__ partials, int nb,
                        int* __restrict__ offsets, int n) {
    __shared__ int s[1024];
    int t = threadIdx.x;
    int v = (t < nb) ? partials[t] : 0;
    s[t] = v;
    __syncthreads();
    for (int d = 1; d < 1024; d <<= 1) {
        int u = (t >= d) ? s[t - d] : 0;
        __syncthreads();
        s[t] += u;
        __syncthreads();
    }
    if (t < nb) partials[t] = s[t] - v;
    if (t == 1023) offsets[n] = s[1023];
}

__global__ void k_scan3(const int* __restrict__ counts, const int* __restrict__ lscan,
                        const int* __restrict__ partials, int* __restrict__ offsets, int n) {
    int i = blockIdx.x * 256 + threadIdx.x;
    if (i >= n) return;
    offsets[i] = partials[blockIdx.x] + lscan[i] - counts[i];
}

__global__ void k_scatter(const int* __restrict__ edge_index, const int* __restrict__ edge_attr,
                          const int* __restrict__ offsets, const int* __restrict__ rank,
                          unsigned* __restrict__ s_pk, int E) {
    int e = blockIdx.x * blockDim.x + threadIdx.x;
    if (e >= E) return;
    int src = edge_index[e];
    int dst = edge_index[E + e];
    int4 at = ((const int4*)edge_attr)[e];
    int combo = ((at.x * 7 + at.y) * 3 + at.z) * 18 + at.w;
    s_pk[offsets[dst] + rank[e]] = (unsigned)src | ((unsigned)combo << 17);
}

// ---------------------------------------------------------------------------
// k_gemm12 (MFMA, fused): pre-GEMM + in-register LN -> LDS bf16 tile ->
// {Gb, Cb} (+{A, Bb} full path). xx never touches HBM.
// ---------------------------------------------------------------------------
__global__ void __launch_bounds__(256) k_gemm12(
        const float* __restrict__ x,
        const short* __restrict__ preT, const float* __restrict__ pre_b,
        const short* __restrict__ w0T, const float* __restrict__ b0,
        const short* __restrict__ w1T, const float* __restrict__ b1,
        const short* __restrict__ w2T, const float* __restrict__ b2,
        const short* __restrict__ w3T, const float* __restrict__ b3,
        const float* __restrict__ scal,
        short* __restrict__ Gb, float* __restrict__ A,
        short* __restrict__ Bb, short* __restrict__ Cb, int n) {
    __shared__ short xs[64 * 128];
    int w    = threadIdx.x >> 6;
    int lane = threadIdx.x & 63;
    int quad = lane >> 4, l16 = lane & 15;
    int m0 = blockIdx.x * 64 + w * 16;
    int mA = min(m0 + l16, n - 1);
    int mD = m0 + quad * 4;

    // ---- stage 1: pre GEMM + LN (C-layout in registers) ----
    {
        bf16x8 a[4];
#pragma unroll
        for (int kc = 0; kc < 4; ++kc) {
            const float* px = x + (size_t)mA * WIDTH + kc * 32 + quad * 8;
            float4 f0 = *(const float4*)(px);
            float4 f1 = *(const float4*)(px + 4);
            bf16x8 av;
            av[0] = f2b(f0.x); av[1] = f2b(f0.y); av[2] = f2b(f0.z); av[3] = f2b(f0.w);
            av[4] = f2b(f1.x); av[5] = f2b(f1.y); av[6] = f2b(f1.z); av[7] = f2b(f1.w);
            a[kc] = av;
        }
        f32x4 acc[8];
#pragma unroll
        for (int t = 0; t < 8; ++t) acc[t] = (f32x4){0.f, 0.f, 0.f, 0.f};
#pragma unroll
        for (int kc = 0; kc < 4; ++kc) {
#pragma unroll
            for (int t = 0; t < 8; ++t) {
                bf16x8 b = *(const bf16x8*)(preT + (t * 16 + l16) * 128 + kc * 32 + quad * 8);
                acc[t] = __builtin_amdgcn_mfma_f32_16x16x32_bf16(a[kc], b, acc[t], 0, 0, 0);
            }
        }
#pragma unroll
        for (int t = 0; t < 8; ++t) {
            float bv = pre_b[t * 16 + l16];
#pragma unroll
            for (int r = 0; r < 4; ++r) acc[t][r] += bv;
        }
#pragma unroll
        for (int r = 0; r < 4; ++r) {
            float s = 0.f, s2 = 0.f;
#pragma unroll
            for (int t = 0; t < 8; ++t) { float v = acc[t][r]; s += v; s2 += v * v; }
            s  += __shfl_xor(s, 1);  s2 += __shfl_xor(s2, 1);
            s  += __shfl_xor(s, 2);  s2 += __shfl_xor(s2, 2);
            s  += __shfl_xor(s, 4);  s2 += __shfl_xor(s2, 4);
            s  += __shfl_xor(s, 8);  s2 += __shfl_xor(s2, 8);
            float m   = s * (1.0f / WIDTH);
            float var = s2 * (1.0f / WIDTH) - m * m;
            float rs  = rsqrtf(var + 1e-5f);
#pragma unroll
            for (int t = 0; t < 8; ++t) acc[t][r] = (acc[t][r] - m) * rs;
        }
        // C-layout -> LDS row-major bf16 tile
        int rowb = w * 16 + quad * 4;
#pragma unroll
        for (int t = 0; t < 8; ++t)
#pragma unroll
            for (int r = 0; r < 4; ++r)
                xs[(rowb + r) * 128 + t * 16 + l16] = f2b(acc[t][r]);
    }
    __syncthreads();

    // ---- stage 2: A-frags from LDS, 2 (or 4) output GEMMs ----
    bf16x8 a[4];
#pragma unroll
    for (int kc = 0; kc < 4; ++kc)
        a[kc] = *(const bf16x8*)(&xs[(w * 16 + l16) * 128 + kc * 32 + quad * 8]);

    {
        f32x4 accG[8], accC[8];
#pragma unroll
        for (int t = 0; t < 8; ++t) { accG[t] = (f32x4){0.f,0.f,0.f,0.f}; accC[t] = (f32x4){0.f,0.f,0.f,0.f}; }
#pragma unroll
        for (int kc = 0; kc < 4; ++kc) {
#pragma unroll
            for (int t = 0; t < 8; ++t) {
                bf16x8 bg = *(const bf16x8*)(w0T + (t * 16 + l16) * 128 + kc * 32 + quad * 8);
                accG[t] = __builtin_amdgcn_mfma_f32_16x16x32_bf16(a[kc], bg, accG[t], 0, 0, 0);
                bf16x8 bc = *(const bf16x8*)(w3T + (t * 16 + l16) * 128 + kc * 32 + quad * 8);
                accC[t] = __builtin_amdgcn_mfma_f32_16x16x32_bf16(a[kc], bc, accC[t], 0, 0, 0);
            }
        }
#pragma unroll
        for (int t = 0; t < 8; ++t) {
            float bg = b0[t * 16 + l16];
            float bc = b3[t * 16 + l16];
#pragma unroll
            for (int r = 0; r < 4; ++r) {
                if (mD + r < n) {
                    size_t idx = (size_t)(mD + r) * WIDTH + t * 16 + l16;
                    Gb[idx] = f2b(gelu_fast(accG[t][r] + bg));
                    Cb[idx] = f2b(accC[t][r] + bc);
                }
            }
        }
    }
    if (scal[0] != 0.0f) {
        f32x4 accA[8], accB[8];
#pragma unroll
        for (int t = 0; t < 8; ++t) { accA[t] = (f32x4){0.f,0.f,0.f,0.f}; accB[t] = (f32x4){0.f,0.f,0.f,0.f}; }
#pragma unroll
        for (int kc = 0; kc < 4; ++kc) {
#pragma unroll
            for (int t = 0; t < 8; ++t) {
                bf16x8 ba = *(const bf16x8*)(w1T + (t * 16 + l16) * 128 + kc * 32 + quad * 8);
                accA[t] = __builtin_amdgcn_mfma_f32_16x16x32_bf16(a[kc], ba, accA[t], 0, 0, 0);
                bf16x8 bb = *(const bf16x8*)(w2T + (t * 16 + l16) * 128 + kc * 32 + quad * 8);
                accB[t] = __builtin_amdgcn_mfma_f32_16x16x32_bf16(a[kc], bb, accB[t], 0, 0, 0);
            }
        }
#pragma unroll
        for (int t = 0; t < 8; ++t) {
            float ba = b1[t * 16 + l16];
            float bb = b2[t * 16 + l16];
#pragma unroll
            for (int r = 0; r < 4; ++r) {
                if (mD + r < n) {
                    size_t idx = (size_t)(mD + r) * WIDTH + t * 16 + l16;
                    A[idx]  = accA[t][r] + ba;
                    Bb[idx] = f2b(accB[t][r] + bb);
                }
            }
        }
    }
}

// ---------------------------------------------------------------------------
// k_agg: one WAVE per node; lane L owns cols {2L, 2L+1} (bf16-pair loads).
// Block 256 = 4 nodes. Edge loop unrolled x2. Writes hb = bf16(Gb + agg).
// ---------------------------------------------------------------------------
__global__ void __launch_bounds__(256)
k_agg(const int* __restrict__ offsets, const unsigned* __restrict__ s_pk,
      const float* __restrict__ A, const short* __restrict__ Bb,
      const short* __restrict__ Cb, const float* __restrict__ Uc,
      const float* __restrict__ scal, const short* __restrict__ Gb,
      short* __restrict__ hb, int n) {
    int wid = threadIdx.x >> 6;
    int L   = threadIdx.x & 63;
    int node = blockIdx.x * 4 + wid;
    if (node >= n) return;
    int start = offsets[node];
    int end   = offsets[node + 1];

    const unsigned* Cb32 = (const unsigned*)Cb;
    const unsigned* Bb32 = (const unsigned*)Bb;
    const float2* U0c2 = (const float2*)(Uc);
    const float2* U1c2 = (const float2*)(Uc + (size_t)NCOMBO * WIDTH);
    const float2* U2c2 = (const float2*)(Uc + 2 * (size_t)NCOMBO * WIDTH);

    float i0 = scal[0], i1 = scal[1];
    float acc0 = 0.0f, acc1 = 0.0f;

    if (i0 == 0.0f) {
        int p = start;
        for (; p + 2 <= end; p += 2) {
            unsigned pk0 = s_pk[p], pk1 = s_pk[p + 1];
            unsigned sA = pk0 & 0x1FFFFu, cA = pk0 >> 17;
            unsigned sB = pk1 & 0x1FFFFu, cB = pk1 >> 17;
            unsigned cc0 = Cb32[sA * 64 + L];
            float2   uu0 = U2c2[cA * 64 + L];
            unsigned cc1 = Cb32[sB * 64 + L];
            float2   uu1 = U2c2[cB * 64 + L];
            acc0 += gelu_fast(b2f_lo(cc0) + uu0.x);
            acc1 += gelu_fast(b2f_hi(cc0) + uu0.y);
            acc0 += gelu_fast(b2f_lo(cc1) + uu1.x);
            acc1 += gelu_fast(b2f_hi(cc1) + uu1.y);
        }
        if (p < end) {
            unsigned pk0 = s_pk[p];
            unsigned sA = pk0 & 0x1FFFFu, cA = pk0 >> 17;
            unsigned cc0 = Cb32[sA * 64 + L];
            float2   uu0 = U2c2[cA * 64 + L];
            acc0 += gelu_fast(b2f_lo(cc0) + uu0.x);
            acc1 += gelu_fast(b2f_hi(cc0) + uu0.y);
        }
        float s = __expf(i1);
        acc0 *= s; acc1 *= s;
    } else {
        float2 av = *(const float2*)(A + (size_t)node * WIDTH + 2 * L);
        for (int p = start; p < end; ++p) {
            unsigned pk = s_pk[p];
            unsigned sA = pk & 0x1FFFFu, cA = pk >> 17;
            float2 u0 = U0c2[cA * 64 + L];
            float2 u1 = U1c2[cA * 64 + L];
            float2 u2 = U2c2[cA * 64 + L];
            unsigned bb = Bb32[sA * 64 + L];
            unsigned cc = Cb32[sA * 64 + L];
            float q0 = av.x + u0.x, q1 = av.y + u0.y;
            float k0 = b2f_lo(bb) + u1.x, k1 = b2f_hi(bb) + u1.y;
            float v0 = gelu_fast(b2f_lo(cc) + u2.x);
            float v1 = gelu_fast(b2f_hi(cc) + u2.y);
            float s = q0 * k0 + q1 * k1;
            // reduce within 32-lane half (one head per half: cols 0..63 / 64..127)
            s += __shfl_xor(s, 1);
            s += __shfl_xor(s, 2);
            s += __shfl_xor(s, 4);
            s += __shfl_xor(s, 8);
            s += __shfl_xor(s, 16);
            float att = __expf(s * 0.125f * i0 + i1);
            acc0 += v0 * att;
            acc1 += v1 * att;
        }
    }
    unsigned g = ((const unsigned*)Gb)[(size_t)node * 64 + L];
    ((unsigned*)hb)[(size_t)node * 64 + L] = pack2(b2f_lo(g) + acc0, b2f_hi(g) + acc1);
}

// ---------------------------------------------------------------------------
// k_post (MFMA): out = x + h @ post_w + post_b; h read directly as bf16.
// ---------------------------------------------------------------------------
__global__ void __launch_bounds__(256) k_post(
        const float* __restrict__ x, const short* __restrict__ hb,
        const short* __restrict__ postT, const float* __restrict__ post_b,
        float* __restrict__ out, int n) {
    int w    = threadIdx.x >> 6;
    int lane = threadIdx.x & 63;
    int quad = lane >> 4, l16 = lane & 15;
    int m0 = blockIdx.x * 64 + w * 16;
    int mA = min(m0 + l16, n - 1);
    int mD = m0 + quad * 4;

    bf16x8 a[4];
#pragma unroll
    for (int kc = 0; kc < 4; ++kc)
        a[kc] = *(const bf16x8*)(hb + (size_t)mA * WIDTH + kc * 32 + quad * 8);

    f32x4 acc[8];
#pragma unroll
    for (int t = 0; t < 8; ++t) acc[t] = (f32x4){0.f, 0.f, 0.f, 0.f};
#pragma unroll
    for (int kc = 0; kc < 4; ++kc) {
#pragma unroll
        for (int t = 0; t < 8; ++t) {
            bf16x8 b = *(const bf16x8*)(postT + (t * 16 + l16) * 128 + kc * 32 + quad * 8);
            acc[t] = __builtin_amdgcn_mfma_f32_16x16x32_bf16(a[kc], b, acc[t], 0, 0, 0);
        }
    }
#pragma unroll
    for (int t = 0; t < 8; ++t) {
        float bv = post_b[t * 16 + l16];
#pragma unroll
        for (int r = 0; r < 4; ++r) {
            if (mD + r < n) {
                size_t idx = (size_t)(mD + r) * WIDTH + t * 16 + l16;
                out[idx] = x[idx] + acc[t][r] + bv;
            }
        }
    }
}

extern "C" void kernel_launch(void* const* d_in, const int* in_sizes, int n_in,
                              void* d_out, int out_size, void* d_ws, size_t ws_size,
                              hipStream_t stream) {
    const float* x      = (const float*)d_in[0];
    const int*   eidx   = (const int*)d_in[1];
    const int*   eattr  = (const int*)d_in[2];
    const float* pre_w  = (const float*)d_in[3];
    const float* pre_b  = (const float*)d_in[4];
    const float* msg0_w = (const float*)d_in[5];
    const float* msg0_b = (const float*)d_in[6];
    const float* msg1_w = (const float*)d_in[7];
    const float* msg1_b = (const float*)d_in[8];
    const float* msg2_w = (const float*)d_in[9];
    const float* msg2_b = (const float*)d_in[10];
    const float* msg3_w = (const float*)d_in[11];
    const float* msg3_b = (const float*)d_in[12];
    const float* r0w    = (const float*)d_in[13];
    const float* r0b    = (const float*)d_in[14];
    const float* r1w    = (const float*)d_in[15];
    const float* r1b    = (const float*)d_in[16];
    const float* r2w    = (const float*)d_in[17];
    const float* r2b    = (const float*)d_in[18];
    const float* post_w = (const float*)d_in[19];
    const float* post_b = (const float*)d_in[20];
    const float* emb0   = (const float*)d_in[21];
    const float* emb1   = (const float*)d_in[22];
    const float* emb2   = (const float*)d_in[23];
    const float* emb3   = (const float*)d_in[24];
    const float* einit  = (const float*)d_in[25];
    const float* init0  = (const float*)d_in[26];

    int n = in_sizes[0] / WIDTH;
    int E = in_sizes[2] / 4;
    size_t NW = (size_t)n * WIDTH;

    float* ws   = (float*)d_ws;
    float* A    = ws;                              // [N,128] f32 (full path only)
    float* U    = ws + NW;                         // [3][34][128]
    float* Uc   = U + 3 * 34 * WIDTH;              // [3][NCOMBO][128]
    float* scal = Uc + 3 * (size_t)NCOMBO * WIDTH; // [2]
    short* sw   = (short*)(scal + 2);
    short* preT  = sw;                             // 6 x [128][128] bf16 weights^T
    short* w0T   = sw + 16384;
    short* w1T   = sw + 2 * 16384;
    short* w2T   = sw + 3 * 16384;
    short* w3T   = sw + 4 * 16384;
    short* postT = sw + 5 * 16384;
    short* Bb    = sw + 6 * 16384;                 // [N,128] bf16 (full path)
    short* Cb    = Bb + NW;                        // [N,128] bf16
    short* Gb    = Cb + NW;                        // [N,128] bf16
    short* hb    = Gb + NW;                        // [N,128] bf16
    int*      ib       = (int*)(hb + NW);
    int*      offsets  = ib;                       // n+1
    int*      counts   = offsets + (n + 1);        // n
    int*      lscan    = counts + n;               // n
    int*      partials = lscan + n;                // <=1024
    int*      rank     = partials + 1024;          // E
    unsigned* s_pk     = (unsigned*)(rank + E);    // E

    int prep_total = 6 * 16384 + 3 * 34 * WIDTH + n;
    k_prep<<<(prep_total + 255) / 256, 256, 0, stream>>>(
        einit, init0, emb0, emb1, emb2, emb3,
        r0w, r0b, r1w, r1b, r2w, r2b,
        pre_w, msg0_w, msg1_w, msg2_w, msg3_w, post_w,
        preT, w0T, w1T, w2T, w3T, postT, U, scal, counts, n);
    k_prepc<<<3 * NCOMBO, 128, 0, stream>>>(U, init0, Uc);

    int eb = (E + 255) / 256;
    k_hist<<<eb, 256, 0, stream>>>(eidx, counts, rank, E);
    int sb = (n + 255) / 256;
    k_scan1<<<sb, 256, 0, stream>>>(counts, lscan, partials, n);
    k_scan2<<<1, 1024, 0, stream>>>(partials, sb, offsets, n);
    k_scan3<<<sb, 256, 0, stream>>>(counts, lscan, partials, offsets, n);
    k_scatter<<<eb, 256, 0, stream>>>(eidx, eattr, offsets, rank, s_pk, E);

    int gb = (n + 63) / 64;
    k_gemm12<<<gb, 256, 0, stream>>>(x, preT, pre_b, w0T, msg0_b, w1T, msg1_b,
                                     w2T, msg2_b, w3T, msg3_b, scal, Gb, A, Bb, Cb, n);
    k_agg<<<(n + 3) / 4, 256, 0, stream>>>(offsets, s_pk, A, Bb, Cb, Uc, scal, Gb, hb, n);
    k_post<<<gb, 256, 0, stream>>>(x, hb, postT, post_b, (float*)d_out, n);
}

// Round 8
// 280.346 us; speedup vs baseline: 4.6543x; 1.0988x over previous
//
#include <hip/hip_runtime.h>
#include <cstdint>

#define WIDTH 128
#define NCOMBO 2268   // 6*7*3*18 attr-combo rows
#define XSL 136       // xs LDS row stride in shorts (128 + 8 pad: kills 16-way conflicts)

typedef short bf16x8 __attribute__((ext_vector_type(8)));
typedef float f32x4  __attribute__((ext_vector_type(4)));

// gelu(v) = v * sigmoid(2u): 9 VALU ops, inf-safe.
__device__ __forceinline__ float gelu_fast(float v) {
    float e = __expf(v * __builtin_fmaf(v * v, 0.0713548f, 1.5957691f));
    return v - v * __builtin_amdgcn_rcpf(e + 1.0f);
}
__device__ __forceinline__ short f2b(float f) {
    unsigned u = __float_as_uint(f);
    unsigned r = (u + 0x7FFFu + ((u >> 16) & 1u)) >> 16;
    return (short)r;
}
__device__ __forceinline__ float b2f(unsigned short s) {
    return __uint_as_float(((unsigned)s) << 16);
}
__device__ __forceinline__ float b2f_lo(unsigned u) { return __uint_as_float(u << 16); }
__device__ __forceinline__ float b2f_hi(unsigned u) { return __uint_as_float(u & 0xFFFF0000u); }
__device__ __forceinline__ unsigned pack2(float lo, float hi) {
    return (unsigned)(unsigned short)f2b(lo) | ((unsigned)(unsigned short)f2b(hi) << 16);
}

// ---------------------------------------------------------------------------
// k_prep: (a) bf16-transpose of 6 weight mats, (b) U tables [3][34][128]
// (bias folded into emb0 rows), (c) zero counts, (d) scal.
// ---------------------------------------------------------------------------
__global__ void k_prep(const float* __restrict__ einit, const float* __restrict__ init0,
                       const float* __restrict__ emb0, const float* __restrict__ emb1,
                       const float* __restrict__ emb2, const float* __restrict__ emb3,
                       const float* __restrict__ r0w, const float* __restrict__ r0b,
                       const float* __restrict__ r1w, const float* __restrict__ r1b,
                       const float* __restrict__ r2w, const float* __restrict__ r2b,
                       const float* __restrict__ pw0, const float* __restrict__ pw1,
                       const float* __restrict__ pw2, const float* __restrict__ pw3,
                       const float* __restrict__ pw4, const float* __restrict__ pw5,
                       short* __restrict__ o0, short* __restrict__ o1,
                       short* __restrict__ o2, short* __restrict__ o3,
                       short* __restrict__ o4, short* __restrict__ o5,
                       float* __restrict__ U, float* __restrict__ scal,
                       int* __restrict__ counts, int n) {
    int tid = blockIdx.x * blockDim.x + threadIdx.x;
    if (tid == 0) { scal[0] = init0[0]; scal[1] = init0[1]; }
    const int TOTW = 6 * 16384;
    const int TOTU = 3 * 34 * WIDTH;
    if (tid < TOTW) {
        int which = tid >> 14;
        int r = tid & 16383;
        int k = r >> 7, nn = r & 127;
        const float* w = (which == 0) ? pw0 : (which == 1) ? pw1 : (which == 2) ? pw2
                       : (which == 3) ? pw3 : (which == 4) ? pw4 : pw5;
        short* o = (which == 0) ? o0 : (which == 1) ? o1 : (which == 2) ? o2
                 : (which == 3) ? o3 : (which == 4) ? o4 : o5;
        o[nn * 128 + k] = f2b(w[k * 128 + nn]);
    } else if (tid < TOTW + TOTU) {
        int idx = tid - TOTW;
        float e0 = expf(einit[0]), e1 = expf(einit[1]), e2 = expf(einit[2]), e3 = expf(einit[3]);
        float inv = 1.0f / sqrtf(e0 + e1 + e2 + e3);
        float xw[4] = {e0 * inv, e1 * inv, e2 * inv, e3 * inv};
        float se = expf(init0[2]);
        float sv = expf(init0[3]);
        int r   = idx / (34 * WIDTH);
        int rem = idx - r * (34 * WIDTH);
        int g   = rem / WIDTH;
        int j   = rem - g * WIDTH;
        int cc, base;
        if (g >= 16)      { cc = 3; base = 16; }
        else if (g >= 13) { cc = 2; base = 13; }
        else if (g >= 6)  { cc = 1; base = 6; }
        else              { cc = 0; base = 0; }
        int i = g - base;
        const float* em = (cc == 0) ? emb0 : (cc == 1) ? emb1 : (cc == 2) ? emb2 : emb3;
        const float* w  = (r == 0) ? r0w : (r == 1) ? r1w : r2w;
        const float* rb = (r == 0) ? r0b : (r == 1) ? r1b : r2b;
        float s = (r == 2) ? sv : se;
        float acc = 0.0f;
        const float* erow = em + i * 64;
        for (int d = 0; d < 64; ++d) acc += erow[d] * w[d * WIDTH + j];
        float val = s * xw[cc] * acc;
        if (cc == 0) val += s * rb[j];
        U[idx] = val;
    } else if (tid < TOTW + TOTU + n) {
        counts[tid - TOTW - TOTU] = 0;
    }
}

// ---------------------------------------------------------------------------
// k_prepc: Uc[r][combo][j] = sum of 4 U rows; fast path skips r=0,1.
// ---------------------------------------------------------------------------
__global__ void k_prepc(const float* __restrict__ U, const float* __restrict__ init0,
                        float* __restrict__ Uc) {
    int bi = blockIdx.x;
    int r  = bi / NCOMBO;
    if (r < 2 && init0[0] == 0.0f) return;
    int cb = bi - r * NCOMBO;
    int a  = cb / 378;
    int rm = cb - a * 378;
    int b  = rm / 54;
    rm -= b * 54;
    int c  = rm / 18;
    int d  = rm - c * 18;
    int j  = threadIdx.x;
    const float* Ur = U + r * 34 * WIDTH;
    Uc[(size_t)bi * WIDTH + j] = Ur[a * WIDTH + j] + Ur[(6 + b) * WIDTH + j]
                               + Ur[(13 + c) * WIDTH + j] + Ur[(16 + d) * WIDTH + j];
}

// ---------------------------------------------------------------------------
// Sort-by-dst: hist(+rank) -> 3-phase scan -> atomic-free scatter.
// ---------------------------------------------------------------------------
__global__ void k_hist(const int* __restrict__ edge_index, int* __restrict__ counts,
                       int* __restrict__ rank, int E) {
    int e = blockIdx.x * blockDim.x + threadIdx.x;
    if (e >= E) return;
    rank[e] = atomicAdd(&counts[edge_index[E + e]], 1);
}

__global__ void k_scan1(const int* __restrict__ counts, int* __restrict__ lscan,
                        int* __restrict__ partials, int n) {
    __shared__ int s[256];
    int t = threadIdx.x;
    int i = blockIdx.x * 256 + t;
    int v = (i < n) ? counts[i] : 0;
    s[t] = v;
    __syncthreads();
    for (int d = 1; d < 256; d <<= 1) {
        int u = (t >= d) ? s[t - d] : 0;
        __syncthreads();
        s[t] += u;
        __syncthreads();
    }
    if (i < n) lscan[i] = s[t];
    if (t == 255) partials[blockIdx.x] = s[255];
}

__global__ void k_scan2(int* __restrict__ partials, int nb,
                        int* __restrict__ offsets, int n) {
    __shared__ int s[1024];
    int t = threadIdx.x;
    int v = (t < nb) ? partials[t] : 0;
    s[t] = v;
    __syncthreads();
    for (int d = 1; d < 1024; d <<= 1) {
        int u = (t >= d) ? s[t - d] : 0;
        __syncthreads();
        s[t] += u;
        __syncthreads();
    }
    if (t < nb) partials[t] = s[t] - v;
    if (t == 1023) offsets[n] = s[1023];
}

__global__ void k_scan3(const int* __restrict__ counts, const int* __restrict__ lscan,
                        const int* __restrict__ partials, int* __restrict__ offsets, int n) {
    int i = blockIdx.x * 256 + threadIdx.x;
    if (i >= n) return;
    offsets[i] = partials[blockIdx.x] + lscan[i] - counts[i];
}

__global__ void k_scatter(const int* __restrict__ edge_index, const int* __restrict__ edge_attr,
                          const int* __restrict__ offsets, const int* __restrict__ rank,
                          unsigned* __restrict__ s_pk, int E) {
    int e = blockIdx.x * blockDim.x + threadIdx.x;
    if (e >= E) return;
    int src = edge_index[e];
    int dst = edge_index[E + e];
    int4 at = ((const int4*)edge_attr)[e];
    int combo = ((at.x * 7 + at.y) * 3 + at.z) * 18 + at.w;
    s_pk[offsets[dst] + rank[e]] = (unsigned)src | ((unsigned)combo << 17);
}

// ---------------------------------------------------------------------------
// k_gemm12 v2: stage 1 = pre-GEMM + in-register LN -> padded LDS bf16 tile.
// Stage 2 = B-STATIONARY: wave w computes ALL 64 rows x col-tiles {2w,2w+1};
// B-frags (8/mat) prefetched into registers BEFORE stage 1 (latency hidden),
// A-frags via ds_read_b128 from padded xs (2-way conflicts only).
// ---------------------------------------------------------------------------
__global__ void __launch_bounds__(256, 2) k_gemm12(
        const float* __restrict__ x,
        const short* __restrict__ preT, const float* __restrict__ pre_b,
        const short* __restrict__ w0T, const float* __restrict__ b0,
        const short* __restrict__ w1T, const float* __restrict__ b1,
        const short* __restrict__ w2T, const float* __restrict__ b2,
        const short* __restrict__ w3T, const float* __restrict__ b3,
        const float* __restrict__ scal,
        short* __restrict__ Gb, float* __restrict__ A,
        short* __restrict__ Bb, short* __restrict__ Cb, int n) {
    __shared__ short xs[64 * XSL];
    int w    = threadIdx.x >> 6;
    int lane = threadIdx.x & 63;
    int quad = lane >> 4, l16 = lane & 15;
    int m0   = blockIdx.x * 64;

    // ---- prefetch stage-2 B-frags (col tiles 2w, 2w+1) for G & C mats ----
    bf16x8 Bg[2][4], Bc[2][4];
#pragma unroll
    for (int tt = 0; tt < 2; ++tt)
#pragma unroll
        for (int kc = 0; kc < 4; ++kc) {
            int row = (2 * w + tt) * 16 + l16;
            Bg[tt][kc] = *(const bf16x8*)(w0T + row * 128 + kc * 32 + quad * 8);
            Bc[tt][kc] = *(const bf16x8*)(w3T + row * 128 + kc * 32 + quad * 8);
        }

    // ---- stage 1: pre GEMM (wave's 16 rows x 128 cols) + in-register LN ----
    {
        int mrow = m0 + w * 16;
        int mA = min(mrow + l16, n - 1);
        bf16x8 a[4];
#pragma unroll
        for (int kc = 0; kc < 4; ++kc) {
            const float* px = x + (size_t)mA * WIDTH + kc * 32 + quad * 8;
            float4 f0 = *(const float4*)(px);
            float4 f1 = *(const float4*)(px + 4);
            bf16x8 av;
            av[0] = f2b(f0.x); av[1] = f2b(f0.y); av[2] = f2b(f0.z); av[3] = f2b(f0.w);
            av[4] = f2b(f1.x); av[5] = f2b(f1.y); av[6] = f2b(f1.z); av[7] = f2b(f1.w);
            a[kc] = av;
        }
        f32x4 acc[8];
#pragma unroll
        for (int t = 0; t < 8; ++t) acc[t] = (f32x4){0.f, 0.f, 0.f, 0.f};
#pragma unroll
        for (int kc = 0; kc < 4; ++kc) {
#pragma unroll
            for (int t = 0; t < 8; ++t) {
                bf16x8 b = *(const bf16x8*)(preT + (t * 16 + l16) * 128 + kc * 32 + quad * 8);
                acc[t] = __builtin_amdgcn_mfma_f32_16x16x32_bf16(a[kc], b, acc[t], 0, 0, 0);
            }
        }
#pragma unroll
        for (int t = 0; t < 8; ++t) {
            float bv = pre_b[t * 16 + l16];
#pragma unroll
            for (int r = 0; r < 4; ++r) acc[t][r] += bv;
        }
#pragma unroll
        for (int r = 0; r < 4; ++r) {
            float s = 0.f, s2 = 0.f;
#pragma unroll
            for (int t = 0; t < 8; ++t) { float v = acc[t][r]; s += v; s2 += v * v; }
            s  += __shfl_xor(s, 1);  s2 += __shfl_xor(s2, 1);
            s  += __shfl_xor(s, 2);  s2 += __shfl_xor(s2, 2);
            s  += __shfl_xor(s, 4);  s2 += __shfl_xor(s2, 4);
            s  += __shfl_xor(s, 8);  s2 += __shfl_xor(s2, 8);
            float m   = s * (1.0f / WIDTH);
            float var = s2 * (1.0f / WIDTH) - m * m;
            float rs  = rsqrtf(var + 1e-5f);
#pragma unroll
            for (int t = 0; t < 8; ++t) acc[t][r] = (acc[t][r] - m) * rs;
        }
        int rowb = w * 16 + quad * 4;
#pragma unroll
        for (int t = 0; t < 8; ++t)
#pragma unroll
            for (int r = 0; r < 4; ++r)
                xs[(rowb + r) * XSL + t * 16 + l16] = f2b(acc[t][r]);
    }
    __syncthreads();

    // ---- stage 2: A-frags (all 4 m-subtiles) from LDS ----
    bf16x8 a2[4][4];
#pragma unroll
    for (int i = 0; i < 4; ++i)
#pragma unroll
        for (int kc = 0; kc < 4; ++kc)
            a2[i][kc] = *(const bf16x8*)(&xs[(i * 16 + l16) * XSL + kc * 32 + quad * 8]);

    {
        f32x4 accG[4][2], accC[4][2];
#pragma unroll
        for (int i = 0; i < 4; ++i)
#pragma unroll
            for (int tt = 0; tt < 2; ++tt) {
                accG[i][tt] = (f32x4){0.f,0.f,0.f,0.f};
                accC[i][tt] = (f32x4){0.f,0.f,0.f,0.f};
            }
#pragma unroll
        for (int kc = 0; kc < 4; ++kc)
#pragma unroll
            for (int i = 0; i < 4; ++i)
#pragma unroll
                for (int tt = 0; tt < 2; ++tt) {
                    accG[i][tt] = __builtin_amdgcn_mfma_f32_16x16x32_bf16(a2[i][kc], Bg[tt][kc], accG[i][tt], 0, 0, 0);
                    accC[i][tt] = __builtin_amdgcn_mfma_f32_16x16x32_bf16(a2[i][kc], Bc[tt][kc], accC[i][tt], 0, 0, 0);
                }
#pragma unroll
        for (int tt = 0; tt < 2; ++tt) {
            int col = (2 * w + tt) * 16 + l16;
            float bg = b0[col];
            float bc = b3[col];
#pragma unroll
            for (int i = 0; i < 4; ++i)
#pragma unroll
                for (int r = 0; r < 4; ++r) {
                    int row = m0 + i * 16 + quad * 4 + r;
                    if (row < n) {
                        size_t idx = (size_t)row * WIDTH + col;
                        Gb[idx] = f2b(gelu_fast(accG[i][tt][r] + bg));
                        Cb[idx] = f2b(accC[i][tt][r] + bc);
                    }
                }
        }
    }
    if (scal[0] != 0.0f) {
        bf16x8 Ba[2][4], Bbf[2][4];
#pragma unroll
        for (int tt = 0; tt < 2; ++tt)
#pragma unroll
            for (int kc = 0; kc < 4; ++kc) {
                int row = (2 * w + tt) * 16 + l16;
                Ba[tt][kc]  = *(const bf16x8*)(w1T + row * 128 + kc * 32 + quad * 8);
                Bbf[tt][kc] = *(const bf16x8*)(w2T + row * 128 + kc * 32 + quad * 8);
            }
        f32x4 accA[4][2], accB[4][2];
#pragma unroll
        for (int i = 0; i < 4; ++i)
#pragma unroll
            for (int tt = 0; tt < 2; ++tt) {
                accA[i][tt] = (f32x4){0.f,0.f,0.f,0.f};
                accB[i][tt] = (f32x4){0.f,0.f,0.f,0.f};
            }
#pragma unroll
        for (int kc = 0; kc < 4; ++kc)
#pragma unroll
            for (int i = 0; i < 4; ++i)
#pragma unroll
                for (int tt = 0; tt < 2; ++tt) {
                    accA[i][tt] = __builtin_amdgcn_mfma_f32_16x16x32_bf16(a2[i][kc], Ba[tt][kc],  accA[i][tt], 0, 0, 0);
                    accB[i][tt] = __builtin_amdgcn_mfma_f32_16x16x32_bf16(a2[i][kc], Bbf[tt][kc], accB[i][tt], 0, 0, 0);
                }
#pragma unroll
        for (int tt = 0; tt < 2; ++tt) {
            int col = (2 * w + tt) * 16 + l16;
            float ba = b1[col];
            float bb = b2[col];
#pragma unroll
            for (int i = 0; i < 4; ++i)
#pragma unroll
                for (int r = 0; r < 4; ++r) {
                    int row = m0 + i * 16 + quad * 4 + r;
                    if (row < n) {
                        size_t idx = (size_t)row * WIDTH + col;
                        A[idx]  = accA[i][tt][r] + ba;
                        Bb[idx] = f2b(accB[i][tt][r] + bb);
                    }
                }
        }
    }
}

// ---------------------------------------------------------------------------
// k_agg: one wave per node; lane L owns cols {2L, 2L+1} (bf16-pair loads).
// ---------------------------------------------------------------------------
__global__ void __launch_bounds__(256)
k_agg(const int* __restrict__ offsets, const unsigned* __restrict__ s_pk,
      const float* __restrict__ A, const short* __restrict__ Bb,
      const short* __restrict__ Cb, const float* __restrict__ Uc,
      const float* __restrict__ scal, const short* __restrict__ Gb,
      short* __restrict__ hb, int n) {
    int wid = threadIdx.x >> 6;
    int L   = threadIdx.x & 63;
    int node = blockIdx.x * 4 + wid;
    if (node >= n) return;
    int start = offsets[node];
    int end   = offsets[node + 1];

    const unsigned* Cb32 = (const unsigned*)Cb;
    const unsigned* Bb32 = (const unsigned*)Bb;
    const float2* U0c2 = (const float2*)(Uc);
    const float2* U1c2 = (const float2*)(Uc + (size_t)NCOMBO * WIDTH);
    const float2* U2c2 = (const float2*)(Uc + 2 * (size_t)NCOMBO * WIDTH);

    float i0 = scal[0], i1 = scal[1];
    float acc0 = 0.0f, acc1 = 0.0f;

    if (i0 == 0.0f) {
        int p = start;
        for (; p + 2 <= end; p += 2) {
            unsigned pk0 = s_pk[p], pk1 = s_pk[p + 1];
            unsigned sA = pk0 & 0x1FFFFu, cA = pk0 >> 17;
            unsigned sB = pk1 & 0x1FFFFu, cB = pk1 >> 17;
            unsigned cc0 = Cb32[sA * 64 + L];
            float2   uu0 = U2c2[cA * 64 + L];
            unsigned cc1 = Cb32[sB * 64 + L];
            float2   uu1 = U2c2[cB * 64 + L];
            acc0 += gelu_fast(b2f_lo(cc0) + uu0.x);
            acc1 += gelu_fast(b2f_hi(cc0) + uu0.y);
            acc0 += gelu_fast(b2f_lo(cc1) + uu1.x);
            acc1 += gelu_fast(b2f_hi(cc1) + uu1.y);
        }
        if (p < end) {
            unsigned pk0 = s_pk[p];
            unsigned sA = pk0 & 0x1FFFFu, cA = pk0 >> 17;
            unsigned cc0 = Cb32[sA * 64 + L];
            float2   uu0 = U2c2[cA * 64 + L];
            acc0 += gelu_fast(b2f_lo(cc0) + uu0.x);
            acc1 += gelu_fast(b2f_hi(cc0) + uu0.y);
        }
        float s = __expf(i1);
        acc0 *= s; acc1 *= s;
    } else {
        float2 av = *(const float2*)(A + (size_t)node * WIDTH + 2 * L);
        for (int p = start; p < end; ++p) {
            unsigned pk = s_pk[p];
            unsigned sA = pk & 0x1FFFFu, cA = pk >> 17;
            float2 u0 = U0c2[cA * 64 + L];
            float2 u1 = U1c2[cA * 64 + L];
            float2 u2 = U2c2[cA * 64 + L];
            unsigned bb = Bb32[sA * 64 + L];
            unsigned cc = Cb32[sA * 64 + L];
            float q0 = av.x + u0.x, q1 = av.y + u0.y;
            float k0 = b2f_lo(bb) + u1.x, k1 = b2f_hi(bb) + u1.y;
            float v0 = gelu_fast(b2f_lo(cc) + u2.x);
            float v1 = gelu_fast(b2f_hi(cc) + u2.y);
            float s = q0 * k0 + q1 * k1;
            s += __shfl_xor(s, 1);
            s += __shfl_xor(s, 2);
            s += __shfl_xor(s, 4);
            s += __shfl_xor(s, 8);
            s += __shfl_xor(s, 16);
            float att = __expf(s * 0.125f * i0 + i1);
            acc0 += v0 * att;
            acc1 += v1 * att;
        }
    }
    unsigned g = ((const unsigned*)Gb)[(size_t)node * 64 + L];
    ((unsigned*)hb)[(size_t)node * 64 + L] = pack2(b2f_lo(g) + acc0, b2f_hi(g) + acc1);
}

// ---------------------------------------------------------------------------
// k_post v2 (B-stationary): out = x + h @ post_w + post_b.
// Wave w: all 64 rows x col-tiles {2w,2w+1}; postT frags prefetched (8 loads).
// ---------------------------------------------------------------------------
__global__ void __launch_bounds__(256, 2) k_post(
        const float* __restrict__ x, const short* __restrict__ hb,
        const short* __restrict__ postT, const float* __restrict__ post_b,
        float* __restrict__ out, int n) {
    int w    = threadIdx.x >> 6;
    int lane = threadIdx.x & 63;
    int quad = lane >> 4, l16 = lane & 15;
    int m0   = blockIdx.x * 64;

    bf16x8 Bp[2][4];
#pragma unroll
    for (int tt = 0; tt < 2; ++tt)
#pragma unroll
        for (int kc = 0; kc < 4; ++kc) {
            int row = (2 * w + tt) * 16 + l16;
            Bp[tt][kc] = *(const bf16x8*)(postT + row * 128 + kc * 32 + quad * 8);
        }

    bf16x8 a[4][4];
#pragma unroll
    for (int i = 0; i < 4; ++i) {
        int mA = min(m0 + i * 16 + l16, n - 1);
#pragma unroll
        for (int kc = 0; kc < 4; ++kc)
            a[i][kc] = *(const bf16x8*)(hb + (size_t)mA * WIDTH + kc * 32 + quad * 8);
    }

    f32x4 acc[4][2];
#pragma unroll
    for (int i = 0; i < 4; ++i)
#pragma unroll
        for (int tt = 0; tt < 2; ++tt) acc[i][tt] = (f32x4){0.f,0.f,0.f,0.f};
#pragma unroll
    for (int kc = 0; kc < 4; ++kc)
#pragma unroll
        for (int i = 0; i < 4; ++i)
#pragma unroll
            for (int tt = 0; tt < 2; ++tt)
                acc[i][tt] = __builtin_amdgcn_mfma_f32_16x16x32_bf16(a[i][kc], Bp[tt][kc], acc[i][tt], 0, 0, 0);

#pragma unroll
    for (int tt = 0; tt < 2; ++tt) {
        int col = (2 * w + tt) * 16 + l16;
        float bv = post_b[col];
#pragma unroll
        for (int i = 0; i < 4; ++i)
#pragma unroll
            for (int r = 0; r < 4; ++r) {
                int row = m0 + i * 16 + quad * 4 + r;
                if (row < n) {
                    size_t idx = (size_t)row * WIDTH + col;
                    out[idx] = x[idx] + acc[i][tt][r] + bv;
                }
            }
    }
}

extern "C" void kernel_launch(void* const* d_in, const int* in_sizes, int n_in,
                              void* d_out, int out_size, void* d_ws, size_t ws_size,
                              hipStream_t stream) {
    const float* x      = (const float*)d_in[0];
    const int*   eidx   = (const int*)d_in[1];
    const int*   eattr  = (const int*)d_in[2];
    const float* pre_w  = (const float*)d_in[3];
    const float* pre_b  = (const float*)d_in[4];
    const float* msg0_w = (const float*)d_in[5];
    const float* msg0_b = (const float*)d_in[6];
    const float* msg1_w = (const float*)d_in[7];
    const float* msg1_b = (const float*)d_in[8];
    const float* msg2_w = (const float*)d_in[9];
    const float* msg2_b = (const float*)d_in[10];
    const float* msg3_w = (const float*)d_in[11];
    const float* msg3_b = (const float*)d_in[12];
    const float* r0w    = (const float*)d_in[13];
    const float* r0b    = (const float*)d_in[14];
    const float* r1w    = (const float*)d_in[15];
    const float* r1b    = (const float*)d_in[16];
    const float* r2w    = (const float*)d_in[17];
    const float* r2b    = (const float*)d_in[18];
    const float* post_w = (const float*)d_in[19];
    const float* post_b = (const float*)d_in[20];
    const float* emb0   = (const float*)d_in[21];
    const float* emb1   = (const float*)d_in[22];
    const float* emb2   = (const float*)d_in[23];
    const float* emb3   = (const float*)d_in[24];
    const float* einit  = (const float*)d_in[25];
    const float* init0  = (const float*)d_in[26];

    int n = in_sizes[0] / WIDTH;
    int E = in_sizes[2] / 4;
    size_t NW = (size_t)n * WIDTH;

    float* ws   = (float*)d_ws;
    float* A    = ws;                              // [N,128] f32 (full path only)
    float* U    = ws + NW;                         // [3][34][128]
    float* Uc   = U + 3 * 34 * WIDTH;              // [3][NCOMBO][128]
    float* scal = Uc + 3 * (size_t)NCOMBO * WIDTH; // [2]
    short* sw   = (short*)(scal + 2);
    short* preT  = sw;                             // 6 x [128][128] bf16 weights^T
    short* w0T   = sw + 16384;
    short* w1T   = sw + 2 * 16384;
    short* w2T   = sw + 3 * 16384;
    short* w3T   = sw + 4 * 16384;
    short* postT = sw + 5 * 16384;
    short* Bb    = sw + 6 * 16384;                 // [N,128] bf16 (full path)
    short* Cb    = Bb + NW;                        // [N,128] bf16
    short* Gb    = Cb + NW;                        // [N,128] bf16
    short* hb    = Gb + NW;                        // [N,128] bf16
    int*      ib       = (int*)(hb + NW);
    int*      offsets  = ib;                       // n+1
    int*      counts   = offsets + (n + 1);        // n
    int*      lscan    = counts + n;               // n
    int*      partials = lscan + n;                // <=1024
    int*      rank     = partials + 1024;          // E
    unsigned* s_pk     = (unsigned*)(rank + E);    // E

    int prep_total = 6 * 16384 + 3 * 34 * WIDTH + n;
    k_prep<<<(prep_total + 255) / 256, 256, 0, stream>>>(
        einit, init0, emb0, emb1, emb2, emb3,
        r0w, r0b, r1w, r1b, r2w, r2b,
        pre_w, msg0_w, msg1_w, msg2_w, msg3_w, post_w,
        preT, w0T, w1T, w2T, w3T, postT, U, scal, counts, n);
    k_prepc<<<3 * NCOMBO, 128, 0, stream>>>(U, init0, Uc);

    int eb = (E + 255) / 256;
    k_hist<<<eb, 256, 0, stream>>>(eidx, counts, rank, E);
    int sb = (n + 255) / 256;
    k_scan1<<<sb, 256, 0, stream>>>(counts, lscan, partials, n);
    k_scan2<<<1, 1024, 0, stream>>>(partials, sb, offsets, n);
    k_scan3<<<sb, 256, 0, stream>>>(counts, lscan, partials, offsets, n);
    k_scatter<<<eb, 256, 0, stream>>>(eidx, eattr, offsets, rank, s_pk, E);

    int gb = (n + 63) / 64;
    k_gemm12<<<gb, 256, 0, stream>>>(x, preT, pre_b, w0T, msg0_b, w1T, msg1_b,
                                     w2T, msg2_b, w3T, msg3_b, scal, Gb, A, Bb, Cb, n);
    k_agg<<<(n + 3) / 4, 256, 0, stream>>>(offsets, s_pk, A, Bb, Cb, Uc, scal, Gb, hb, n);
    k_post<<<gb, 256, 0, stream>>>(x, hb, postT, post_b, (float*)d_out, n);
}

// Round 9
// 247.548 us; speedup vs baseline: 5.2710x; 1.1325x over previous
//
#include <hip/hip_runtime.h>
#include <cstdint>

#define WIDTH 128
#define NCOMBO 2268   // 6*7*3*18 attr-combo rows
#define XSL 136       // bf16 LDS tile row stride (128 + 8 pad)
#define OSL 132       // f32 LDS tile row stride (128 + 4 pad)

typedef short bf16x8 __attribute__((ext_vector_type(8)));
typedef float f32x4  __attribute__((ext_vector_type(4)));

// gelu(v) = v * sigmoid(2u): ~9 VALU ops, inf-safe.
__device__ __forceinline__ float gelu_fast(float v) {
    float e = __expf(v * __builtin_fmaf(v * v, 0.0713548f, 1.5957691f));
    return v - v * __builtin_amdgcn_rcpf(e + 1.0f);
}
__device__ __forceinline__ short f2b(float f) {
    unsigned u = __float_as_uint(f);
    unsigned r = (u + 0x7FFFu + ((u >> 16) & 1u)) >> 16;
    return (short)r;
}
__device__ __forceinline__ float b2f_lo(unsigned u) { return __uint_as_float(u << 16); }
__device__ __forceinline__ float b2f_hi(unsigned u) { return __uint_as_float(u & 0xFFFF0000u); }
__device__ __forceinline__ unsigned pack2(float lo, float hi) {
    return (unsigned)(unsigned short)f2b(lo) | ((unsigned)(unsigned short)f2b(hi) << 16);
}

// ---------------------------------------------------------------------------
// k_prep: (a) 6 weight mats -> bf16 FRAGMENT-ORDER tables:
//   F[r] with r = t*2048 + kc*512 + lane*8 + j  holds W[k][n],
//   n = t*16 + (lane&15), k = kc*32 + (lane>>4)*8 + j.
//   => a B-frag load is 64 consecutive 16B chunks (fully coalesced).
// (b) U tables [3][34][128]; (c) zero counts; (d) scal.
// ---------------------------------------------------------------------------
__global__ void k_prep(const float* __restrict__ einit, const float* __restrict__ init0,
                       const float* __restrict__ emb0, const float* __restrict__ emb1,
                       const float* __restrict__ emb2, const float* __restrict__ emb3,
                       const float* __restrict__ r0w, const float* __restrict__ r0b,
                       const float* __restrict__ r1w, const float* __restrict__ r1b,
                       const float* __restrict__ r2w, const float* __restrict__ r2b,
                       const float* __restrict__ pw0, const float* __restrict__ pw1,
                       const float* __restrict__ pw2, const float* __restrict__ pw3,
                       const float* __restrict__ pw4, const float* __restrict__ pw5,
                       short* __restrict__ o0, short* __restrict__ o1,
                       short* __restrict__ o2, short* __restrict__ o3,
                       short* __restrict__ o4, short* __restrict__ o5,
                       float* __restrict__ U, float* __restrict__ scal,
                       int* __restrict__ counts, int n) {
    int tid = blockIdx.x * blockDim.x + threadIdx.x;
    if (tid == 0) { scal[0] = init0[0]; scal[1] = init0[1]; }
    const int TOTW = 6 * 16384;
    const int TOTU = 3 * 34 * WIDTH;
    if (tid < TOTW) {
        int which = tid >> 14;
        int r = tid & 16383;
        int t    = r >> 11;
        int kc   = (r >> 9) & 3;
        int lane = (r >> 3) & 63;
        int j    = r & 7;
        int k  = kc * 32 + ((lane >> 4) << 3) + j;
        int nn = (t << 4) + (lane & 15);
        const float* w = (which == 0) ? pw0 : (which == 1) ? pw1 : (which == 2) ? pw2
                       : (which == 3) ? pw3 : (which == 4) ? pw4 : pw5;
        short* o = (which == 0) ? o0 : (which == 1) ? o1 : (which == 2) ? o2
                 : (which == 3) ? o3 : (which == 4) ? o4 : o5;
        o[r] = f2b(w[k * 128 + nn]);
    } else if (tid < TOTW + TOTU) {
        int idx = tid - TOTW;
        float e0 = expf(einit[0]), e1 = expf(einit[1]), e2 = expf(einit[2]), e3 = expf(einit[3]);
        float inv = 1.0f / sqrtf(e0 + e1 + e2 + e3);
        float xw[4] = {e0 * inv, e1 * inv, e2 * inv, e3 * inv};
        float se = expf(init0[2]);
        float sv = expf(init0[3]);
        int r   = idx / (34 * WIDTH);
        int rem = idx - r * (34 * WIDTH);
        int g   = rem / WIDTH;
        int j   = rem - g * WIDTH;
        int cc, base;
        if (g >= 16)      { cc = 3; base = 16; }
        else if (g >= 13) { cc = 2; base = 13; }
        else if (g >= 6)  { cc = 1; base = 6; }
        else              { cc = 0; base = 0; }
        int i = g - base;
        const float* em = (cc == 0) ? emb0 : (cc == 1) ? emb1 : (cc == 2) ? emb2 : emb3;
        const float* w  = (r == 0) ? r0w : (r == 1) ? r1w : r2w;
        const float* rb = (r == 0) ? r0b : (r == 1) ? r1b : r2b;
        float s = (r == 2) ? sv : se;
        float acc = 0.0f;
        const float* erow = em + i * 64;
        for (int d = 0; d < 64; ++d) acc += erow[d] * w[d * WIDTH + j];
        float val = s * xw[cc] * acc;
        if (cc == 0) val += s * rb[j];
        U[idx] = val;
    } else if (tid < TOTW + TOTU + n) {
        counts[tid - TOTW - TOTU] = 0;
    }
}

// ---------------------------------------------------------------------------
// k_prepc: Uc[r][combo][j] = sum of 4 U rows; fast path skips r=0,1.
// ---------------------------------------------------------------------------
__global__ void k_prepc(const float* __restrict__ U, const float* __restrict__ init0,
                        float* __restrict__ Uc) {
    int bi = blockIdx.x;
    int r  = bi / NCOMBO;
    if (r < 2 && init0[0] == 0.0f) return;
    int cb = bi - r * NCOMBO;
    int a  = cb / 378;
    int rm = cb - a * 378;
    int b  = rm / 54;
    rm -= b * 54;
    int c  = rm / 18;
    int d  = rm - c * 18;
    int j  = threadIdx.x;
    const float* Ur = U + r * 34 * WIDTH;
    Uc[(size_t)bi * WIDTH + j] = Ur[a * WIDTH + j] + Ur[(6 + b) * WIDTH + j]
                               + Ur[(13 + c) * WIDTH + j] + Ur[(16 + d) * WIDTH + j];
}

// ---------------------------------------------------------------------------
// Sort-by-dst: hist(+rank) -> 3-phase scan -> atomic-free scatter.
// ---------------------------------------------------------------------------
__global__ void k_hist(const int* __restrict__ edge_index, int* __restrict__ counts,
                       int* __restrict__ rank, int E) {
    int e = blockIdx.x * blockDim.x + threadIdx.x;
    if (e >= E) return;
    rank[e] = atomicAdd(&counts[edge_index[E + e]], 1);
}

__global__ void k_scan1(const int* __restrict__ counts, int* __restrict__ lscan,
                        int* __restrict__ partials, int n) {
    __shared__ int s[256];
    int t = threadIdx.x;
    int i = blockIdx.x * 256 + t;
    int v = (i < n) ? counts[i] : 0;
    s[t] = v;
    __syncthreads();
    for (int d = 1; d < 256; d <<= 1) {
        int u = (t >= d) ? s[t - d] : 0;
        __syncthreads();
        s[t] += u;
        __syncthreads();
    }
    if (i < n) lscan[i] = s[t];
    if (t == 255) partials[blockIdx.x] = s[255];
}

__global__ void k_scan2(int* __restrict__ partials, int nb,
                        int* __restrict__ offsets, int n) {
    __shared__ int s[1024];
    int t = threadIdx.x;
    int v = (t < nb) ? partials[t] : 0;
    s[t] = v;
    __syncthreads();
    for (int d = 1; d < 1024; d <<= 1) {
        int u = (t >= d) ? s[t - d] : 0;
        __syncthreads();
        s[t] += u;
        __syncthreads();
    }
    if (t < nb) partials[t] = s[t] - v;
    if (t == 1023) offsets[n] = s[1023];
}

__global__ void k_scan3(const int* __restrict__ counts, const int* __restrict__ lscan,
                        const int* __restrict__ partials, int* __restrict__ offsets, int n) {
    int i = blockIdx.x * 256 + threadIdx.x;
    if (i >= n) return;
    offsets[i] = partials[blockIdx.x] + lscan[i] - counts[i];
}

__global__ void k_scatter(const int* __restrict__ edge_index, const int* __restrict__ edge_attr,
                          const int* __restrict__ offsets, const int* __restrict__ rank,
                          unsigned* __restrict__ s_pk, int E) {
    int e = blockIdx.x * blockDim.x + threadIdx.x;
    if (e >= E) return;
    int src = edge_index[e];
    int dst = edge_index[E + e];
    int4 at = ((const int4*)edge_attr)[e];
    int combo = ((at.x * 7 + at.y) * 3 + at.z) * 18 + at.w;
    s_pk[offsets[dst] + rank[e]] = (unsigned)src | ((unsigned)combo << 17);
}

// ---------------------------------------------------------------------------
// k_gemm12 v3: all global traffic coalesced.
//  coop-load x -> xs_raw (bf16) | stage1 pre-GEMM+LN -> xs_xx | stage2
//  B-stationary (frag-order weights, coalesced) | results staged in LDS,
//  coop-stored 16B/lane.  Full path (scal[0]!=0) stores A/Bb directly.
// ---------------------------------------------------------------------------
__global__ void __launch_bounds__(256, 2) k_gemm12(
        const float* __restrict__ x,
        const short* __restrict__ preF, const float* __restrict__ pre_b,
        const short* __restrict__ w0F, const float* __restrict__ b0,
        const short* __restrict__ w1F, const float* __restrict__ b1,
        const short* __restrict__ w2F, const float* __restrict__ b2,
        const short* __restrict__ w3F, const float* __restrict__ b3,
        const float* __restrict__ scal,
        short* __restrict__ Gb, float* __restrict__ A,
        short* __restrict__ Bb, short* __restrict__ Cb, int n) {
    __shared__ short xs_raw[64 * XSL];
    __shared__ short xs_xx[64 * XSL];
    int tid  = threadIdx.x;
    int w    = tid >> 6;
    int lane = tid & 63;
    int quad = lane >> 4, l16 = lane & 15;
    int m0   = blockIdx.x * 64;

    // prefetch stage-2 B-frags (col tiles 2w,2w+1), coalesced frag-order
    bf16x8 Bg[2][4], Bc[2][4];
#pragma unroll
    for (int tt = 0; tt < 2; ++tt)
#pragma unroll
        for (int kc = 0; kc < 4; ++kc) {
            int fo = (((2 * w + tt) * 4 + kc) * 64 + lane) * 8;
            Bg[tt][kc] = *(const bf16x8*)(w0F + fo);
            Bc[tt][kc] = *(const bf16x8*)(w3F + fo);
        }

    // coop load x -> xs_raw (bf16), fully coalesced
#pragma unroll
    for (int it = 0; it < 8; ++it) {
        int fi  = it * 256 + tid;
        int row = fi >> 5, c4 = fi & 31;
        int gr  = min(m0 + row, n - 1);
        float4 v = ((const float4*)x)[(size_t)gr * 32 + c4];
        uint2 p;
        p.x = pack2(v.x, v.y);
        p.y = pack2(v.z, v.w);
        *(uint2*)(&xs_raw[row * XSL + c4 * 4]) = p;
    }
    __syncthreads();

    // stage 1: pre GEMM (wave rows w*16..+15) + in-register LN -> xs_xx
    {
        bf16x8 a[4];
#pragma unroll
        for (int kc = 0; kc < 4; ++kc)
            a[kc] = *(const bf16x8*)(&xs_raw[(w * 16 + l16) * XSL + kc * 32 + quad * 8]);
        f32x4 acc[8];
#pragma unroll
        for (int t = 0; t < 8; ++t) acc[t] = (f32x4){0.f, 0.f, 0.f, 0.f};
#pragma unroll
        for (int kc = 0; kc < 4; ++kc)
#pragma unroll
            for (int t = 0; t < 8; ++t) {
                bf16x8 b = *(const bf16x8*)(preF + ((t * 4 + kc) * 64 + lane) * 8);
                acc[t] = __builtin_amdgcn_mfma_f32_16x16x32_bf16(a[kc], b, acc[t], 0, 0, 0);
            }
#pragma unroll
        for (int t = 0; t < 8; ++t) {
            float bv = pre_b[t * 16 + l16];
#pragma unroll
            for (int r = 0; r < 4; ++r) acc[t][r] += bv;
        }
#pragma unroll
        for (int r = 0; r < 4; ++r) {
            float s = 0.f, s2 = 0.f;
#pragma unroll
            for (int t = 0; t < 8; ++t) { float v = acc[t][r]; s += v; s2 += v * v; }
            s  += __shfl_xor(s, 1);  s2 += __shfl_xor(s2, 1);
            s  += __shfl_xor(s, 2);  s2 += __shfl_xor(s2, 2);
            s  += __shfl_xor(s, 4);  s2 += __shfl_xor(s2, 4);
            s  += __shfl_xor(s, 8);  s2 += __shfl_xor(s2, 8);
            float m   = s * (1.0f / WIDTH);
            float var = s2 * (1.0f / WIDTH) - m * m;
            float rs  = rsqrtf(var + 1e-5f);
#pragma unroll
            for (int t = 0; t < 8; ++t) acc[t][r] = (acc[t][r] - m) * rs;
        }
        int rowb = w * 16 + quad * 4;
#pragma unroll
        for (int t = 0; t < 8; ++t)
#pragma unroll
            for (int r = 0; r < 4; ++r)
                xs_xx[(rowb + r) * XSL + t * 16 + l16] = f2b(acc[t][r]);
    }
    __syncthreads();

    // stage 2: A-frags (all 4 m-subtiles) from xs_xx
    bf16x8 a2[4][4];
#pragma unroll
    for (int i = 0; i < 4; ++i)
#pragma unroll
        for (int kc = 0; kc < 4; ++kc)
            a2[i][kc] = *(const bf16x8*)(&xs_xx[(i * 16 + l16) * XSL + kc * 32 + quad * 8]);
    __syncthreads();   // xs_raw/xs_xx free for result staging

    {
        f32x4 accG[4][2], accC[4][2];
#pragma unroll
        for (int i = 0; i < 4; ++i)
#pragma unroll
            for (int tt = 0; tt < 2; ++tt) {
                accG[i][tt] = (f32x4){0.f,0.f,0.f,0.f};
                accC[i][tt] = (f32x4){0.f,0.f,0.f,0.f};
            }
#pragma unroll
        for (int kc = 0; kc < 4; ++kc)
#pragma unroll
            for (int i = 0; i < 4; ++i)
#pragma unroll
                for (int tt = 0; tt < 2; ++tt) {
                    accG[i][tt] = __builtin_amdgcn_mfma_f32_16x16x32_bf16(a2[i][kc], Bg[tt][kc], accG[i][tt], 0, 0, 0);
                    accC[i][tt] = __builtin_amdgcn_mfma_f32_16x16x32_bf16(a2[i][kc], Bc[tt][kc], accC[i][tt], 0, 0, 0);
                }
        // stage results into LDS (G -> xs_raw, C -> xs_xx)
#pragma unroll
        for (int tt = 0; tt < 2; ++tt) {
            int col = (2 * w + tt) * 16 + l16;
            float bg = b0[col];
            float bc = b3[col];
#pragma unroll
            for (int i = 0; i < 4; ++i)
#pragma unroll
                for (int r = 0; r < 4; ++r) {
                    int row = i * 16 + quad * 4 + r;
                    xs_raw[row * XSL + col] = f2b(gelu_fast(accG[i][tt][r] + bg));
                    xs_xx[row * XSL + col]  = f2b(accC[i][tt][r] + bc);
                }
        }
    }
    __syncthreads();

    // coop store G, C: 16B per lane, coalesced
#pragma unroll
    for (int it = 0; it < 4; ++it) {
        int si  = it * 256 + tid;
        int row = si >> 4, c8 = si & 15;
        if (m0 + row < n) {
            *(bf16x8*)(Gb + (size_t)(m0 + row) * WIDTH + c8 * 8) = *(const bf16x8*)(&xs_raw[row * XSL + c8 * 8]);
            *(bf16x8*)(Cb + (size_t)(m0 + row) * WIDTH + c8 * 8) = *(const bf16x8*)(&xs_xx[row * XSL + c8 * 8]);
        }
    }

    // full path (rare): A (f32) and Bb direct stores
    if (scal[0] != 0.0f) {
        bf16x8 Ba[2][4], Bbf[2][4];
#pragma unroll
        for (int tt = 0; tt < 2; ++tt)
#pragma unroll
            for (int kc = 0; kc < 4; ++kc) {
                int fo = (((2 * w + tt) * 4 + kc) * 64 + lane) * 8;
                Ba[tt][kc]  = *(const bf16x8*)(w1F + fo);
                Bbf[tt][kc] = *(const bf16x8*)(w2F + fo);
            }
        f32x4 accA[4][2], accB[4][2];
#pragma unroll
        for (int i = 0; i < 4; ++i)
#pragma unroll
            for (int tt = 0; tt < 2; ++tt) {
                accA[i][tt] = (f32x4){0.f,0.f,0.f,0.f};
                accB[i][tt] = (f32x4){0.f,0.f,0.f,0.f};
            }
#pragma unroll
        for (int kc = 0; kc < 4; ++kc)
#pragma unroll
            for (int i = 0; i < 4; ++i)
#pragma unroll
                for (int tt = 0; tt < 2; ++tt) {
                    accA[i][tt] = __builtin_amdgcn_mfma_f32_16x16x32_bf16(a2[i][kc], Ba[tt][kc],  accA[i][tt], 0, 0, 0);
                    accB[i][tt] = __builtin_amdgcn_mfma_f32_16x16x32_bf16(a2[i][kc], Bbf[tt][kc], accB[i][tt], 0, 0, 0);
                }
#pragma unroll
        for (int tt = 0; tt < 2; ++tt) {
            int col = (2 * w + tt) * 16 + l16;
            float ba = b1[col];
            float bb = b2[col];
#pragma unroll
            for (int i = 0; i < 4; ++i)
#pragma unroll
                for (int r = 0; r < 4; ++r) {
                    int row = m0 + i * 16 + quad * 4 + r;
                    if (row < n) {
                        size_t idx = (size_t)row * WIDTH + col;
                        A[idx]  = accA[i][tt][r] + ba;
                        Bb[idx] = f2b(accB[i][tt][r] + bb);
                    }
                }
        }
    }
}

// ---------------------------------------------------------------------------
// k_agg: one wave per node; lane L owns cols {2L, 2L+1} (bf16-pair loads).
// ---------------------------------------------------------------------------
__global__ void __launch_bounds__(256)
k_agg(const int* __restrict__ offsets, const unsigned* __restrict__ s_pk,
      const float* __restrict__ A, const short* __restrict__ Bb,
      const short* __restrict__ Cb, const float* __restrict__ Uc,
      const float* __restrict__ scal, const short* __restrict__ Gb,
      short* __restrict__ hb, int n) {
    int wid = threadIdx.x >> 6;
    int L   = threadIdx.x & 63;
    int node = blockIdx.x * 4 + wid;
    if (node >= n) return;
    int start = offsets[node];
    int end   = offsets[node + 1];

    const unsigned* Cb32 = (const unsigned*)Cb;
    const unsigned* Bb32 = (const unsigned*)Bb;
    const float2* U0c2 = (const float2*)(Uc);
    const float2* U1c2 = (const float2*)(Uc + (size_t)NCOMBO * WIDTH);
    const float2* U2c2 = (const float2*)(Uc + 2 * (size_t)NCOMBO * WIDTH);

    float i0 = scal[0], i1 = scal[1];
    float acc0 = 0.0f, acc1 = 0.0f;

    if (i0 == 0.0f) {
        int p = start;
        for (; p + 2 <= end; p += 2) {
            unsigned pk0 = s_pk[p], pk1 = s_pk[p + 1];
            unsigned sA = pk0 & 0x1FFFFu, cA = pk0 >> 17;
            unsigned sB = pk1 & 0x1FFFFu, cB = pk1 >> 17;
            unsigned cc0 = Cb32[sA * 64 + L];
            float2   uu0 = U2c2[cA * 64 + L];
            unsigned cc1 = Cb32[sB * 64 + L];
            float2   uu1 = U2c2[cB * 64 + L];
            acc0 += gelu_fast(b2f_lo(cc0) + uu0.x);
            acc1 += gelu_fast(b2f_hi(cc0) + uu0.y);
            acc0 += gelu_fast(b2f_lo(cc1) + uu1.x);
            acc1 += gelu_fast(b2f_hi(cc1) + uu1.y);
        }
        if (p < end) {
            unsigned pk0 = s_pk[p];
            unsigned sA = pk0 & 0x1FFFFu, cA = pk0 >> 17;
            unsigned cc0 = Cb32[sA * 64 + L];
            float2   uu0 = U2c2[cA * 64 + L];
            acc0 += gelu_fast(b2f_lo(cc0) + uu0.x);
            acc1 += gelu_fast(b2f_hi(cc0) + uu0.y);
        }
        float s = __expf(i1);
        acc0 *= s; acc1 *= s;
    } else {
        float2 av = *(const float2*)(A + (size_t)node * WIDTH + 2 * L);
        for (int p = start; p < end; ++p) {
            unsigned pk = s_pk[p];
            unsigned sA = pk & 0x1FFFFu, cA = pk >> 17;
            float2 u0 = U0c2[cA * 64 + L];
            float2 u1 = U1c2[cA * 64 + L];
            float2 u2 = U2c2[cA * 64 + L];
            unsigned bb = Bb32[sA * 64 + L];
            unsigned cc = Cb32[sA * 64 + L];
            float q0 = av.x + u0.x, q1 = av.y + u0.y;
            float k0 = b2f_lo(bb) + u1.x, k1 = b2f_hi(bb) + u1.y;
            float v0 = gelu_fast(b2f_lo(cc) + u2.x);
            float v1 = gelu_fast(b2f_hi(cc) + u2.y);
            float s = q0 * k0 + q1 * k1;
            s += __shfl_xor(s, 1);
            s += __shfl_xor(s, 2);
            s += __shfl_xor(s, 4);
            s += __shfl_xor(s, 8);
            s += __shfl_xor(s, 16);
            float att = __expf(s * 0.125f * i0 + i1);
            acc0 += v0 * att;
            acc1 += v1 * att;
        }
    }
    unsigned g = ((const unsigned*)Gb)[(size_t)node * 64 + L];
    ((unsigned*)hb)[(size_t)node * 64 + L] = pack2(b2f_lo(g) + acc0, b2f_hi(g) + acc1);
}

// ---------------------------------------------------------------------------
// k_post v3: coop-load hb -> LDS, B-stationary MFMA (frag-order postT),
// result+bias staged to f32 LDS tile, coop out = x + tile (coalesced).
// ---------------------------------------------------------------------------
__global__ void __launch_bounds__(256, 2) k_post(
        const float* __restrict__ x, const short* __restrict__ hb,
        const short* __restrict__ postF, const float* __restrict__ post_b,
        float* __restrict__ out, int n) {
    __shared__ short hs[64 * XSL];
    __shared__ float os[64 * OSL];
    int tid  = threadIdx.x;
    int w    = tid >> 6;
    int lane = tid & 63;
    int quad = lane >> 4, l16 = lane & 15;
    int m0   = blockIdx.x * 64;

    bf16x8 Bp[2][4];
#pragma unroll
    for (int tt = 0; tt < 2; ++tt)
#pragma unroll
        for (int kc = 0; kc < 4; ++kc)
            Bp[tt][kc] = *(const bf16x8*)(postF + (((2 * w + tt) * 4 + kc) * 64 + lane) * 8);

    // coop load hb -> LDS (coalesced 16B)
#pragma unroll
    for (int it = 0; it < 4; ++it) {
        int si  = it * 256 + tid;
        int row = si >> 4, c8 = si & 15;
        int gr  = min(m0 + row, n - 1);
        *(bf16x8*)(&hs[row * XSL + c8 * 8]) = *(const bf16x8*)(hb + (size_t)gr * WIDTH + c8 * 8);
    }
    __syncthreads();

    bf16x8 a[4][4];
#pragma unroll
    for (int i = 0; i < 4; ++i)
#pragma unroll
        for (int kc = 0; kc < 4; ++kc)
            a[i][kc] = *(const bf16x8*)(&hs[(i * 16 + l16) * XSL + kc * 32 + quad * 8]);

    f32x4 acc[4][2];
#pragma unroll
    for (int i = 0; i < 4; ++i)
#pragma unroll
        for (int tt = 0; tt < 2; ++tt) acc[i][tt] = (f32x4){0.f,0.f,0.f,0.f};
#pragma unroll
    for (int kc = 0; kc < 4; ++kc)
#pragma unroll
        for (int i = 0; i < 4; ++i)
#pragma unroll
            for (int tt = 0; tt < 2; ++tt)
                acc[i][tt] = __builtin_amdgcn_mfma_f32_16x16x32_bf16(a[i][kc], Bp[tt][kc], acc[i][tt], 0, 0, 0);

#pragma unroll
    for (int tt = 0; tt < 2; ++tt) {
        int col = (2 * w + tt) * 16 + l16;
        float bv = post_b[col];
#pragma unroll
        for (int i = 0; i < 4; ++i)
#pragma unroll
            for (int r = 0; r < 4; ++r)
                os[(i * 16 + quad * 4 + r) * OSL + col] = acc[i][tt][r] + bv;
    }
    __syncthreads();

    // coop: out = x + os (coalesced float4)
#pragma unroll
    for (int it = 0; it < 8; ++it) {
        int fi  = it * 256 + tid;
        int row = fi >> 5, c4 = fi & 31;
        if (m0 + row < n) {
            float4 xv = ((const float4*)x)[(size_t)(m0 + row) * 32 + c4];
            float4 av = *(const float4*)(&os[row * OSL + c4 * 4]);
            float4 ov = {xv.x + av.x, xv.y + av.y, xv.z + av.z, xv.w + av.w};
            ((float4*)out)[(size_t)(m0 + row) * 32 + c4] = ov;
        }
    }
}

extern "C" void kernel_launch(void* const* d_in, const int* in_sizes, int n_in,
                              void* d_out, int out_size, void* d_ws, size_t ws_size,
                              hipStream_t stream) {
    const float* x      = (const float*)d_in[0];
    const int*   eidx   = (const int*)d_in[1];
    const int*   eattr  = (const int*)d_in[2];
    const float* pre_w  = (const float*)d_in[3];
    const float* pre_b  = (const float*)d_in[4];
    const float* msg0_w = (const float*)d_in[5];
    const float* msg0_b = (const float*)d_in[6];
    const float* msg1_w = (const float*)d_in[7];
    const float* msg1_b = (const float*)d_in[8];
    const float* msg2_w = (const float*)d_in[9];
    const float* msg2_b = (const float*)d_in[10];
    const float* msg3_w = (const float*)d_in[11];
    const float* msg3_b = (const float*)d_in[12];
    const float* r0w    = (const float*)d_in[13];
    const float* r0b    = (const float*)d_in[14];
    const float* r1w    = (const float*)d_in[15];
    const float* r1b    = (const float*)d_in[16];
    const float* r2w    = (const float*)d_in[17];
    const float* r2b    = (const float*)d_in[18];
    const float* post_w = (const float*)d_in[19];
    const float* post_b = (const float*)d_in[20];
    const float* emb0   = (const float*)d_in[21];
    const float* emb1   = (const float*)d_in[22];
    const float* emb2   = (const float*)d_in[23];
    const float* emb3   = (const float*)d_in[24];
    const float* einit  = (const float*)d_in[25];
    const float* init0  = (const float*)d_in[26];

    int n = in_sizes[0] / WIDTH;
    int E = in_sizes[2] / 4;
    size_t NW = (size_t)n * WIDTH;

    float* ws   = (float*)d_ws;
    float* A    = ws;                              // [N,128] f32 (full path only)
    float* U    = ws + NW;                         // [3][34][128]
    float* Uc   = U + 3 * 34 * WIDTH;              // [3][NCOMBO][128]
    float* scal = Uc + 3 * (size_t)NCOMBO * WIDTH; // [2]
    short* sw   = (short*)(scal + 2);
    short* preF  = sw;                             // 6 x 16384 bf16 frag-order weights
    short* w0F   = sw + 16384;
    short* w1F   = sw + 2 * 16384;
    short* w2F   = sw + 3 * 16384;
    short* w3F   = sw + 4 * 16384;
    short* postF = sw + 5 * 16384;
    short* Bb    = sw + 6 * 16384;                 // [N,128] bf16 (full path)
    short* Cb    = Bb + NW;                        // [N,128] bf16
    short* Gb    = Cb + NW;                        // [N,128] bf16
    short* hb    = Gb + NW;                        // [N,128] bf16
    int*      ib       = (int*)(hb + NW);
    int*      offsets  = ib;                       // n+1
    int*      counts   = offsets + (n + 1);        // n
    int*      lscan    = counts + n;               // n
    int*      partials = lscan + n;                // <=1024
    int*      rank     = partials + 1024;          // E
    unsigned* s_pk     = (unsigned*)(rank + E);    // E

    int prep_total = 6 * 16384 + 3 * 34 * WIDTH + n;
    k_prep<<<(prep_total + 255) / 256, 256, 0, stream>>>(
        einit, init0, emb0, emb1, emb2, emb3,
        r0w, r0b, r1w, r1b, r2w, r2b,
        pre_w, msg0_w, msg1_w, msg2_w, msg3_w, post_w,
        preF, w0F, w1F, w2F, w3F, postF, U, scal, counts, n);
    k_prepc<<<3 * NCOMBO, 128, 0, stream>>>(U, init0, Uc);

    int eb = (E + 255) / 256;
    k_hist<<<eb, 256, 0, stream>>>(eidx, counts, rank, E);
    int sb = (n + 255) / 256;
    k_scan1<<<sb, 256, 0, stream>>>(counts, lscan, partials, n);
    k_scan2<<<1, 1024, 0, stream>>>(partials, sb, offsets, n);
    k_scan3<<<sb, 256, 0, stream>>>(counts, lscan, partials, offsets, n);
    k_scatter<<<eb, 256, 0, stream>>>(eidx, eattr, offsets, rank, s_pk, E);

    int gb = (n + 63) / 64;
    k_gemm12<<<gb, 256, 0, stream>>>(x, preF, pre_b, w0F, msg0_b, w1F, msg1_b,
                                     w2F, msg2_b, w3F, msg3_b, scal, Gb, A, Bb, Cb, n);
    k_agg<<<(n + 3) / 4, 256, 0, stream>>>(offsets, s_pk, A, Bb, Cb, Uc, scal, Gb, hb, n);
    k_post<<<gb, 256, 0, stream>>>(x, hb, postF, post_b, (float*)d_out, n);
}

// Round 10
// 240.698 us; speedup vs baseline: 5.4210x; 1.0285x over previous
//
#include <hip/hip_runtime.h>
#include <cstdint>

#define WIDTH 128
#define NCOMBO 2268   // 6*7*3*18 attr-combo rows
#define XSL 136       // bf16 LDS tile row stride (128 + 8 pad)
#define OSL 132       // f32 LDS tile row stride (128 + 4 pad)

typedef short bf16x8 __attribute__((ext_vector_type(8)));
typedef float f32x4  __attribute__((ext_vector_type(4)));

// gelu(v) = v * sigmoid(2u): ~9 VALU ops, inf-safe.
__device__ __forceinline__ float gelu_fast(float v) {
    float e = __expf(v * __builtin_fmaf(v * v, 0.0713548f, 1.5957691f));
    return v - v * __builtin_amdgcn_rcpf(e + 1.0f);
}
__device__ __forceinline__ short f2b(float f) {
    unsigned u = __float_as_uint(f);
    unsigned r = (u + 0x7FFFu + ((u >> 16) & 1u)) >> 16;
    return (short)r;
}
__device__ __forceinline__ float b2f_lo(unsigned u) { return __uint_as_float(u << 16); }
__device__ __forceinline__ float b2f_hi(unsigned u) { return __uint_as_float(u & 0xFFFF0000u); }
__device__ __forceinline__ unsigned pack2(float lo, float hi) {
    return (unsigned)(unsigned short)f2b(lo) | ((unsigned)(unsigned short)f2b(hi) << 16);
}

// ---------------------------------------------------------------------------
// k_prep: (a) 6 weight mats -> bf16 FRAGMENT-ORDER tables (coalesced B-frag
// loads); (b) U tables [3][34][128]; (c) zero counts; (d) scal.
// ---------------------------------------------------------------------------
__global__ void k_prep(const float* __restrict__ einit, const float* __restrict__ init0,
                       const float* __restrict__ emb0, const float* __restrict__ emb1,
                       const float* __restrict__ emb2, const float* __restrict__ emb3,
                       const float* __restrict__ r0w, const float* __restrict__ r0b,
                       const float* __restrict__ r1w, const float* __restrict__ r1b,
                       const float* __restrict__ r2w, const float* __restrict__ r2b,
                       const float* __restrict__ pw0, const float* __restrict__ pw1,
                       const float* __restrict__ pw2, const float* __restrict__ pw3,
                       const float* __restrict__ pw4, const float* __restrict__ pw5,
                       short* __restrict__ o0, short* __restrict__ o1,
                       short* __restrict__ o2, short* __restrict__ o3,
                       short* __restrict__ o4, short* __restrict__ o5,
                       float* __restrict__ U, float* __restrict__ scal,
                       int* __restrict__ counts, int n) {
    int tid = blockIdx.x * blockDim.x + threadIdx.x;
    if (tid == 0) { scal[0] = init0[0]; scal[1] = init0[1]; }
    const int TOTW = 6 * 16384;
    const int TOTU = 3 * 34 * WIDTH;
    if (tid < TOTW) {
        int which = tid >> 14;
        int r = tid & 16383;
        int t    = r >> 11;
        int kc   = (r >> 9) & 3;
        int lane = (r >> 3) & 63;
        int j    = r & 7;
        int k  = kc * 32 + ((lane >> 4) << 3) + j;
        int nn = (t << 4) + (lane & 15);
        const float* w = (which == 0) ? pw0 : (which == 1) ? pw1 : (which == 2) ? pw2
                       : (which == 3) ? pw3 : (which == 4) ? pw4 : pw5;
        short* o = (which == 0) ? o0 : (which == 1) ? o1 : (which == 2) ? o2
                 : (which == 3) ? o3 : (which == 4) ? o4 : o5;
        o[r] = f2b(w[k * 128 + nn]);
    } else if (tid < TOTW + TOTU) {
        int idx = tid - TOTW;
        float e0 = expf(einit[0]), e1 = expf(einit[1]), e2 = expf(einit[2]), e3 = expf(einit[3]);
        float inv = 1.0f / sqrtf(e0 + e1 + e2 + e3);
        float xw[4] = {e0 * inv, e1 * inv, e2 * inv, e3 * inv};
        float se = expf(init0[2]);
        float sv = expf(init0[3]);
        int r   = idx / (34 * WIDTH);
        int rem = idx - r * (34 * WIDTH);
        int g   = rem / WIDTH;
        int j   = rem - g * WIDTH;
        int cc, base;
        if (g >= 16)      { cc = 3; base = 16; }
        else if (g >= 13) { cc = 2; base = 13; }
        else if (g >= 6)  { cc = 1; base = 6; }
        else              { cc = 0; base = 0; }
        int i = g - base;
        const float* em = (cc == 0) ? emb0 : (cc == 1) ? emb1 : (cc == 2) ? emb2 : emb3;
        const float* w  = (r == 0) ? r0w : (r == 1) ? r1w : r2w;
        const float* rb = (r == 0) ? r0b : (r == 1) ? r1b : r2b;
        float s = (r == 2) ? sv : se;
        float acc = 0.0f;
        const float* erow = em + i * 64;
        for (int d = 0; d < 64; ++d) acc += erow[d] * w[d * WIDTH + j];
        float val = s * xw[cc] * acc;
        if (cc == 0) val += s * rb[j];
        U[idx] = val;
    } else if (tid < TOTW + TOTU + n) {
        counts[tid - TOTW - TOTU] = 0;
    }
}

// ---------------------------------------------------------------------------
// k_prepc: Uc[r][combo][j] = sum of 4 U rows; fast path skips r=0,1.
// ---------------------------------------------------------------------------
__global__ void k_prepc(const float* __restrict__ U, const float* __restrict__ init0,
                        float* __restrict__ Uc) {
    int bi = blockIdx.x;
    int r  = bi / NCOMBO;
    if (r < 2 && init0[0] == 0.0f) return;
    int cb = bi - r * NCOMBO;
    int a  = cb / 378;
    int rm = cb - a * 378;
    int b  = rm / 54;
    rm -= b * 54;
    int c  = rm / 18;
    int d  = rm - c * 18;
    int j  = threadIdx.x;
    const float* Ur = U + r * 34 * WIDTH;
    Uc[(size_t)bi * WIDTH + j] = Ur[a * WIDTH + j] + Ur[(6 + b) * WIDTH + j]
                               + Ur[(13 + c) * WIDTH + j] + Ur[(16 + d) * WIDTH + j];
}

// ---------------------------------------------------------------------------
// Sort-by-dst: hist(+rank) -> 3-phase scan -> atomic-free scatter.
// ---------------------------------------------------------------------------
__global__ void k_hist(const int* __restrict__ edge_index, int* __restrict__ counts,
                       int* __restrict__ rank, int E) {
    int e = blockIdx.x * blockDim.x + threadIdx.x;
    if (e >= E) return;
    rank[e] = atomicAdd(&counts[edge_index[E + e]], 1);
}

__global__ void k_scan1(const int* __restrict__ counts, int* __restrict__ lscan,
                        int* __restrict__ partials, int n) {
    __shared__ int s[256];
    int t = threadIdx.x;
    int i = blockIdx.x * 256 + t;
    int v = (i < n) ? counts[i] : 0;
    s[t] = v;
    __syncthreads();
    for (int d = 1; d < 256; d <<= 1) {
        int u = (t >= d) ? s[t - d] : 0;
        __syncthreads();
        s[t] += u;
        __syncthreads();
    }
    if (i < n) lscan[i] = s[t];
    if (t == 255) partials[blockIdx.x] = s[255];
}

__global__ void k_scan2(int* __restrict__ partials, int nb,
                        int* __restrict__ offsets, int n) {
    __shared__ int s[1024];
    int t = threadIdx.x;
    int v = (t < nb) ? partials[t] : 0;
    s[t] = v;
    __syncthreads();
    for (int d = 1; d < 1024; d <<= 1) {
        int u = (t >= d) ? s[t - d] : 0;
        __syncthreads();
        s[t] += u;
        __syncthreads();
    }
    if (t < nb) partials[t] = s[t] - v;
    if (t == 1023) offsets[n] = s[1023];
}

__global__ void k_scan3(const int* __restrict__ counts, const int* __restrict__ lscan,
                        const int* __restrict__ partials, int* __restrict__ offsets, int n) {
    int i = blockIdx.x * 256 + threadIdx.x;
    if (i >= n) return;
    offsets[i] = partials[blockIdx.x] + lscan[i] - counts[i];
}

__global__ void k_scatter(const int* __restrict__ edge_index, const int* __restrict__ edge_attr,
                          const int* __restrict__ offsets, const int* __restrict__ rank,
                          unsigned* __restrict__ s_pk, int E) {
    int e = blockIdx.x * blockDim.x + threadIdx.x;
    if (e >= E) return;
    int src = edge_index[e];
    int dst = edge_index[E + e];
    int4 at = ((const int4*)edge_attr)[e];
    int combo = ((at.x * 7 + at.y) * 3 + at.z) * 18 + at.w;
    s_pk[offsets[dst] + rank[e]] = (unsigned)src | ((unsigned)combo << 17);
}

// ---------------------------------------------------------------------------
// k_gemm12 v3: coalesced everywhere (frag-order weights, LDS staging).
// ---------------------------------------------------------------------------
__global__ void __launch_bounds__(256, 2) k_gemm12(
        const float* __restrict__ x,
        const short* __restrict__ preF, const float* __restrict__ pre_b,
        const short* __restrict__ w0F, const float* __restrict__ b0,
        const short* __restrict__ w1F, const float* __restrict__ b1,
        const short* __restrict__ w2F, const float* __restrict__ b2,
        const short* __restrict__ w3F, const float* __restrict__ b3,
        const float* __restrict__ scal,
        short* __restrict__ Gb, float* __restrict__ A,
        short* __restrict__ Bb, short* __restrict__ Cb, int n) {
    __shared__ short xs_raw[64 * XSL];
    __shared__ short xs_xx[64 * XSL];
    int tid  = threadIdx.x;
    int w    = tid >> 6;
    int lane = tid & 63;
    int quad = lane >> 4, l16 = lane & 15;
    int m0   = blockIdx.x * 64;

    bf16x8 Bg[2][4], Bc[2][4];
#pragma unroll
    for (int tt = 0; tt < 2; ++tt)
#pragma unroll
        for (int kc = 0; kc < 4; ++kc) {
            int fo = (((2 * w + tt) * 4 + kc) * 64 + lane) * 8;
            Bg[tt][kc] = *(const bf16x8*)(w0F + fo);
            Bc[tt][kc] = *(const bf16x8*)(w3F + fo);
        }

#pragma unroll
    for (int it = 0; it < 8; ++it) {
        int fi  = it * 256 + tid;
        int row = fi >> 5, c4 = fi & 31;
        int gr  = min(m0 + row, n - 1);
        float4 v = ((const float4*)x)[(size_t)gr * 32 + c4];
        uint2 p;
        p.x = pack2(v.x, v.y);
        p.y = pack2(v.z, v.w);
        *(uint2*)(&xs_raw[row * XSL + c4 * 4]) = p;
    }
    __syncthreads();

    {
        bf16x8 a[4];
#pragma unroll
        for (int kc = 0; kc < 4; ++kc)
            a[kc] = *(const bf16x8*)(&xs_raw[(w * 16 + l16) * XSL + kc * 32 + quad * 8]);
        f32x4 acc[8];
#pragma unroll
        for (int t = 0; t < 8; ++t) acc[t] = (f32x4){0.f, 0.f, 0.f, 0.f};
#pragma unroll
        for (int kc = 0; kc < 4; ++kc)
#pragma unroll
            for (int t = 0; t < 8; ++t) {
                bf16x8 b = *(const bf16x8*)(preF + ((t * 4 + kc) * 64 + lane) * 8);
                acc[t] = __builtin_amdgcn_mfma_f32_16x16x32_bf16(a[kc], b, acc[t], 0, 0, 0);
            }
#pragma unroll
        for (int t = 0; t < 8; ++t) {
            float bv = pre_b[t * 16 + l16];
#pragma unroll
            for (int r = 0; r < 4; ++r) acc[t][r] += bv;
        }
#pragma unroll
        for (int r = 0; r < 4; ++r) {
            float s = 0.f, s2 = 0.f;
#pragma unroll
            for (int t = 0; t < 8; ++t) { float v = acc[t][r]; s += v; s2 += v * v; }
            s  += __shfl_xor(s, 1);  s2 += __shfl_xor(s2, 1);
            s  += __shfl_xor(s, 2);  s2 += __shfl_xor(s2, 2);
            s  += __shfl_xor(s, 4);  s2 += __shfl_xor(s2, 4);
            s  += __shfl_xor(s, 8);  s2 += __shfl_xor(s2, 8);
            float m   = s * (1.0f / WIDTH);
            float var = s2 * (1.0f / WIDTH) - m * m;
            float rs  = rsqrtf(var + 1e-5f);
#pragma unroll
            for (int t = 0; t < 8; ++t) acc[t][r] = (acc[t][r] - m) * rs;
        }
        int rowb = w * 16 + quad * 4;
#pragma unroll
        for (int t = 0; t < 8; ++t)
#pragma unroll
            for (int r = 0; r < 4; ++r)
                xs_xx[(rowb + r) * XSL + t * 16 + l16] = f2b(acc[t][r]);
    }
    __syncthreads();

    bf16x8 a2[4][4];
#pragma unroll
    for (int i = 0; i < 4; ++i)
#pragma unroll
        for (int kc = 0; kc < 4; ++kc)
            a2[i][kc] = *(const bf16x8*)(&xs_xx[(i * 16 + l16) * XSL + kc * 32 + quad * 8]);
    __syncthreads();

    {
        f32x4 accG[4][2], accC[4][2];
#pragma unroll
        for (int i = 0; i < 4; ++i)
#pragma unroll
            for (int tt = 0; tt < 2; ++tt) {
                accG[i][tt] = (f32x4){0.f,0.f,0.f,0.f};
                accC[i][tt] = (f32x4){0.f,0.f,0.f,0.f};
            }
#pragma unroll
        for (int kc = 0; kc < 4; ++kc)
#pragma unroll
            for (int i = 0; i < 4; ++i)
#pragma unroll
                for (int tt = 0; tt < 2; ++tt) {
                    accG[i][tt] = __builtin_amdgcn_mfma_f32_16x16x32_bf16(a2[i][kc], Bg[tt][kc], accG[i][tt], 0, 0, 0);
                    accC[i][tt] = __builtin_amdgcn_mfma_f32_16x16x32_bf16(a2[i][kc], Bc[tt][kc], accC[i][tt], 0, 0, 0);
                }
#pragma unroll
        for (int tt = 0; tt < 2; ++tt) {
            int col = (2 * w + tt) * 16 + l16;
            float bg = b0[col];
            float bc = b3[col];
#pragma unroll
            for (int i = 0; i < 4; ++i)
#pragma unroll
                for (int r = 0; r < 4; ++r) {
                    int row = i * 16 + quad * 4 + r;
                    xs_raw[row * XSL + col] = f2b(gelu_fast(accG[i][tt][r] + bg));
                    xs_xx[row * XSL + col]  = f2b(accC[i][tt][r] + bc);
                }
        }
    }
    __syncthreads();

#pragma unroll
    for (int it = 0; it < 4; ++it) {
        int si  = it * 256 + tid;
        int row = si >> 4, c8 = si & 15;
        if (m0 + row < n) {
            *(bf16x8*)(Gb + (size_t)(m0 + row) * WIDTH + c8 * 8) = *(const bf16x8*)(&xs_raw[row * XSL + c8 * 8]);
            *(bf16x8*)(Cb + (size_t)(m0 + row) * WIDTH + c8 * 8) = *(const bf16x8*)(&xs_xx[row * XSL + c8 * 8]);
        }
    }

    if (scal[0] != 0.0f) {
        bf16x8 Ba[2][4], Bbf[2][4];
#pragma unroll
        for (int tt = 0; tt < 2; ++tt)
#pragma unroll
            for (int kc = 0; kc < 4; ++kc) {
                int fo = (((2 * w + tt) * 4 + kc) * 64 + lane) * 8;
                Ba[tt][kc]  = *(const bf16x8*)(w1F + fo);
                Bbf[tt][kc] = *(const bf16x8*)(w2F + fo);
            }
        f32x4 accA[4][2], accB[4][2];
#pragma unroll
        for (int i = 0; i < 4; ++i)
#pragma unroll
            for (int tt = 0; tt < 2; ++tt) {
                accA[i][tt] = (f32x4){0.f,0.f,0.f,0.f};
                accB[i][tt] = (f32x4){0.f,0.f,0.f,0.f};
            }
#pragma unroll
        for (int kc = 0; kc < 4; ++kc)
#pragma unroll
            for (int i = 0; i < 4; ++i)
#pragma unroll
                for (int tt = 0; tt < 2; ++tt) {
                    accA[i][tt] = __builtin_amdgcn_mfma_f32_16x16x32_bf16(a2[i][kc], Ba[tt][kc],  accA[i][tt], 0, 0, 0);
                    accB[i][tt] = __builtin_amdgcn_mfma_f32_16x16x32_bf16(a2[i][kc], Bbf[tt][kc], accB[i][tt], 0, 0, 0);
                }
#pragma unroll
        for (int tt = 0; tt < 2; ++tt) {
            int col = (2 * w + tt) * 16 + l16;
            float ba = b1[col];
            float bb = b2[col];
#pragma unroll
            for (int i = 0; i < 4; ++i)
#pragma unroll
                for (int r = 0; r < 4; ++r) {
                    int row = m0 + i * 16 + quad * 4 + r;
                    if (row < n) {
                        size_t idx = (size_t)row * WIDTH + col;
                        A[idx]  = accA[i][tt][r] + ba;
                        Bb[idx] = f2b(accB[i][tt][r] + bb);
                    }
                }
        }
    }
}

// ---------------------------------------------------------------------------
// k_agg v3: one wave per node; lane L owns cols {2L,2L+1}.  Fast path
// unrolled x4 with ALL loads hoisted (4 pk broadcasts -> 8 gathers in
// flight) to quadruple memory-level parallelism.
// ---------------------------------------------------------------------------
__global__ void __launch_bounds__(256)
k_agg(const int* __restrict__ offsets, const unsigned* __restrict__ s_pk,
      const float* __restrict__ A, const short* __restrict__ Bb,
      const short* __restrict__ Cb, const float* __restrict__ Uc,
      const float* __restrict__ scal, const short* __restrict__ Gb,
      short* __restrict__ hb, int n) {
    int wid = threadIdx.x >> 6;
    int L   = threadIdx.x & 63;
    int node = blockIdx.x * 4 + wid;
    if (node >= n) return;
    int start = offsets[node];
    int end   = offsets[node + 1];

    const unsigned* Cb32 = (const unsigned*)Cb;
    const unsigned* Bb32 = (const unsigned*)Bb;
    const float2* U0c2 = (const float2*)(Uc);
    const float2* U1c2 = (const float2*)(Uc + (size_t)NCOMBO * WIDTH);
    const float2* U2c2 = (const float2*)(Uc + 2 * (size_t)NCOMBO * WIDTH);

    float i0 = scal[0], i1 = scal[1];
    float acc0 = 0.0f, acc1 = 0.0f;

    if (i0 == 0.0f) {
        int p = start;
        for (; p + 4 <= end; p += 4) {
            unsigned pk0 = s_pk[p],     pk1 = s_pk[p + 1];
            unsigned pk2 = s_pk[p + 2], pk3 = s_pk[p + 3];
            unsigned cc0 = Cb32[(pk0 & 0x1FFFFu) * 64 + L];
            unsigned cc1 = Cb32[(pk1 & 0x1FFFFu) * 64 + L];
            unsigned cc2 = Cb32[(pk2 & 0x1FFFFu) * 64 + L];
            unsigned cc3 = Cb32[(pk3 & 0x1FFFFu) * 64 + L];
            float2   uu0 = U2c2[(pk0 >> 17) * 64 + L];
            float2   uu1 = U2c2[(pk1 >> 17) * 64 + L];
            float2   uu2 = U2c2[(pk2 >> 17) * 64 + L];
            float2   uu3 = U2c2[(pk3 >> 17) * 64 + L];
            acc0 += gelu_fast(b2f_lo(cc0) + uu0.x);
            acc1 += gelu_fast(b2f_hi(cc0) + uu0.y);
            acc0 += gelu_fast(b2f_lo(cc1) + uu1.x);
            acc1 += gelu_fast(b2f_hi(cc1) + uu1.y);
            acc0 += gelu_fast(b2f_lo(cc2) + uu2.x);
            acc1 += gelu_fast(b2f_hi(cc2) + uu2.y);
            acc0 += gelu_fast(b2f_lo(cc3) + uu3.x);
            acc1 += gelu_fast(b2f_hi(cc3) + uu3.y);
        }
        if (p + 2 <= end) {
            unsigned pk0 = s_pk[p], pk1 = s_pk[p + 1];
            unsigned cc0 = Cb32[(pk0 & 0x1FFFFu) * 64 + L];
            unsigned cc1 = Cb32[(pk1 & 0x1FFFFu) * 64 + L];
            float2   uu0 = U2c2[(pk0 >> 17) * 64 + L];
            float2   uu1 = U2c2[(pk1 >> 17) * 64 + L];
            acc0 += gelu_fast(b2f_lo(cc0) + uu0.x);
            acc1 += gelu_fast(b2f_hi(cc0) + uu0.y);
            acc0 += gelu_fast(b2f_lo(cc1) + uu1.x);
            acc1 += gelu_fast(b2f_hi(cc1) + uu1.y);
            p += 2;
        }
        if (p < end) {
            unsigned pk0 = s_pk[p];
            unsigned cc0 = Cb32[(pk0 & 0x1FFFFu) * 64 + L];
            float2   uu0 = U2c2[(pk0 >> 17) * 64 + L];
            acc0 += gelu_fast(b2f_lo(cc0) + uu0.x);
            acc1 += gelu_fast(b2f_hi(cc0) + uu0.y);
        }
        float s = __expf(i1);
        acc0 *= s; acc1 *= s;
    } else {
        float2 av = *(const float2*)(A + (size_t)node * WIDTH + 2 * L);
        int p = start;
        for (; p + 2 <= end; p += 2) {
            unsigned pk0 = s_pk[p], pk1 = s_pk[p + 1];
            unsigned sA = pk0 & 0x1FFFFu, cA = pk0 >> 17;
            unsigned sB = pk1 & 0x1FFFFu, cB = pk1 >> 17;
            float2 u0a = U0c2[cA * 64 + L], u0b = U0c2[cB * 64 + L];
            float2 u1a = U1c2[cA * 64 + L], u1b = U1c2[cB * 64 + L];
            float2 u2a = U2c2[cA * 64 + L], u2b = U2c2[cB * 64 + L];
            unsigned bba = Bb32[sA * 64 + L], bbb = Bb32[sB * 64 + L];
            unsigned cca = Cb32[sA * 64 + L], ccb = Cb32[sB * 64 + L];
            {
                float q0 = av.x + u0a.x, q1 = av.y + u0a.y;
                float k0 = b2f_lo(bba) + u1a.x, k1 = b2f_hi(bba) + u1a.y;
                float v0 = gelu_fast(b2f_lo(cca) + u2a.x);
                float v1 = gelu_fast(b2f_hi(cca) + u2a.y);
                float s = q0 * k0 + q1 * k1;
                s += __shfl_xor(s, 1);
                s += __shfl_xor(s, 2);
                s += __shfl_xor(s, 4);
                s += __shfl_xor(s, 8);
                s += __shfl_xor(s, 16);
                float att = __expf(s * 0.125f * i0 + i1);
                acc0 += v0 * att;
                acc1 += v1 * att;
            }
            {
                float q0 = av.x + u0b.x, q1 = av.y + u0b.y;
                float k0 = b2f_lo(bbb) + u1b.x, k1 = b2f_hi(bbb) + u1b.y;
                float v0 = gelu_fast(b2f_lo(ccb) + u2b.x);
                float v1 = gelu_fast(b2f_hi(ccb) + u2b.y);
                float s = q0 * k0 + q1 * k1;
                s += __shfl_xor(s, 1);
                s += __shfl_xor(s, 2);
                s += __shfl_xor(s, 4);
                s += __shfl_xor(s, 8);
                s += __shfl_xor(s, 16);
                float att = __expf(s * 0.125f * i0 + i1);
                acc0 += v0 * att;
                acc1 += v1 * att;
            }
        }
        if (p < end) {
            unsigned pk = s_pk[p];
            unsigned sA = pk & 0x1FFFFu, cA = pk >> 17;
            float2 u0 = U0c2[cA * 64 + L];
            float2 u1 = U1c2[cA * 64 + L];
            float2 u2 = U2c2[cA * 64 + L];
            unsigned bb = Bb32[sA * 64 + L];
            unsigned cc = Cb32[sA * 64 + L];
            float q0 = av.x + u0.x, q1 = av.y + u0.y;
            float k0 = b2f_lo(bb) + u1.x, k1 = b2f_hi(bb) + u1.y;
            float v0 = gelu_fast(b2f_lo(cc) + u2.x);
            float v1 = gelu_fast(b2f_hi(cc) + u2.y);
            float s = q0 * k0 + q1 * k1;
            s += __shfl_xor(s, 1);
            s += __shfl_xor(s, 2);
            s += __shfl_xor(s, 4);
            s += __shfl_xor(s, 8);
            s += __shfl_xor(s, 16);
            float att = __expf(s * 0.125f * i0 + i1);
            acc0 += v0 * att;
            acc1 += v1 * att;
        }
    }
    unsigned g = ((const unsigned*)Gb)[(size_t)node * 64 + L];
    ((unsigned*)hb)[(size_t)node * 64 + L] = pack2(b2f_lo(g) + acc0, b2f_hi(g) + acc1);
}

// ---------------------------------------------------------------------------
// k_post v3: coop-load hb -> LDS, B-stationary MFMA, staged coalesced out.
// ---------------------------------------------------------------------------
__global__ void __launch_bounds__(256, 2) k_post(
        const float* __restrict__ x, const short* __restrict__ hb,
        const short* __restrict__ postF, const float* __restrict__ post_b,
        float* __restrict__ out, int n) {
    __shared__ short hs[64 * XSL];
    __shared__ float os[64 * OSL];
    int tid  = threadIdx.x;
    int w    = tid >> 6;
    int lane = tid & 63;
    int quad = lane >> 4, l16 = lane & 15;
    int m0   = blockIdx.x * 64;

    bf16x8 Bp[2][4];
#pragma unroll
    for (int tt = 0; tt < 2; ++tt)
#pragma unroll
        for (int kc = 0; kc < 4; ++kc)
            Bp[tt][kc] = *(const bf16x8*)(postF + (((2 * w + tt) * 4 + kc) * 64 + lane) * 8);

#pragma unroll
    for (int it = 0; it < 4; ++it) {
        int si  = it * 256 + tid;
        int row = si >> 4, c8 = si & 15;
        int gr  = min(m0 + row, n - 1);
        *(bf16x8*)(&hs[row * XSL + c8 * 8]) = *(const bf16x8*)(hb + (size_t)gr * WIDTH + c8 * 8);
    }
    __syncthreads();

    bf16x8 a[4][4];
#pragma unroll
    for (int i = 0; i < 4; ++i)
#pragma unroll
        for (int kc = 0; kc < 4; ++kc)
            a[i][kc] = *(const bf16x8*)(&hs[(i * 16 + l16) * XSL + kc * 32 + quad * 8]);

    f32x4 acc[4][2];
#pragma unroll
    for (int i = 0; i < 4; ++i)
#pragma unroll
        for (int tt = 0; tt < 2; ++tt) acc[i][tt] = (f32x4){0.f,0.f,0.f,0.f};
#pragma unroll
    for (int kc = 0; kc < 4; ++kc)
#pragma unroll
        for (int i = 0; i < 4; ++i)
#pragma unroll
            for (int tt = 0; tt < 2; ++tt)
                acc[i][tt] = __builtin_amdgcn_mfma_f32_16x16x32_bf16(a[i][kc], Bp[tt][kc], acc[i][tt], 0, 0, 0);

#pragma unroll
    for (int tt = 0; tt < 2; ++tt) {
        int col = (2 * w + tt) * 16 + l16;
        float bv = post_b[col];
#pragma unroll
        for (int i = 0; i < 4; ++i)
#pragma unroll
            for (int r = 0; r < 4; ++r)
                os[(i * 16 + quad * 4 + r) * OSL + col] = acc[i][tt][r] + bv;
    }
    __syncthreads();

#pragma unroll
    for (int it = 0; it < 8; ++it) {
        int fi  = it * 256 + tid;
        int row = fi >> 5, c4 = fi & 31;
        if (m0 + row < n) {
            float4 xv = ((const float4*)x)[(size_t)(m0 + row) * 32 + c4];
            float4 av = *(const float4*)(&os[row * OSL + c4 * 4]);
            float4 ov = {xv.x + av.x, xv.y + av.y, xv.z + av.z, xv.w + av.w};
            ((float4*)out)[(size_t)(m0 + row) * 32 + c4] = ov;
        }
    }
}

extern "C" void kernel_launch(void* const* d_in, const int* in_sizes, int n_in,
                              void* d_out, int out_size, void* d_ws, size_t ws_size,
                              hipStream_t stream) {
    const float* x      = (const float*)d_in[0];
    const int*   eidx   = (const int*)d_in[1];
    const int*   eattr  = (const int*)d_in[2];
    const float* pre_w  = (const float*)d_in[3];
    const float* pre_b  = (const float*)d_in[4];
    const float* msg0_w = (const float*)d_in[5];
    const float* msg0_b = (const float*)d_in[6];
    const float* msg1_w = (const float*)d_in[7];
    const float* msg1_b = (const float*)d_in[8];
    const float* msg2_w = (const float*)d_in[9];
    const float* msg2_b = (const float*)d_in[10];
    const float* msg3_w = (const float*)d_in[11];
    const float* msg3_b = (const float*)d_in[12];
    const float* r0w    = (const float*)d_in[13];
    const float* r0b    = (const float*)d_in[14];
    const float* r1w    = (const float*)d_in[15];
    const float* r1b    = (const float*)d_in[16];
    const float* r2w    = (const float*)d_in[17];
    const float* r2b    = (const float*)d_in[18];
    const float* post_w = (const float*)d_in[19];
    const float* post_b = (const float*)d_in[20];
    const float* emb0   = (const float*)d_in[21];
    const float* emb1   = (const float*)d_in[22];
    const float* emb2   = (const float*)d_in[23];
    const float* emb3   = (const float*)d_in[24];
    const float* einit  = (const float*)d_in[25];
    const float* init0  = (const float*)d_in[26];

    int n = in_sizes[0] / WIDTH;
    int E = in_sizes[2] / 4;
    size_t NW = (size_t)n * WIDTH;

    float* ws   = (float*)d_ws;
    float* A    = ws;                              // [N,128] f32 (full path only)
    float* U    = ws + NW;                         // [3][34][128]
    float* Uc   = U + 3 * 34 * WIDTH;              // [3][NCOMBO][128]
    float* scal = Uc + 3 * (size_t)NCOMBO * WIDTH; // [2]
    short* sw   = (short*)(scal + 2);
    short* preF  = sw;                             // 6 x 16384 bf16 frag-order weights
    short* w0F   = sw + 16384;
    short* w1F   = sw + 2 * 16384;
    short* w2F   = sw + 3 * 16384;
    short* w3F   = sw + 4 * 16384;
    short* postF = sw + 5 * 16384;
    short* Bb    = sw + 6 * 16384;                 // [N,128] bf16 (full path)
    short* Cb    = Bb + NW;                        // [N,128] bf16
    short* Gb    = Cb + NW;                        // [N,128] bf16
    short* hb    = Gb + NW;                        // [N,128] bf16
    int*      ib       = (int*)(hb + NW);
    int*      offsets  = ib;                       // n+1
    int*      counts   = offsets + (n + 1);        // n
    int*      lscan    = counts + n;               // n
    int*      partials = lscan + n;                // <=1024
    int*      rank     = partials + 1024;          // E
    unsigned* s_pk     = (unsigned*)(rank + E);    // E

    int prep_total = 6 * 16384 + 3 * 34 * WIDTH + n;
    k_prep<<<(prep_total + 255) / 256, 256, 0, stream>>>(
        einit, init0, emb0, emb1, emb2, emb3,
        r0w, r0b, r1w, r1b, r2w, r2b,
        pre_w, msg0_w, msg1_w, msg2_w, msg3_w, post_w,
        preF, w0F, w1F, w2F, w3F, postF, U, scal, counts, n);
    k_prepc<<<3 * NCOMBO, 128, 0, stream>>>(U, init0, Uc);

    int eb = (E + 255) / 256;
    k_hist<<<eb, 256, 0, stream>>>(eidx, counts, rank, E);
    int sb = (n + 255) / 256;
    k_scan1<<<sb, 256, 0, stream>>>(counts, lscan, partials, n);
    k_scan2<<<1, 1024, 0, stream>>>(partials, sb, offsets, n);
    k_scan3<<<sb, 256, 0, stream>>>(counts, lscan, partials, offsets, n);
    k_scatter<<<eb, 256, 0, stream>>>(eidx, eattr, offsets, rank, s_pk, E);

    int gb = (n + 63) / 64;
    k_gemm12<<<gb, 256, 0, stream>>>(x, preF, pre_b, w0F, msg0_b, w1F, msg1_b,
                                     w2F, msg2_b, w3F, msg3_b, scal, Gb, A, Bb, Cb, n);
    k_agg<<<(n + 3) / 4, 256, 0, stream>>>(offsets, s_pk, A, Bb, Cb, Uc, scal, Gb, hb, n);
    k_post<<<gb, 256, 0, stream>>>(x, hb, postF, post_b, (float*)d_out, n);
}

// Round 11
// 231.291 us; speedup vs baseline: 5.6415x; 1.0407x over previous
//
#include <hip/hip_runtime.h>
#include <cstdint>

#define WIDTH 128
#define NCOMBO 2268   // 6*7*3*18 attr-combo rows
#define XSL 136       // bf16 LDS tile row stride (128 + 8 pad)
#define OSL 132       // f32 LDS tile row stride (128 + 4 pad)
#define TOTW (6 * 16384)
#define TOTU (3 * 34 * WIDTH)

typedef short bf16x8 __attribute__((ext_vector_type(8)));
typedef float f32x4  __attribute__((ext_vector_type(4)));

// gelu(v) = v * sigmoid(2u): ~9 VALU ops, inf-safe.
__device__ __forceinline__ float gelu_fast(float v) {
    float e = __expf(v * __builtin_fmaf(v * v, 0.0713548f, 1.5957691f));
    return v - v * __builtin_amdgcn_rcpf(e + 1.0f);
}
__device__ __forceinline__ short f2b(float f) {
    unsigned u = __float_as_uint(f);
    unsigned r = (u + 0x7FFFu + ((u >> 16) & 1u)) >> 16;
    return (short)r;
}
__device__ __forceinline__ float b2f_lo(unsigned u) { return __uint_as_float(u << 16); }
__device__ __forceinline__ float b2f_hi(unsigned u) { return __uint_as_float(u & 0xFFFF0000u); }
__device__ __forceinline__ unsigned pack2(float lo, float hi) {
    return (unsigned)(unsigned short)f2b(lo) | ((unsigned)(unsigned short)f2b(hi) << 16);
}

// ---------------------------------------------------------------------------
// F1: (a) 6 weight mats -> bf16 fragment-order tables; (b) U tables
// [3][34][128] (bias folded into emb0 rows); (c) scal; (d) HIST with rank
// (counts pre-zeroed by memset).  All parts independent.
// ---------------------------------------------------------------------------
__global__ void k_f1(const float* __restrict__ einit, const float* __restrict__ init0,
                     const float* __restrict__ emb0, const float* __restrict__ emb1,
                     const float* __restrict__ emb2, const float* __restrict__ emb3,
                     const float* __restrict__ r0w, const float* __restrict__ r0b,
                     const float* __restrict__ r1w, const float* __restrict__ r1b,
                     const float* __restrict__ r2w, const float* __restrict__ r2b,
                     const float* __restrict__ pw0, const float* __restrict__ pw1,
                     const float* __restrict__ pw2, const float* __restrict__ pw3,
                     const float* __restrict__ pw4, const float* __restrict__ pw5,
                     short* __restrict__ o0, short* __restrict__ o1,
                     short* __restrict__ o2, short* __restrict__ o3,
                     short* __restrict__ o4, short* __restrict__ o5,
                     float* __restrict__ U, float* __restrict__ scal,
                     const int* __restrict__ edge_index, int* __restrict__ counts,
                     int* __restrict__ rank, int E) {
    int tid = blockIdx.x * blockDim.x + threadIdx.x;
    if (tid == 0) { scal[0] = init0[0]; scal[1] = init0[1]; }
    if (tid < TOTW) {
        int which = tid >> 14;
        int r = tid & 16383;
        int t    = r >> 11;
        int kc   = (r >> 9) & 3;
        int lane = (r >> 3) & 63;
        int j    = r & 7;
        int k  = kc * 32 + ((lane >> 4) << 3) + j;
        int nn = (t << 4) + (lane & 15);
        const float* w = (which == 0) ? pw0 : (which == 1) ? pw1 : (which == 2) ? pw2
                       : (which == 3) ? pw3 : (which == 4) ? pw4 : pw5;
        short* o = (which == 0) ? o0 : (which == 1) ? o1 : (which == 2) ? o2
                 : (which == 3) ? o3 : (which == 4) ? o4 : o5;
        o[r] = f2b(w[k * 128 + nn]);
    } else if (tid < TOTW + TOTU) {
        int idx = tid - TOTW;
        float e0 = expf(einit[0]), e1 = expf(einit[1]), e2 = expf(einit[2]), e3 = expf(einit[3]);
        float inv = 1.0f / sqrtf(e0 + e1 + e2 + e3);
        float xw[4] = {e0 * inv, e1 * inv, e2 * inv, e3 * inv};
        float se = expf(init0[2]);
        float sv = expf(init0[3]);
        int r   = idx / (34 * WIDTH);
        int rem = idx - r * (34 * WIDTH);
        int g   = rem / WIDTH;
        int j   = rem - g * WIDTH;
        int cc, base;
        if (g >= 16)      { cc = 3; base = 16; }
        else if (g >= 13) { cc = 2; base = 13; }
        else if (g >= 6)  { cc = 1; base = 6; }
        else              { cc = 0; base = 0; }
        int i = g - base;
        const float* em = (cc == 0) ? emb0 : (cc == 1) ? emb1 : (cc == 2) ? emb2 : emb3;
        const float* w  = (r == 0) ? r0w : (r == 1) ? r1w : r2w;
        const float* rb = (r == 0) ? r0b : (r == 1) ? r1b : r2b;
        float s = (r == 2) ? sv : se;
        float acc = 0.0f;
        const float* erow = em + i * 64;
        for (int d = 0; d < 64; ++d) acc += erow[d] * w[d * WIDTH + j];
        float val = s * xw[cc] * acc;
        if (cc == 0) val += s * rb[j];
        U[idx] = val;
    } else if (tid < TOTW + TOTU + E) {
        int e = tid - TOTW - TOTU;
        rank[e] = atomicAdd(&counts[edge_index[E + e]], 1);
    }
}

// ---------------------------------------------------------------------------
// F2: blocks [0,sb): scan1 (block-local inclusive scan of counts).
//     blocks [sb,...): prepc — 2 combo-rows per 256-thread block.
// ---------------------------------------------------------------------------
__global__ void k_f2(const int* __restrict__ counts, int* __restrict__ lscan,
                     int* __restrict__ partials, int n, int sb,
                     const float* __restrict__ U, const float* __restrict__ init0,
                     float* __restrict__ Uc) {
    if ((int)blockIdx.x < sb) {
        __shared__ int s[256];
        int t = threadIdx.x;
        int i = blockIdx.x * 256 + t;
        int v = (i < n) ? counts[i] : 0;
        s[t] = v;
        __syncthreads();
        for (int d = 1; d < 256; d <<= 1) {
            int u = (t >= d) ? s[t - d] : 0;
            __syncthreads();
            s[t] += u;
            __syncthreads();
        }
        if (i < n) lscan[i] = s[t];
        if (t == 255) partials[blockIdx.x] = s[255];
    } else {
        int bi = ((int)blockIdx.x - sb) * 2 + (threadIdx.x >> 7);
        if (bi >= 3 * NCOMBO) return;
        int r  = bi / NCOMBO;
        if (r < 2 && init0[0] == 0.0f) return;
        int cb = bi - r * NCOMBO;
        int a  = cb / 378;
        int rm = cb - a * 378;
        int b  = rm / 54;
        rm -= b * 54;
        int c  = rm / 18;
        int d  = rm - c * 18;
        int j  = threadIdx.x & 127;
        const float* Ur = U + r * 34 * WIDTH;
        Uc[(size_t)bi * WIDTH + j] = Ur[a * WIDTH + j] + Ur[(6 + b) * WIDTH + j]
                                   + Ur[(13 + c) * WIDTH + j] + Ur[(16 + d) * WIDTH + j];
    }
}

// ---------------------------------------------------------------------------
// scan2: single block exclusive-scans block totals; grand total -> offsets[n].
// ---------------------------------------------------------------------------
__global__ void k_scan2(int* __restrict__ partials, int nb,
                        int* __restrict__ offsets, int n) {
    __shared__ int s[1024];
    int t = threadIdx.x;
    int v = (t < nb) ? partials[t] : 0;
    s[t] = v;
    __syncthreads();
    for (int d = 1; d < 1024; d <<= 1) {
        int u = (t >= d) ? s[t - d] : 0;
        __syncthreads();
        s[t] += u;
        __syncthreads();
    }
    if (t < nb) partials[t] = s[t] - v;
    if (t == 1023) offsets[n] = s[1023];
}

// ---------------------------------------------------------------------------
// F3: blocks [0,gb): gemm12 (pre GEMM + LN + 2/4 output GEMMs, coalesced).
//     blocks [gb,gb+eb): scatter (offsets computed inline — no dependency).
//     blocks [gb+eb,...): scan3 (write offsets[] for k_agg).
// ---------------------------------------------------------------------------
__global__ void __launch_bounds__(256, 2) k_f3(
        const float* __restrict__ x,
        const short* __restrict__ preF, const float* __restrict__ pre_b,
        const short* __restrict__ w0F, const float* __restrict__ b0,
        const short* __restrict__ w1F, const float* __restrict__ b1,
        const short* __restrict__ w2F, const float* __restrict__ b2,
        const short* __restrict__ w3F, const float* __restrict__ b3,
        const float* __restrict__ scal,
        short* __restrict__ Gb, float* __restrict__ A,
        short* __restrict__ Bb, short* __restrict__ Cb, int n,
        const int* __restrict__ edge_index, const int* __restrict__ edge_attr,
        const int* __restrict__ counts, const int* __restrict__ lscan,
        const int* __restrict__ partials, const int* __restrict__ rank,
        int* __restrict__ offsets, unsigned* __restrict__ s_pk, int E,
        int gb, int eb) {
    __shared__ short xs_raw[64 * XSL];
    __shared__ short xs_xx[64 * XSL];
    int tid = threadIdx.x;

    if ((int)blockIdx.x >= gb) {
        int rb = (int)blockIdx.x - gb;
        if (rb < eb) {
            // ---- scatter ----
            int e = rb * 256 + tid;
            if (e >= E) return;
            int src = edge_index[e];
            int dst = edge_index[E + e];
            int4 at = ((const int4*)edge_attr)[e];
            int combo = ((at.x * 7 + at.y) * 3 + at.z) * 18 + at.w;
            int off = partials[dst >> 8] + lscan[dst] - counts[dst];
            s_pk[off + rank[e]] = (unsigned)src | ((unsigned)combo << 17);
        } else {
            // ---- scan3: offsets[i] for k_agg ----
            int i = (rb - eb) * 256 + tid;
            if (i >= n) return;
            offsets[i] = partials[i >> 8] + lscan[i] - counts[i];
        }
        return;
    }

    // ---- gemm12 ----
    int w    = tid >> 6;
    int lane = tid & 63;
    int quad = lane >> 4, l16 = lane & 15;
    int m0   = blockIdx.x * 64;

    bf16x8 Bg[2][4], Bc[2][4];
#pragma unroll
    for (int tt = 0; tt < 2; ++tt)
#pragma unroll
        for (int kc = 0; kc < 4; ++kc) {
            int fo = (((2 * w + tt) * 4 + kc) * 64 + lane) * 8;
            Bg[tt][kc] = *(const bf16x8*)(w0F + fo);
            Bc[tt][kc] = *(const bf16x8*)(w3F + fo);
        }

#pragma unroll
    for (int it = 0; it < 8; ++it) {
        int fi  = it * 256 + tid;
        int row = fi >> 5, c4 = fi & 31;
        int gr  = min(m0 + row, n - 1);
        float4 v = ((const float4*)x)[(size_t)gr * 32 + c4];
        uint2 p;
        p.x = pack2(v.x, v.y);
        p.y = pack2(v.z, v.w);
        *(uint2*)(&xs_raw[row * XSL + c4 * 4]) = p;
    }
    __syncthreads();

    {
        bf16x8 a[4];
#pragma unroll
        for (int kc = 0; kc < 4; ++kc)
            a[kc] = *(const bf16x8*)(&xs_raw[(w * 16 + l16) * XSL + kc * 32 + quad * 8]);
        f32x4 acc[8];
#pragma unroll
        for (int t = 0; t < 8; ++t) acc[t] = (f32x4){0.f, 0.f, 0.f, 0.f};
#pragma unroll
        for (int kc = 0; kc < 4; ++kc)
#pragma unroll
            for (int t = 0; t < 8; ++t) {
                bf16x8 b = *(const bf16x8*)(preF + ((t * 4 + kc) * 64 + lane) * 8);
                acc[t] = __builtin_amdgcn_mfma_f32_16x16x32_bf16(a[kc], b, acc[t], 0, 0, 0);
            }
#pragma unroll
        for (int t = 0; t < 8; ++t) {
            float bv = pre_b[t * 16 + l16];
#pragma unroll
            for (int r = 0; r < 4; ++r) acc[t][r] += bv;
        }
#pragma unroll
        for (int r = 0; r < 4; ++r) {
            float s = 0.f, s2 = 0.f;
#pragma unroll
            for (int t = 0; t < 8; ++t) { float v = acc[t][r]; s += v; s2 += v * v; }
            s  += __shfl_xor(s, 1);  s2 += __shfl_xor(s2, 1);
            s  += __shfl_xor(s, 2);  s2 += __shfl_xor(s2, 2);
            s  += __shfl_xor(s, 4);  s2 += __shfl_xor(s2, 4);
            s  += __shfl_xor(s, 8);  s2 += __shfl_xor(s2, 8);
            float m   = s * (1.0f / WIDTH);
            float var = s2 * (1.0f / WIDTH) - m * m;
            float rs  = rsqrtf(var + 1e-5f);
#pragma unroll
            for (int t = 0; t < 8; ++t) acc[t][r] = (acc[t][r] - m) * rs;
        }
        int rowb = w * 16 + quad * 4;
#pragma unroll
        for (int t = 0; t < 8; ++t)
#pragma unroll
            for (int r = 0; r < 4; ++r)
                xs_xx[(rowb + r) * XSL + t * 16 + l16] = f2b(acc[t][r]);
    }
    __syncthreads();

    bf16x8 a2[4][4];
#pragma unroll
    for (int i = 0; i < 4; ++i)
#pragma unroll
        for (int kc = 0; kc < 4; ++kc)
            a2[i][kc] = *(const bf16x8*)(&xs_xx[(i * 16 + l16) * XSL + kc * 32 + quad * 8]);
    __syncthreads();

    {
        f32x4 accG[4][2], accC[4][2];
#pragma unroll
        for (int i = 0; i < 4; ++i)
#pragma unroll
            for (int tt = 0; tt < 2; ++tt) {
                accG[i][tt] = (f32x4){0.f,0.f,0.f,0.f};
                accC[i][tt] = (f32x4){0.f,0.f,0.f,0.f};
            }
#pragma unroll
        for (int kc = 0; kc < 4; ++kc)
#pragma unroll
            for (int i = 0; i < 4; ++i)
#pragma unroll
                for (int tt = 0; tt < 2; ++tt) {
                    accG[i][tt] = __builtin_amdgcn_mfma_f32_16x16x32_bf16(a2[i][kc], Bg[tt][kc], accG[i][tt], 0, 0, 0);
                    accC[i][tt] = __builtin_amdgcn_mfma_f32_16x16x32_bf16(a2[i][kc], Bc[tt][kc], accC[i][tt], 0, 0, 0);
                }
#pragma unroll
        for (int tt = 0; tt < 2; ++tt) {
            int col = (2 * w + tt) * 16 + l16;
            float bg = b0[col];
            float bc = b3[col];
#pragma unroll
            for (int i = 0; i < 4; ++i)
#pragma unroll
                for (int r = 0; r < 4; ++r) {
                    int row = i * 16 + quad * 4 + r;
                    xs_raw[row * XSL + col] = f2b(gelu_fast(accG[i][tt][r] + bg));
                    xs_xx[row * XSL + col]  = f2b(accC[i][tt][r] + bc);
                }
        }
    }
    __syncthreads();

#pragma unroll
    for (int it = 0; it < 4; ++it) {
        int si  = it * 256 + tid;
        int row = si >> 4, c8 = si & 15;
        if (m0 + row < n) {
            *(bf16x8*)(Gb + (size_t)(m0 + row) * WIDTH + c8 * 8) = *(const bf16x8*)(&xs_raw[row * XSL + c8 * 8]);
            *(bf16x8*)(Cb + (size_t)(m0 + row) * WIDTH + c8 * 8) = *(const bf16x8*)(&xs_xx[row * XSL + c8 * 8]);
        }
    }

    if (scal[0] != 0.0f) {
        bf16x8 Ba[2][4], Bbf[2][4];
#pragma unroll
        for (int tt = 0; tt < 2; ++tt)
#pragma unroll
            for (int kc = 0; kc < 4; ++kc) {
                int fo = (((2 * w + tt) * 4 + kc) * 64 + lane) * 8;
                Ba[tt][kc]  = *(const bf16x8*)(w1F + fo);
                Bbf[tt][kc] = *(const bf16x8*)(w2F + fo);
            }
        f32x4 accA[4][2], accB[4][2];
#pragma unroll
        for (int i = 0; i < 4; ++i)
#pragma unroll
            for (int tt = 0; tt < 2; ++tt) {
                accA[i][tt] = (f32x4){0.f,0.f,0.f,0.f};
                accB[i][tt] = (f32x4){0.f,0.f,0.f,0.f};
            }
#pragma unroll
        for (int kc = 0; kc < 4; ++kc)
#pragma unroll
            for (int i = 0; i < 4; ++i)
#pragma unroll
                for (int tt = 0; tt < 2; ++tt) {
                    accA[i][tt] = __builtin_amdgcn_mfma_f32_16x16x32_bf16(a2[i][kc], Ba[tt][kc],  accA[i][tt], 0, 0, 0);
                    accB[i][tt] = __builtin_amdgcn_mfma_f32_16x16x32_bf16(a2[i][kc], Bbf[tt][kc], accB[i][tt], 0, 0, 0);
                }
#pragma unroll
        for (int tt = 0; tt < 2; ++tt) {
            int col = (2 * w + tt) * 16 + l16;
            float ba = b1[col];
            float bb = b2[col];
#pragma unroll
            for (int i = 0; i < 4; ++i)
#pragma unroll
                for (int r = 0; r < 4; ++r) {
                    int row = m0 + i * 16 + quad * 4 + r;
                    if (row < n) {
                        size_t idx = (size_t)row * WIDTH + col;
                        A[idx]  = accA[i][tt][r] + ba;
                        Bb[idx] = f2b(accB[i][tt][r] + bb);
                    }
                }
        }
    }
}

// ---------------------------------------------------------------------------
// k_agg: one wave per node; lane L owns cols {2L,2L+1}; fast path unrolled x4
// with all loads hoisted (8 gathers in flight).
// ---------------------------------------------------------------------------
__global__ void __launch_bounds__(256)
k_agg(const int* __restrict__ offsets, const unsigned* __restrict__ s_pk,
      const float* __restrict__ A, const short* __restrict__ Bb,
      const short* __restrict__ Cb, const float* __restrict__ Uc,
      const float* __restrict__ scal, const short* __restrict__ Gb,
      short* __restrict__ hb, int n) {
    int wid = threadIdx.x >> 6;
    int L   = threadIdx.x & 63;
    int node = blockIdx.x * 4 + wid;
    if (node >= n) return;
    int start = offsets[node];
    int end   = offsets[node + 1];

    const unsigned* Cb32 = (const unsigned*)Cb;
    const unsigned* Bb32 = (const unsigned*)Bb;
    const float2* U0c2 = (const float2*)(Uc);
    const float2* U1c2 = (const float2*)(Uc + (size_t)NCOMBO * WIDTH);
    const float2* U2c2 = (const float2*)(Uc + 2 * (size_t)NCOMBO * WIDTH);

    float i0 = scal[0], i1 = scal[1];
    float acc0 = 0.0f, acc1 = 0.0f;

    if (i0 == 0.0f) {
        int p = start;
        for (; p + 4 <= end; p += 4) {
            unsigned pk0 = s_pk[p],     pk1 = s_pk[p + 1];
            unsigned pk2 = s_pk[p + 2], pk3 = s_pk[p + 3];
            unsigned cc0 = Cb32[(pk0 & 0x1FFFFu) * 64 + L];
            unsigned cc1 = Cb32[(pk1 & 0x1FFFFu) * 64 + L];
            unsigned cc2 = Cb32[(pk2 & 0x1FFFFu) * 64 + L];
            unsigned cc3 = Cb32[(pk3 & 0x1FFFFu) * 64 + L];
            float2   uu0 = U2c2[(pk0 >> 17) * 64 + L];
            float2   uu1 = U2c2[(pk1 >> 17) * 64 + L];
            float2   uu2 = U2c2[(pk2 >> 17) * 64 + L];
            float2   uu3 = U2c2[(pk3 >> 17) * 64 + L];
            acc0 += gelu_fast(b2f_lo(cc0) + uu0.x);
            acc1 += gelu_fast(b2f_hi(cc0) + uu0.y);
            acc0 += gelu_fast(b2f_lo(cc1) + uu1.x);
            acc1 += gelu_fast(b2f_hi(cc1) + uu1.y);
            acc0 += gelu_fast(b2f_lo(cc2) + uu2.x);
            acc1 += gelu_fast(b2f_hi(cc2) + uu2.y);
            acc0 += gelu_fast(b2f_lo(cc3) + uu3.x);
            acc1 += gelu_fast(b2f_hi(cc3) + uu3.y);
        }
        if (p + 2 <= end) {
            unsigned pk0 = s_pk[p], pk1 = s_pk[p + 1];
            unsigned cc0 = Cb32[(pk0 & 0x1FFFFu) * 64 + L];
            unsigned cc1 = Cb32[(pk1 & 0x1FFFFu) * 64 + L];
            float2   uu0 = U2c2[(pk0 >> 17) * 64 + L];
            float2   uu1 = U2c2[(pk1 >> 17) * 64 + L];
            acc0 += gelu_fast(b2f_lo(cc0) + uu0.x);
            acc1 += gelu_fast(b2f_hi(cc0) + uu0.y);
            acc0 += gelu_fast(b2f_lo(cc1) + uu1.x);
            acc1 += gelu_fast(b2f_hi(cc1) + uu1.y);
            p += 2;
        }
        if (p < end) {
            unsigned pk0 = s_pk[p];
            unsigned cc0 = Cb32[(pk0 & 0x1FFFFu) * 64 + L];
            float2   uu0 = U2c2[(pk0 >> 17) * 64 + L];
            acc0 += gelu_fast(b2f_lo(cc0) + uu0.x);
            acc1 += gelu_fast(b2f_hi(cc0) + uu0.y);
        }
        float s = __expf(i1);
        acc0 *= s; acc1 *= s;
    } else {
        float2 av = *(const float2*)(A + (size_t)node * WIDTH + 2 * L);
        int p = start;
        for (; p + 2 <= end; p += 2) {
            unsigned pk0 = s_pk[p], pk1 = s_pk[p + 1];
            unsigned sA = pk0 & 0x1FFFFu, cA = pk0 >> 17;
            unsigned sB = pk1 & 0x1FFFFu, cB = pk1 >> 17;
            float2 u0a = U0c2[cA * 64 + L], u0b = U0c2[cB * 64 + L];
            float2 u1a = U1c2[cA * 64 + L], u1b = U1c2[cB * 64 + L];
            float2 u2a = U2c2[cA * 64 + L], u2b = U2c2[cB * 64 + L];
            unsigned bba = Bb32[sA * 64 + L], bbb = Bb32[sB * 64 + L];
            unsigned cca = Cb32[sA * 64 + L], ccb = Cb32[sB * 64 + L];
            {
                float q0 = av.x + u0a.x, q1 = av.y + u0a.y;
                float k0 = b2f_lo(bba) + u1a.x, k1 = b2f_hi(bba) + u1a.y;
                float v0 = gelu_fast(b2f_lo(cca) + u2a.x);
                float v1 = gelu_fast(b2f_hi(cca) + u2a.y);
                float s = q0 * k0 + q1 * k1;
                s += __shfl_xor(s, 1);
                s += __shfl_xor(s, 2);
                s += __shfl_xor(s, 4);
                s += __shfl_xor(s, 8);
                s += __shfl_xor(s, 16);
                float att = __expf(s * 0.125f * i0 + i1);
                acc0 += v0 * att;
                acc1 += v1 * att;
            }
            {
                float q0 = av.x + u0b.x, q1 = av.y + u0b.y;
                float k0 = b2f_lo(bbb) + u1b.x, k1 = b2f_hi(bbb) + u1b.y;
                float v0 = gelu_fast(b2f_lo(ccb) + u2b.x);
                float v1 = gelu_fast(b2f_hi(ccb) + u2b.y);
                float s = q0 * k0 + q1 * k1;
                s += __shfl_xor(s, 1);
                s += __shfl_xor(s, 2);
                s += __shfl_xor(s, 4);
                s += __shfl_xor(s, 8);
                s += __shfl_xor(s, 16);
                float att = __expf(s * 0.125f * i0 + i1);
                acc0 += v0 * att;
                acc1 += v1 * att;
            }
        }
        if (p < end) {
            unsigned pk = s_pk[p];
            unsigned sA = pk & 0x1FFFFu, cA = pk >> 17;
            float2 u0 = U0c2[cA * 64 + L];
            float2 u1 = U1c2[cA * 64 + L];
            float2 u2 = U2c2[cA * 64 + L];
            unsigned bb = Bb32[sA * 64 + L];
            unsigned cc = Cb32[sA * 64 + L];
            float q0 = av.x + u0.x, q1 = av.y + u0.y;
            float k0 = b2f_lo(bb) + u1.x, k1 = b2f_hi(bb) + u1.y;
            float v0 = gelu_fast(b2f_lo(cc) + u2.x);
            float v1 = gelu_fast(b2f_hi(cc) + u2.y);
            float s = q0 * k0 + q1 * k1;
            s += __shfl_xor(s, 1);
            s += __shfl_xor(s, 2);
            s += __shfl_xor(s, 4);
            s += __shfl_xor(s, 8);
            s += __shfl_xor(s, 16);
            float att = __expf(s * 0.125f * i0 + i1);
            acc0 += v0 * att;
            acc1 += v1 * att;
        }
    }
    unsigned g = ((const unsigned*)Gb)[(size_t)node * 64 + L];
    ((unsigned*)hb)[(size_t)node * 64 + L] = pack2(b2f_lo(g) + acc0, b2f_hi(g) + acc1);
}

// ---------------------------------------------------------------------------
// k_post: coop-load hb -> LDS, B-stationary MFMA, staged coalesced out.
// ---------------------------------------------------------------------------
__global__ void __launch_bounds__(256, 2) k_post(
        const float* __restrict__ x, const short* __restrict__ hb,
        const short* __restrict__ postF, const float* __restrict__ post_b,
        float* __restrict__ out, int n) {
    __shared__ short hs[64 * XSL];
    __shared__ float os[64 * OSL];
    int tid  = threadIdx.x;
    int w    = tid >> 6;
    int lane = tid & 63;
    int quad = lane >> 4, l16 = lane & 15;
    int m0   = blockIdx.x * 64;

    bf16x8 Bp[2][4];
#pragma unroll
    for (int tt = 0; tt < 2; ++tt)
#pragma unroll
        for (int kc = 0; kc < 4; ++kc)
            Bp[tt][kc] = *(const bf16x8*)(postF + (((2 * w + tt) * 4 + kc) * 64 + lane) * 8);

#pragma unroll
    for (int it = 0; it < 4; ++it) {
        int si  = it * 256 + tid;
        int row = si >> 4, c8 = si & 15;
        int gr  = min(m0 + row, n - 1);
        *(bf16x8*)(&hs[row * XSL + c8 * 8]) = *(const bf16x8*)(hb + (size_t)gr * WIDTH + c8 * 8);
    }
    __syncthreads();

    bf16x8 a[4][4];
#pragma unroll
    for (int i = 0; i < 4; ++i)
#pragma unroll
        for (int kc = 0; kc < 4; ++kc)
            a[i][kc] = *(const bf16x8*)(&hs[(i * 16 + l16) * XSL + kc * 32 + quad * 8]);

    f32x4 acc[4][2];
#pragma unroll
    for (int i = 0; i < 4; ++i)
#pragma unroll
        for (int tt = 0; tt < 2; ++tt) acc[i][tt] = (f32x4){0.f,0.f,0.f,0.f};
#pragma unroll
    for (int kc = 0; kc < 4; ++kc)
#pragma unroll
        for (int i = 0; i < 4; ++i)
#pragma unroll
            for (int tt = 0; tt < 2; ++tt)
                acc[i][tt] = __builtin_amdgcn_mfma_f32_16x16x32_bf16(a[i][kc], Bp[tt][kc], acc[i][tt], 0, 0, 0);

#pragma unroll
    for (int tt = 0; tt < 2; ++tt) {
        int col = (2 * w + tt) * 16 + l16;
        float bv = post_b[col];
#pragma unroll
        for (int i = 0; i < 4; ++i)
#pragma unroll
            for (int r = 0; r < 4; ++r)
                os[(i * 16 + quad * 4 + r) * OSL + col] = acc[i][tt][r] + bv;
    }
    __syncthreads();

#pragma unroll
    for (int it = 0; it < 8; ++it) {
        int fi  = it * 256 + tid;
        int row = fi >> 5, c4 = fi & 31;
        if (m0 + row < n) {
            float4 xv = ((const float4*)x)[(size_t)(m0 + row) * 32 + c4];
            float4 av = *(const float4*)(&os[row * OSL + c4 * 4]);
            float4 ov = {xv.x + av.x, xv.y + av.y, xv.z + av.z, xv.w + av.w};
            ((float4*)out)[(size_t)(m0 + row) * 32 + c4] = ov;
        }
    }
}

extern "C" void kernel_launch(void* const* d_in, const int* in_sizes, int n_in,
                              void* d_out, int out_size, void* d_ws, size_t ws_size,
                              hipStream_t stream) {
    const float* x      = (const float*)d_in[0];
    const int*   eidx   = (const int*)d_in[1];
    const int*   eattr  = (const int*)d_in[2];
    const float* pre_w  = (const float*)d_in[3];
    const float* pre_b  = (const float*)d_in[4];
    const float* msg0_w = (const float*)d_in[5];
    const float* msg0_b = (const float*)d_in[6];
    const float* msg1_w = (const float*)d_in[7];
    const float* msg1_b = (const float*)d_in[8];
    const float* msg2_w = (const float*)d_in[9];
    const float* msg2_b = (const float*)d_in[10];
    const float* msg3_w = (const float*)d_in[11];
    const float* msg3_b = (const float*)d_in[12];
    const float* r0w    = (const float*)d_in[13];
    const float* r0b    = (const float*)d_in[14];
    const float* r1w    = (const float*)d_in[15];
    const float* r1b    = (const float*)d_in[16];
    const float* r2w    = (const float*)d_in[17];
    const float* r2b    = (const float*)d_in[18];
    const float* post_w = (const float*)d_in[19];
    const float* post_b = (const float*)d_in[20];
    const float* emb0   = (const float*)d_in[21];
    const float* emb1   = (const float*)d_in[22];
    const float* emb2   = (const float*)d_in[23];
    const float* emb3   = (const float*)d_in[24];
    const float* einit  = (const float*)d_in[25];
    const float* init0  = (const float*)d_in[26];

    int n = in_sizes[0] / WIDTH;
    int E = in_sizes[2] / 4;
    size_t NW = (size_t)n * WIDTH;

    float* ws   = (float*)d_ws;
    float* A    = ws;                              // [N,128] f32 (full path only)
    float* U    = ws + NW;                         // [3][34][128]
    float* Uc   = U + 3 * 34 * WIDTH;              // [3][NCOMBO][128]
    float* scal = Uc + 3 * (size_t)NCOMBO * WIDTH; // [2]
    short* sw   = (short*)(scal + 2);
    short* preF  = sw;                             // 6 x 16384 bf16 frag-order weights
    short* w0F   = sw + 16384;
    short* w1F   = sw + 2 * 16384;
    short* w2F   = sw + 3 * 16384;
    short* w3F   = sw + 4 * 16384;
    short* postF = sw + 5 * 16384;
    short* Bb    = sw + 6 * 16384;                 // [N,128] bf16 (full path)
    short* Cb    = Bb + NW;                        // [N,128] bf16
    short* Gb    = Cb + NW;                        // [N,128] bf16
    short* hb    = Gb + NW;                        // [N,128] bf16
    int*      ib       = (int*)(hb + NW);
    int*      offsets  = ib;                       // n+1
    int*      counts   = offsets + (n + 1);        // n
    int*      lscan    = counts + n;               // n
    int*      partials = lscan + n;                // <=1024
    int*      rank     = partials + 1024;          // E
    unsigned* s_pk     = (unsigned*)(rank + E);    // E

    hipMemsetAsync(counts, 0, (size_t)n * sizeof(int), stream);

    // F1: weight swizzle + U tables + hist(rank)
    int f1_total = TOTW + TOTU + E;
    k_f1<<<(f1_total + 255) / 256, 256, 0, stream>>>(
        einit, init0, emb0, emb1, emb2, emb3,
        r0w, r0b, r1w, r1b, r2w, r2b,
        pre_w, msg0_w, msg1_w, msg2_w, msg3_w, post_w,
        preF, w0F, w1F, w2F, w3F, postF, U, scal,
        eidx, counts, rank, E);

    // F2: scan1 + prepc
    int sb  = (n + 255) / 256;
    int pcb = (3 * NCOMBO + 1) / 2;
    k_f2<<<sb + pcb, 256, 0, stream>>>(counts, lscan, partials, n, sb, U, init0, Uc);

    k_scan2<<<1, 1024, 0, stream>>>(partials, sb, offsets, n);

    // F3: gemm12 + scatter (inline offsets) + scan3
    int gb = (n + 63) / 64;
    int eb = (E + 255) / 256;
    k_f3<<<gb + eb + sb, 256, 0, stream>>>(
        x, preF, pre_b, w0F, msg0_b, w1F, msg1_b, w2F, msg2_b, w3F, msg3_b,
        scal, Gb, A, Bb, Cb, n,
        eidx, eattr, counts, lscan, partials, rank, offsets, s_pk, E, gb, eb);

    k_agg<<<(n + 3) / 4, 256, 0, stream>>>(offsets, s_pk, A, Bb, Cb, Uc, scal, Gb, hb, n);
    k_post<<<gb, 256, 0, stream>>>(x, hb, postF, post_b, (float*)d_out, n);
}